// Round 1
// baseline (1236.226 us; speedup 1.0000x reference)
//
#include <hip/hip_runtime.h>
#include <hip/hip_bf16.h>

typedef __hip_bfloat16 bf16;
typedef __hip_bfloat162 bf162;

#define U_N   100000
#define B_N   50000
#define N_TOT 150000
#define NE_UB 800000
#define NE_BB 600000
#define NP    400000
#define DU    64
#define DB    128
#define HD    128

// bucketed-fill geometry: one bucket per CU (256 total per fill)
#define NBU 128                          // user-side buckets (ub graph)
#define NBB 128                          // book-side buckets (ub graph)
#define UPB ((U_N + NBU - 1) / NBU)      // 782 users / bucket
#define BPB ((B_N + NBB - 1) / NBB)      // 391 books / bucket
#define NB2 256                          // buckets for bb graph
#define BPB2 ((B_N + NB2 - 1) / NB2)     // 196 books / bucket

__device__ __forceinline__ float b2f(bf16 v) { return __bfloat162float(v); }
__device__ __forceinline__ float2 ldb2(const bf16* row, int lane) {
    bf162 v = ((const bf162*)row)[lane];
    return make_float2(b2f(v.x), b2f(v.y));
}
__device__ __forceinline__ void stb2(bf16* row, int lane, float2 v) {
    bf162 o;
    o.x = __float2bfloat16(v.x);
    o.y = __float2bfloat16(v.y);
    ((bf162*)row)[lane] = o;
}

// ---------------- dense blocks (f32 compute; f32 and/or bf16 outputs) ----------------

template<int K>
__global__ void k_init_gemm(const float* __restrict__ x, const float* __restrict__ W,
                            const float* __restrict__ bias,
                            float* outf, bf16* out16, int nrows) {
    __shared__ float row[8][K];
    const int c  = threadIdx.x;
    const int r0 = blockIdx.x * 8;
    for (int i = threadIdx.x; i < 8 * K; i += 128) {
        int rr = i / K, kk = i % K;
        int r = r0 + rr;
        row[rr][kk] = (r < nrows) ? x[(size_t)r * K + kk] : 0.0f;
    }
    __syncthreads();
    float acc[8];
#pragma unroll
    for (int i = 0; i < 8; i++) acc[i] = 0.0f;
    for (int k = 0; k < K; k++) {
        float w = W[k * HD + c];
#pragma unroll
        for (int i = 0; i < 8; i++) acc[i] = fmaf(row[i][k], w, acc[i]);
    }
    float bv = bias[c];
#pragma unroll
    for (int i = 0; i < 8; i++) {
        int r = r0 + i;
        if (r < nrows) {
            float v = acc[i] + bv;
            if (outf)  outf[(size_t)r * HD + c] = v;
            if (out16) out16[(size_t)r * HD + c] = __float2bfloat16(v);
        }
    }
}

// ---------------- CSR build: count -> scan -> bucketed fill ----------------

__global__ void k_cnt_ub(const int* __restrict__ us, const int* __restrict__ ud,
                         int* __restrict__ cnt) {
    int e = blockIdx.x * blockDim.x + threadIdx.x;
    if (e < NE_UB) {
        atomicAdd(&cnt[us[e]], 1);
        atomicAdd(&cnt[U_N + ud[e]], 1);
    }
}

__global__ void k_cnt_bb(const int* __restrict__ bd, int* __restrict__ cnt) {
    int e = blockIdx.x * blockDim.x + threadIdx.x;
    if (e < NE_BB) atomicAdd(&cnt[bd[e]], 1);
}

__global__ void k_dinv(const int* __restrict__ cnt, float* __restrict__ dinv) {
    int i = blockIdx.x * blockDim.x + threadIdx.x;
    if (i < N_TOT) {
        int d = cnt[i];
        dinv[i] = (d > 0) ? 1.0f / sqrtf((float)d) : 0.0f;
    }
}

__global__ void k_scan1(const int* __restrict__ cnt, int* __restrict__ rs,
                        int* __restrict__ bsum, int n) {
    __shared__ int ts[256];
    const int t = threadIdx.x;
    const int base = blockIdx.x * 1024 + t * 4;
    int v0 = (base + 0 < n) ? cnt[base + 0] : 0;
    int v1 = (base + 1 < n) ? cnt[base + 1] : 0;
    int v2 = (base + 2 < n) ? cnt[base + 2] : 0;
    int v3 = (base + 3 < n) ? cnt[base + 3] : 0;
    int local = v0 + v1 + v2 + v3;
    ts[t] = local;
    __syncthreads();
    for (int off = 1; off < 256; off <<= 1) {
        int x = (t >= off) ? ts[t - off] : 0;
        __syncthreads();
        ts[t] += x;
        __syncthreads();
    }
    int ex = ts[t] - local;
    if (base + 0 < n) rs[base + 0] = ex;
    if (base + 1 < n) rs[base + 1] = ex + v0;
    if (base + 2 < n) rs[base + 2] = ex + v0 + v1;
    if (base + 3 < n) rs[base + 3] = ex + v0 + v1 + v2;
    if (t == 0) bsum[blockIdx.x] = ts[255];
}

__global__ void k_scan2(int* __restrict__ bsum, int nb) {
    __shared__ int ts[256];
    const int t = threadIdx.x;
    const int base = t * 4;
    int v0 = (base + 0 < nb) ? bsum[base + 0] : 0;
    int v1 = (base + 1 < nb) ? bsum[base + 1] : 0;
    int v2 = (base + 2 < nb) ? bsum[base + 2] : 0;
    int v3 = (base + 3 < nb) ? bsum[base + 3] : 0;
    int local = v0 + v1 + v2 + v3;
    ts[t] = local;
    __syncthreads();
    for (int off = 1; off < 256; off <<= 1) {
        int x = (t >= off) ? ts[t - off] : 0;
        __syncthreads();
        ts[t] += x;
        __syncthreads();
    }
    int ex = ts[t] - local;
    if (base + 0 < nb) bsum[base + 0] = ex;
    if (base + 1 < nb) bsum[base + 1] = ex + v0;
    if (base + 2 < nb) bsum[base + 2] = ex + v0 + v1;
    if (base + 3 < nb) bsum[base + 3] = ex + v0 + v1 + v2;
}

__global__ void k_scan3(int* __restrict__ rs, const int* __restrict__ bsum, int n) {
    int i = blockIdx.x * blockDim.x + threadIdx.x;
    if (i < n) rs[i] += bsum[i >> 10];
}

// Bucketed fill for the bipartite ub graph. Block b < NBU owns users
// [b*UPB, b*UPB+UPB); block b >= NBU owns books [(b-NBU)*BPB, ...).
// Each WG streams the full key array (int4-vectorized), keeps its own
// edges, and places them via LDS cursors: all eidx lines of the owned
// range are fully written by ONE workgroup -> packed L2 writebacks
// (kills the 16x partial-line write amplification of the atomic fill).
// rs is NOT mutated: it stays the exclusive prefix.
__global__ __launch_bounds__(1024) void k_fill_ub2(const int* __restrict__ us,
                                                   const int* __restrict__ ud,
                                                   const int* __restrict__ rs,
                                                   int* __restrict__ eidx) {
    __shared__ int cur[UPB];
    const bool userSide = blockIdx.x < NBU;
    int node0, nn, rbase;
    const int* keys;
    if (userSide) {
        node0 = blockIdx.x * UPB;
        nn    = min(UPB, U_N - node0);
        rbase = node0;
        keys  = us;
    } else {
        int b = blockIdx.x - NBU;
        node0 = b * BPB;
        nn    = min(BPB, B_N - node0);
        rbase = U_N + node0;
        keys  = ud;
    }
    for (int i = threadIdx.x; i < nn; i += 1024) cur[i] = rs[rbase + i];
    __syncthreads();
    const int4* k4 = (const int4*)keys;
    for (int q = threadIdx.x; q < NE_UB / 4; q += 1024) {
        int4 kv = k4[q];
        int ka[4] = {kv.x, kv.y, kv.z, kv.w};
#pragma unroll
        for (int i = 0; i < 4; i++) {
            int key = ka[i];
            if (key >= node0 && key < node0 + nn) {
                int p = atomicAdd(&cur[key - node0], 1);
                eidx[p] = userSide ? (U_N + ud[4 * q + i]) : us[4 * q + i];
            }
        }
    }
}

__global__ __launch_bounds__(1024) void k_fill_bb2(const int* __restrict__ bs,
                                                   const int* __restrict__ bd,
                                                   const int* __restrict__ rs,
                                                   int* __restrict__ eidx) {
    __shared__ int cur[BPB2];
    const int node0 = blockIdx.x * BPB2;
    const int nn    = min(BPB2, B_N - node0);
    for (int i = threadIdx.x; i < nn; i += 1024) cur[i] = rs[node0 + i];
    __syncthreads();
    const int4* k4 = (const int4*)bd;
    for (int q = threadIdx.x; q < NE_BB / 4; q += 1024) {
        int4 kv = k4[q];
        int ka[4] = {kv.x, kv.y, kv.z, kv.w};
#pragma unroll
        for (int i = 0; i < 4; i++) {
            int key = ka[i];
            if (key >= node0 && key < node0 + nn) {
                int p = atomicAdd(&cur[key - node0], 1);
                eidx[p] = bs[4 * q + i];
            }
        }
    }
}

// ---------------- pull-mode propagation (bf16 tables, f32 accumulate) ----------------
// rs convention: exclusive prefix; segment of w = [rs[w], rs[w+1]) with a
// constant total at the last node.

// round 1: x1[w] = sum_nb x0[nb]*dinv[nb]*dinv[w]
__global__ void k_gather1(const int* __restrict__ rs, const int* __restrict__ eidx,
                          const float* __restrict__ dinv,
                          const bf16* __restrict__ x016, bf16* __restrict__ x116) {
    int w    = (blockIdx.x * blockDim.x + threadIdx.x) >> 6;
    int lane = threadIdx.x & 63;
    if (w >= N_TOT) return;
    int s = rs[w];
    int e = (w == N_TOT - 1) ? (2 * NE_UB) : rs[w + 1];
    s = __builtin_amdgcn_readfirstlane(s);
    e = __builtin_amdgcn_readfirstlane(e);
    float nd = dinv[w];
    float2 acc = make_float2(0.0f, 0.0f);
    for (int j = s; j < e; ++j) {
        int nb = eidx[j];
        float wgt = nd * dinv[nb];
        float2 v = ldb2(x016 + (size_t)nb * HD, lane);
        acc.x = fmaf(v.x, wgt, acc.x);
        acc.y = fmaf(v.y, wgt, acc.y);
    }
    stb2(x116 + (size_t)w * HD, lane, acc);
}

// round 2: xf[w] = (x0[w] + x1[w] + sum_nb x1[nb]*dinv[nb]*dinv[w]) / 3
__global__ void k_gather2(const int* __restrict__ rs, const int* __restrict__ eidx,
                          const float* __restrict__ dinv,
                          const bf16* __restrict__ x016, const bf16* __restrict__ x116,
                          bf16* __restrict__ xf16) {
    int w    = (blockIdx.x * blockDim.x + threadIdx.x) >> 6;
    int lane = threadIdx.x & 63;
    if (w >= N_TOT) return;
    int s = rs[w];
    int e = (w == N_TOT - 1) ? (2 * NE_UB) : rs[w + 1];
    s = __builtin_amdgcn_readfirstlane(s);
    e = __builtin_amdgcn_readfirstlane(e);
    float nd = dinv[w];
    float2 acc = make_float2(0.0f, 0.0f);
    for (int j = s; j < e; ++j) {
        int nb = eidx[j];
        float wgt = nd * dinv[nb];
        float2 v = ldb2(x116 + (size_t)nb * HD, lane);
        acc.x = fmaf(v.x, wgt, acc.x);
        acc.y = fmaf(v.y, wgt, acc.y);
    }
    float2 a = ldb2(x016 + (size_t)w * HD, lane);
    float2 b = ldb2(x116 + (size_t)w * HD, lane);
    acc.x = (acc.x + a.x + b.x) * (1.0f / 3.0f);
    acc.y = (acc.y + a.y + b.y) * (1.0f / 3.0f);
    stb2(xf16 + (size_t)w * HD, lane, acc);
}

// agg[w] = (sum_nb h16[nb]) / max(deg,1)   (bf16 in, f32 out)
__global__ void k_gather_bb(const int* __restrict__ rs, const int* __restrict__ eidx,
                            const bf16* __restrict__ h16, float* __restrict__ agg) {
    int w    = (blockIdx.x * blockDim.x + threadIdx.x) >> 6;
    int lane = threadIdx.x & 63;
    if (w >= B_N) return;
    int s = rs[w];
    int e = (w == B_N - 1) ? NE_BB : rs[w + 1];
    s = __builtin_amdgcn_readfirstlane(s);
    e = __builtin_amdgcn_readfirstlane(e);
    float2 acc = make_float2(0.0f, 0.0f);
    for (int j = s; j < e; ++j) {
        int nb = eidx[j];
        float2 v = ldb2(h16 + (size_t)nb * HD, lane);
        acc.x += v.x;
        acc.y += v.y;
    }
    float inv = 1.0f / fmaxf((float)(e - s), 1.0f);
    acc.x *= inv;
    acc.y *= inv;
    ((float2*)(agg + (size_t)w * HD))[lane] = acc;
}

// hout = relu(agg@Wl + bl + h@Wr); in-place safe (block-row-local via LDS)
__global__ void k_glayer(const float* __restrict__ agg, const float* __restrict__ h,
                         const float* __restrict__ Wl, const float* __restrict__ bl,
                         const float* __restrict__ Wr,
                         float* outf, bf16* out16) {
    __shared__ float sa[8][HD];
    __shared__ float sh[8][HD];
    const int c  = threadIdx.x;
    const int r0 = blockIdx.x * 8;
#pragma unroll
    for (int i = 0; i < 8; i++) {
        int r = r0 + i;
        sa[i][c] = (r < B_N) ? agg[(size_t)r * HD + c] : 0.0f;
        sh[i][c] = (r < B_N) ? h[(size_t)r * HD + c] : 0.0f;
    }
    __syncthreads();
    float acc[8];
#pragma unroll
    for (int i = 0; i < 8; i++) acc[i] = 0.0f;
    for (int k = 0; k < HD; k++) {
        float wl = Wl[k * HD + c];
        float wr = Wr[k * HD + c];
#pragma unroll
        for (int i = 0; i < 8; i++) {
            acc[i] = fmaf(sa[i][k], wl, acc[i]);
            acc[i] = fmaf(sh[i][k], wr, acc[i]);
        }
    }
    float bv = bl[c];
#pragma unroll
    for (int i = 0; i < 8; i++) {
        int r = r0 + i;
        if (r < B_N) {
            float v = fmaxf(acc[i] + bv, 0.0f);
            if (outf)  outf[(size_t)r * HD + c] = v;
            if (out16) out16[(size_t)r * HD + c] = __float2bfloat16(v);
        }
    }
}

// attention fusion head, 4 rows per 128-thread block (2 waves); bf16 in/out
__global__ void k_fuse(const bf16* __restrict__ collab16, const bf16* __restrict__ content16,
                       const float* __restrict__ Wf1, const float* __restrict__ bf1v,
                       const float* __restrict__ Wf2, const float* __restrict__ bf2v,
                       bf16* __restrict__ fused16) {
    const int R = 4;
    __shared__ float sc[R][HD];
    __shared__ float sh[R][HD];
    __shared__ float part[2][R][2];
    __shared__ float attn[R][2];
    const int c  = threadIdx.x;
    const int r0 = blockIdx.x * R;
#pragma unroll
    for (int i = 0; i < R; i++) {
        int r = r0 + i;
        sc[i][c] = (r < B_N) ? b2f(collab16[(size_t)r * HD + c]) : 0.0f;
        sh[i][c] = (r < B_N) ? b2f(content16[(size_t)r * HD + c]) : 0.0f;
    }
    __syncthreads();
    float t[R];
#pragma unroll
    for (int i = 0; i < R; i++) t[i] = 0.0f;
    for (int k = 0; k < HD; k++) {
        float w = Wf1[k * HD + c];
#pragma unroll
        for (int i = 0; i < R; i++) t[i] = fmaf(sc[i][k], w, t[i]);
    }
    for (int k = 0; k < HD; k++) {
        float w = Wf1[(size_t)(HD + k) * HD + c];
#pragma unroll
        for (int i = 0; i < R; i++) t[i] = fmaf(sh[i][k], w, t[i]);
    }
    float b1  = bf1v[c];
    float w20 = Wf2[c * 2 + 0];
    float w21 = Wf2[c * 2 + 1];
    float p0[R], p1[R];
#pragma unroll
    for (int i = 0; i < R; i++) {
        float tv = fmaxf(t[i] + b1, 0.0f);
        p0[i] = tv * w20;
        p1[i] = tv * w21;
    }
#pragma unroll
    for (int i = 0; i < R; i++) {
        for (int off = 32; off > 0; off >>= 1) {
            p0[i] += __shfl_down(p0[i], off, 64);
            p1[i] += __shfl_down(p1[i], off, 64);
        }
    }
    int wv   = threadIdx.x >> 6;
    int lane = threadIdx.x & 63;
    if (lane == 0) {
#pragma unroll
        for (int i = 0; i < R; i++) { part[wv][i][0] = p0[i]; part[wv][i][1] = p1[i]; }
    }
    __syncthreads();
    if (threadIdx.x < R) {
        int i = threadIdx.x;
        float s0 = part[0][i][0] + part[1][i][0] + bf2v[0];
        float s1 = part[0][i][1] + part[1][i][1] + bf2v[1];
        float m  = fmaxf(s0, s1);
        float e0 = expf(s0 - m), e1 = expf(s1 - m);
        float inv = 1.0f / (e0 + e1);
        attn[i][0] = e0 * inv;
        attn[i][1] = e1 * inv;
    }
    __syncthreads();
#pragma unroll
    for (int i = 0; i < R; i++) {
        int r = r0 + i;
        if (r < B_N) {
            float v = attn[i][0] * sc[i][c] + attn[i][1] * sh[i][c];
            fused16[(size_t)r * HD + c] = __float2bfloat16(v);
        }
    }
}

// 4 predictions per wave, 16 lanes x 16B (int4 of 8 bf16) per row
__global__ void k_score(const int* __restrict__ pu, const int* __restrict__ pb,
                        const bf16* __restrict__ uemb16, const bf16* __restrict__ fused16,
                        float* __restrict__ out) {
    int wid  = (blockIdx.x * blockDim.x + threadIdx.x) >> 6;
    int lane = threadIdx.x & 63;
    int g = lane >> 4;
    int l = lane & 15;
    int p = wid * 4 + g;
    if (p >= NP) return;
    int u = pu[p];
    int b = pb[p];
    int4 av = ((const int4*)(uemb16 + (size_t)u * HD))[l];
    int4 fv = ((const int4*)(fused16 + (size_t)b * HD))[l];
    const int* ap = (const int*)&av;
    const int* fp = (const int*)&fv;
    float s = 0.0f;
#pragma unroll
    for (int i = 0; i < 4; i++) {
        bf162 a2 = *(const bf162*)&ap[i];
        bf162 f2 = *(const bf162*)&fp[i];
        s = fmaf(b2f(a2.x), b2f(f2.x), s);
        s = fmaf(b2f(a2.y), b2f(f2.y), s);
    }
#pragma unroll
    for (int off = 8; off > 0; off >>= 1) s += __shfl_xor(s, off, 64);
    if (l == 0) out[p] = s;
}

extern "C" void kernel_launch(void* const* d_in, const int* in_sizes, int n_in,
                              void* d_out, int out_size, void* d_ws, size_t ws_size,
                              hipStream_t stream) {
    const float* user_x = (const float*)d_in[0];
    const float* book_x = (const float*)d_in[1];
    const int*   ub_src = (const int*)d_in[2];
    const int*   ub_dst = (const int*)d_in[3];
    const int*   bb_src = (const int*)d_in[4];
    const int*   bb_dst = (const int*)d_in[5];
    const int*   pred_u = (const int*)d_in[6];
    const int*   pred_b = (const int*)d_in[7];
    const float* Wu   = (const float*)d_in[8];
    const float* bu   = (const float*)d_in[9];
    const float* Wub  = (const float*)d_in[10];
    const float* bub  = (const float*)d_in[11];
    const float* Wbb  = (const float*)d_in[12];
    const float* bbb  = (const float*)d_in[13];
    const float* Wl1  = (const float*)d_in[14];
    const float* bl1  = (const float*)d_in[15];
    const float* Wr1  = (const float*)d_in[16];
    const float* Wl2  = (const float*)d_in[17];
    const float* bl2  = (const float*)d_in[18];
    const float* Wr2  = (const float*)d_in[19];
    const float* Wf1  = (const float*)d_in[20];
    const float* bf1v = (const float*)d_in[21];
    const float* Wf2  = (const float*)d_in[22];
    const float* bf2v = (const float*)d_in[23];
    float* out = (float*)d_out;

    // ---- workspace layout (4-byte words), total 30.96M words = 123.84 MB ----
    // [0,       560000)   aux: dinv|cnt_ub|rs_ub|cnt_bb|rs_bb|bsum
    // [560000, 2160000)   eidx (ub CSR 1.6M; bb CSR 600k aliased later)
    // [2160000,11760000)  X016  bf16 N*H   | content: hf f32 [2160000,8560000)
    //                                      |          h16 bf16 [8560000,11760000)
    // [11760000,21360000) X1_16 bf16 N*H   | content: aggf f32 [11760000,18160000)
    //                                      |          fused16 [11760000,14960000) after aggf dies
    // [21360000,30960000) XF16  bf16 N*H   (uemb = rows 0..U, collab = rows U..N)
    float* ws = (float*)d_ws;
    const size_t need = 30960000ull * sizeof(float);
    if (ws_size < need) return;

    float* dinv    = ws;
    int*   cnt_ub  = (int*)(ws + 150000);
    int*   rs_ub   = (int*)(ws + 300000);
    int*   cnt_bb  = (int*)(ws + 450000);
    int*   rs_bb   = (int*)(ws + 500000);
    int*   bsum    = (int*)(ws + 550000);
    int*   eidx    = (int*)(ws + 560000);
    bf16*  X016    = (bf16*)(ws + 2160000);
    bf16*  X1_16   = (bf16*)(ws + 11760000);
    bf16*  XF16    = (bf16*)(ws + 21360000);
    float* hf        = ws + 2160000;
    bf16*  h16       = (bf16*)(ws + 8560000);
    float* aggf      = ws + 11760000;
    bf16*  content16 = h16;
    bf16*  fused16   = (bf16*)(ws + 11760000);
    bf16*  uemb16    = XF16;
    bf16*  collab16  = XF16 + (size_t)U_N * HD;

    hipMemsetAsync(ws + 150000, 0, 350000 * sizeof(float), stream);

    // x0 -> X016 (bf16 only)
    k_init_gemm<DU><<<(U_N + 7) / 8, 128, 0, stream>>>(
        user_x, Wu, bu, (float*)nullptr, X016, U_N);
    k_init_gemm<DB><<<(B_N + 7) / 8, 128, 0, stream>>>(
        book_x, Wub, bub, (float*)nullptr, X016 + (size_t)U_N * HD, B_N);

    // ---- CSR build (ub graph, bidirectional) ----
    k_cnt_ub<<<(NE_UB + 255) / 256, 256, 0, stream>>>(ub_src, ub_dst, cnt_ub);
    k_cnt_bb<<<(NE_BB + 255) / 256, 256, 0, stream>>>(bb_dst, cnt_bb);
    k_dinv<<<(N_TOT + 255) / 256, 256, 0, stream>>>(cnt_ub, dinv);
    {
        int nb = (N_TOT + 1023) / 1024;
        k_scan1<<<nb, 256, 0, stream>>>(cnt_ub, rs_ub, bsum, N_TOT);
        k_scan2<<<1, 256, 0, stream>>>(bsum, nb);
        k_scan3<<<(N_TOT + 255) / 256, 256, 0, stream>>>(rs_ub, bsum, N_TOT);
    }
    k_fill_ub2<<<NBU + NBB, 1024, 0, stream>>>(ub_src, ub_dst, rs_ub, eidx);

    // ---- LightGCN propagation ----
    k_gather1<<<(N_TOT + 3) / 4, 256, 0, stream>>>(rs_ub, eidx, dinv, X016, X1_16);
    k_gather2<<<(N_TOT + 3) / 4, 256, 0, stream>>>(rs_ub, eidx, dinv, X016, X1_16, XF16);

    // ---- CSR build (bb graph) — ub CSR dead ----
    {
        int nb = (B_N + 1023) / 1024;
        k_scan1<<<nb, 256, 0, stream>>>(cnt_bb, rs_bb, bsum, B_N);
        k_scan2<<<1, 256, 0, stream>>>(bsum, nb);
        k_scan3<<<(B_N + 255) / 256, 256, 0, stream>>>(rs_bb, bsum, B_N);
    }
    k_fill_bb2<<<NB2, 1024, 0, stream>>>(bb_src, bb_dst, rs_bb, eidx);

    // ---- content network ----
    k_init_gemm<DB><<<(B_N + 7) / 8, 128, 0, stream>>>(book_x, Wbb, bbb, hf, h16, B_N);
    k_gather_bb<<<(B_N + 3) / 4, 256, 0, stream>>>(rs_bb, eidx, h16, aggf);
    k_glayer<<<(B_N + 7) / 8, 128, 0, stream>>>(aggf, hf, Wl1, bl1, Wr1, hf, h16);
    k_gather_bb<<<(B_N + 3) / 4, 256, 0, stream>>>(rs_bb, eidx, h16, aggf);
    k_glayer<<<(B_N + 7) / 8, 128, 0, stream>>>(aggf, hf, Wl2, bl2, Wr2,
                                                (float*)nullptr, content16);

    // ---- fusion + scores ----
    k_fuse<<<(B_N + 3) / 4, 128, 0, stream>>>(collab16, content16,
                                              Wf1, bf1v, Wf2, bf2v, fused16);
    k_score<<<NP / 16, 256, 0, stream>>>(pred_u, pred_b, uemb16, fused16, out);
}

// Round 2
// 963.112 us; speedup vs baseline: 1.2836x; 1.2836x over previous
//
#include <hip/hip_runtime.h>
#include <hip/hip_bf16.h>

typedef __hip_bfloat16 bf16;
typedef __hip_bfloat162 bf162;

using short8 = __attribute__((ext_vector_type(8))) short;
using f32x4  = __attribute__((ext_vector_type(4))) float;

#define U_N   100000
#define B_N   50000
#define N_TOT 150000
#define NE_UB 800000
#define NE_BB 600000
#define NP    400000
#define DU    64
#define DB    128
#define HD    128

// bucketed-fill geometry
#define NBU 128
#define NBB 128
#define UPB ((U_N + NBU - 1) / NBU)
#define BPB ((B_N + NBB - 1) / NBB)
#define NB2 256
#define BPB2 ((B_N + NB2 - 1) / NB2)

__device__ __forceinline__ float b2f(bf16 v) { return __bfloat162float(v); }
__device__ __forceinline__ float2 ldb2(const bf16* row, int lane) {
    bf162 v = ((const bf162*)row)[lane];
    return make_float2(b2f(v.x), b2f(v.y));
}
__device__ __forceinline__ void stb2(bf16* row, int lane, float2 v) {
    bf162 o;
    o.x = __float2bfloat16(v.x);
    o.y = __float2bfloat16(v.y);
    ((bf162*)row)[lane] = o;
}
// f32 -> bf16 bits (RNE)
__device__ __forceinline__ short f2bs(float f) {
    unsigned u = __float_as_uint(f);
    unsigned r = (u + 0x7fffu + ((u >> 16) & 1u)) >> 16;
    return (short)r;
}

// ---------------- bf16 conversion + weight packing ----------------

// n must be a multiple of 8
__global__ void k_f2b(const float* __restrict__ in, short* __restrict__ out, int n) {
    int i = (blockIdx.x * blockDim.x + threadIdx.x) * 8;
    if (i >= n) return;
    float4 a = ((const float4*)(in + i))[0];
    float4 b = ((const float4*)(in + i))[1];
    short8 v;
    v[0] = f2bs(a.x); v[1] = f2bs(a.y); v[2] = f2bs(a.z); v[3] = f2bs(a.w);
    v[4] = f2bs(b.x); v[5] = f2bs(b.y); v[6] = f2bs(b.z); v[7] = f2bs(b.w);
    *(short8*)(out + i) = v;
}

// Pack W[KTOT][128] f32 into MFMA B-fragment order (bf16):
// Wp[((kk*8 + n)*64 + lane)*8 + j] = bf16(W[kk*32 + (lane>>4)*8 + j][n*16 + (lane&15)])
template<int KTOT>
__global__ void k_pack_w(const float* __restrict__ W, short* __restrict__ Wp) {
    int t = blockIdx.x * blockDim.x + threadIdx.x;
    if (t >= (KTOT / 32) * 8 * 64) return;
    int lane = t & 63;
    int n    = (t >> 6) & 7;
    int kk   = t >> 9;
    int lr = lane & 15, lg = lane >> 4;
    short8 v;
#pragma unroll
    for (int j = 0; j < 8; j++) {
        float f = W[(size_t)(kk * 32 + lg * 8 + j) * HD + (n * 16 + lr)];
        v[j] = f2bs(f);
    }
    *(short8*)(Wp + (size_t)t * 8) = v;
}

// ---------------- MFMA GEMM: out = [relu](A1@W1 [+ A2@W2] + bias), bf16 in/out ----
// A row-major [nrows][KS*32] bf16; Wp packed as above; out [nrows][128] bf16.
// Wave = 16 rows x 128 cols (8 col tiles); block = 4 waves = 64 rows.
// D layout (verified m89): col = lane&15, row = (lane>>4)*4 + reg.
template<int KS1, int KS2, bool RELU>
__global__ __launch_bounds__(256) void k_mgemm(
    const short* __restrict__ A1, const short* __restrict__ Wp1,
    const short* __restrict__ A2, const short* __restrict__ Wp2,
    const float* __restrict__ bias, bf16* __restrict__ out, int nrows) {
    const int wv   = threadIdx.x >> 6;
    const int lane = threadIdx.x & 63;
    const int row0 = blockIdx.x * 64 + wv * 16;
    if (row0 >= nrows) return;   // nrows % 16 == 0 in all uses
    const int lr = lane & 15, lg = lane >> 4;

    f32x4 acc[8];
#pragma unroll
    for (int n = 0; n < 8; n++) acc[n] = (f32x4){0.f, 0.f, 0.f, 0.f};

    {
        const short* a1p = A1 + (size_t)(row0 + lr) * (KS1 * 32) + lg * 8;
#pragma unroll
        for (int kk = 0; kk < KS1; kk++) {
            short8 af = *(const short8*)(a1p + kk * 32);
            const short* wp = Wp1 + ((size_t)(kk * 8) * 64 + lane) * 8;
#pragma unroll
            for (int n = 0; n < 8; n++) {
                short8 bfr = *(const short8*)(wp + (size_t)n * 64 * 8);
                acc[n] = __builtin_amdgcn_mfma_f32_16x16x32_bf16(af, bfr, acc[n], 0, 0, 0);
            }
        }
    }
    if constexpr (KS2 > 0) {
        const short* a2p = A2 + (size_t)(row0 + lr) * (KS2 * 32) + lg * 8;
#pragma unroll
        for (int kk = 0; kk < KS2; kk++) {
            short8 af = *(const short8*)(a2p + kk * 32);
            const short* wp = Wp2 + ((size_t)(kk * 8) * 64 + lane) * 8;
#pragma unroll
            for (int n = 0; n < 8; n++) {
                short8 bfr = *(const short8*)(wp + (size_t)n * 64 * 8);
                acc[n] = __builtin_amdgcn_mfma_f32_16x16x32_bf16(af, bfr, acc[n], 0, 0, 0);
            }
        }
    }
#pragma unroll
    for (int n = 0; n < 8; n++) {
        int col = n * 16 + lr;
        float bv = bias[col];
#pragma unroll
        for (int r = 0; r < 4; r++) {
            int row = row0 + lg * 4 + r;
            float v = acc[n][r] + bv;
            if (RELU) v = fmaxf(v, 0.0f);
            out[(size_t)row * HD + col] = __float2bfloat16(v);
        }
    }
}

// ---------------- CSR build: count -> scan -> bucketed fill ----------------

__global__ void k_cnt_ub(const int* __restrict__ us, const int* __restrict__ ud,
                         int* __restrict__ cnt) {
    int e = blockIdx.x * blockDim.x + threadIdx.x;
    if (e < NE_UB) {
        atomicAdd(&cnt[us[e]], 1);
        atomicAdd(&cnt[U_N + ud[e]], 1);
    }
}

__global__ void k_cnt_bb(const int* __restrict__ bd, int* __restrict__ cnt) {
    int e = blockIdx.x * blockDim.x + threadIdx.x;
    if (e < NE_BB) atomicAdd(&cnt[bd[e]], 1);
}

__global__ void k_dinv(const int* __restrict__ cnt, float* __restrict__ dinv) {
    int i = blockIdx.x * blockDim.x + threadIdx.x;
    if (i < N_TOT) {
        int d = cnt[i];
        dinv[i] = (d > 0) ? 1.0f / sqrtf((float)d) : 0.0f;
    }
}

__global__ void k_scan1(const int* __restrict__ cnt, int* __restrict__ rs,
                        int* __restrict__ bsum, int n) {
    __shared__ int ts[256];
    const int t = threadIdx.x;
    const int base = blockIdx.x * 1024 + t * 4;
    int v0 = (base + 0 < n) ? cnt[base + 0] : 0;
    int v1 = (base + 1 < n) ? cnt[base + 1] : 0;
    int v2 = (base + 2 < n) ? cnt[base + 2] : 0;
    int v3 = (base + 3 < n) ? cnt[base + 3] : 0;
    int local = v0 + v1 + v2 + v3;
    ts[t] = local;
    __syncthreads();
    for (int off = 1; off < 256; off <<= 1) {
        int x = (t >= off) ? ts[t - off] : 0;
        __syncthreads();
        ts[t] += x;
        __syncthreads();
    }
    int ex = ts[t] - local;
    if (base + 0 < n) rs[base + 0] = ex;
    if (base + 1 < n) rs[base + 1] = ex + v0;
    if (base + 2 < n) rs[base + 2] = ex + v0 + v1;
    if (base + 3 < n) rs[base + 3] = ex + v0 + v1 + v2;
    if (t == 0) bsum[blockIdx.x] = ts[255];
}

__global__ void k_scan2(int* __restrict__ bsum, int nb) {
    __shared__ int ts[256];
    const int t = threadIdx.x;
    const int base = t * 4;
    int v0 = (base + 0 < nb) ? bsum[base + 0] : 0;
    int v1 = (base + 1 < nb) ? bsum[base + 1] : 0;
    int v2 = (base + 2 < nb) ? bsum[base + 2] : 0;
    int v3 = (base + 3 < nb) ? bsum[base + 3] : 0;
    int local = v0 + v1 + v2 + v3;
    ts[t] = local;
    __syncthreads();
    for (int off = 1; off < 256; off <<= 1) {
        int x = (t >= off) ? ts[t - off] : 0;
        __syncthreads();
        ts[t] += x;
        __syncthreads();
    }
    int ex = ts[t] - local;
    if (base + 0 < nb) bsum[base + 0] = ex;
    if (base + 1 < nb) bsum[base + 1] = ex + v0;
    if (base + 2 < nb) bsum[base + 2] = ex + v0 + v1;
    if (base + 3 < nb) bsum[base + 3] = ex + v0 + v1 + v2;
}

__global__ void k_scan3(int* __restrict__ rs, const int* __restrict__ bsum, int n) {
    int i = blockIdx.x * blockDim.x + threadIdx.x;
    if (i < n) rs[i] += bsum[i >> 10];
}

__global__ __launch_bounds__(1024) void k_fill_ub2(const int* __restrict__ us,
                                                   const int* __restrict__ ud,
                                                   const int* __restrict__ rs,
                                                   int* __restrict__ eidx) {
    __shared__ int cur[UPB];
    const bool userSide = blockIdx.x < NBU;
    int node0, nn, rbase;
    const int* keys;
    if (userSide) {
        node0 = blockIdx.x * UPB;
        nn    = min(UPB, U_N - node0);
        rbase = node0;
        keys  = us;
    } else {
        int b = blockIdx.x - NBU;
        node0 = b * BPB;
        nn    = min(BPB, B_N - node0);
        rbase = U_N + node0;
        keys  = ud;
    }
    for (int i = threadIdx.x; i < nn; i += 1024) cur[i] = rs[rbase + i];
    __syncthreads();
    const int4* k4 = (const int4*)keys;
    for (int q = threadIdx.x; q < NE_UB / 4; q += 1024) {
        int4 kv = k4[q];
        int ka[4] = {kv.x, kv.y, kv.z, kv.w};
#pragma unroll
        for (int i = 0; i < 4; i++) {
            int key = ka[i];
            if (key >= node0 && key < node0 + nn) {
                int p = atomicAdd(&cur[key - node0], 1);
                eidx[p] = userSide ? (U_N + ud[4 * q + i]) : us[4 * q + i];
            }
        }
    }
}

__global__ __launch_bounds__(1024) void k_fill_bb2(const int* __restrict__ bs,
                                                   const int* __restrict__ bd,
                                                   const int* __restrict__ rs,
                                                   int* __restrict__ eidx) {
    __shared__ int cur[BPB2];
    const int node0 = blockIdx.x * BPB2;
    const int nn    = min(BPB2, B_N - node0);
    for (int i = threadIdx.x; i < nn; i += 1024) cur[i] = rs[node0 + i];
    __syncthreads();
    const int4* k4 = (const int4*)bd;
    for (int q = threadIdx.x; q < NE_BB / 4; q += 1024) {
        int4 kv = k4[q];
        int ka[4] = {kv.x, kv.y, kv.z, kv.w};
#pragma unroll
        for (int i = 0; i < 4; i++) {
            int key = ka[i];
            if (key >= node0 && key < node0 + nn) {
                int p = atomicAdd(&cur[key - node0], 1);
                eidx[p] = bs[4 * q + i];
            }
        }
    }
}

// ---------------- pull-mode propagation (bf16 tables, f32 accumulate) ----------------
// rs convention: exclusive prefix; segment of w = [rs[w], rs[w+1]).

__global__ void k_gather1(const int* __restrict__ rs, const int* __restrict__ eidx,
                          const float* __restrict__ dinv,
                          const bf16* __restrict__ x016, bf16* __restrict__ x116) {
    int w    = (blockIdx.x * blockDim.x + threadIdx.x) >> 6;
    int lane = threadIdx.x & 63;
    if (w >= N_TOT) return;
    int s = rs[w];
    int e = (w == N_TOT - 1) ? (2 * NE_UB) : rs[w + 1];
    s = __builtin_amdgcn_readfirstlane(s);
    e = __builtin_amdgcn_readfirstlane(e);
    float nd = dinv[w];
    float2 acc = make_float2(0.0f, 0.0f);
    for (int j = s; j < e; ++j) {
        int nb = eidx[j];
        float wgt = nd * dinv[nb];
        float2 v = ldb2(x016 + (size_t)nb * HD, lane);
        acc.x = fmaf(v.x, wgt, acc.x);
        acc.y = fmaf(v.y, wgt, acc.y);
    }
    stb2(x116 + (size_t)w * HD, lane, acc);
}

__global__ void k_gather2(const int* __restrict__ rs, const int* __restrict__ eidx,
                          const float* __restrict__ dinv,
                          const bf16* __restrict__ x016, const bf16* __restrict__ x116,
                          bf16* __restrict__ xf16) {
    int w    = (blockIdx.x * blockDim.x + threadIdx.x) >> 6;
    int lane = threadIdx.x & 63;
    if (w >= N_TOT) return;
    int s = rs[w];
    int e = (w == N_TOT - 1) ? (2 * NE_UB) : rs[w + 1];
    s = __builtin_amdgcn_readfirstlane(s);
    e = __builtin_amdgcn_readfirstlane(e);
    float nd = dinv[w];
    float2 acc = make_float2(0.0f, 0.0f);
    for (int j = s; j < e; ++j) {
        int nb = eidx[j];
        float wgt = nd * dinv[nb];
        float2 v = ldb2(x116 + (size_t)nb * HD, lane);
        acc.x = fmaf(v.x, wgt, acc.x);
        acc.y = fmaf(v.y, wgt, acc.y);
    }
    float2 a = ldb2(x016 + (size_t)w * HD, lane);
    float2 b = ldb2(x116 + (size_t)w * HD, lane);
    acc.x = (acc.x + a.x + b.x) * (1.0f / 3.0f);
    acc.y = (acc.y + a.y + b.y) * (1.0f / 3.0f);
    stb2(xf16 + (size_t)w * HD, lane, acc);
}

// agg[w] = (sum_nb h16[nb]) / max(deg,1)   (bf16 in, bf16 out)
__global__ void k_gather_bb(const int* __restrict__ rs, const int* __restrict__ eidx,
                            const bf16* __restrict__ h16, bf16* __restrict__ agg16) {
    int w    = (blockIdx.x * blockDim.x + threadIdx.x) >> 6;
    int lane = threadIdx.x & 63;
    if (w >= B_N) return;
    int s = rs[w];
    int e = (w == B_N - 1) ? NE_BB : rs[w + 1];
    s = __builtin_amdgcn_readfirstlane(s);
    e = __builtin_amdgcn_readfirstlane(e);
    float2 acc = make_float2(0.0f, 0.0f);
    for (int j = s; j < e; ++j) {
        int nb = eidx[j];
        float2 v = ldb2(h16 + (size_t)nb * HD, lane);
        acc.x += v.x;
        acc.y += v.y;
    }
    float inv = 1.0f / fmaxf((float)(e - s), 1.0f);
    acc.x *= inv;
    acc.y *= inv;
    stb2(agg16 + (size_t)w * HD, lane, acc);
}

// attention fusion head, 4 rows per 128-thread block (2 waves); bf16 in/out
__global__ void k_fuse(const bf16* __restrict__ collab16, const bf16* __restrict__ content16,
                       const float* __restrict__ Wf1, const float* __restrict__ bf1v,
                       const float* __restrict__ Wf2, const float* __restrict__ bf2v,
                       bf16* __restrict__ fused16) {
    const int R = 4;
    __shared__ float sc[R][HD];
    __shared__ float sh[R][HD];
    __shared__ float part[2][R][2];
    __shared__ float attn[R][2];
    const int c  = threadIdx.x;
    const int r0 = blockIdx.x * R;
#pragma unroll
    for (int i = 0; i < R; i++) {
        int r = r0 + i;
        sc[i][c] = (r < B_N) ? b2f(collab16[(size_t)r * HD + c]) : 0.0f;
        sh[i][c] = (r < B_N) ? b2f(content16[(size_t)r * HD + c]) : 0.0f;
    }
    __syncthreads();
    float t[R];
#pragma unroll
    for (int i = 0; i < R; i++) t[i] = 0.0f;
    for (int k = 0; k < HD; k++) {
        float w = Wf1[k * HD + c];
#pragma unroll
        for (int i = 0; i < R; i++) t[i] = fmaf(sc[i][k], w, t[i]);
    }
    for (int k = 0; k < HD; k++) {
        float w = Wf1[(size_t)(HD + k) * HD + c];
#pragma unroll
        for (int i = 0; i < R; i++) t[i] = fmaf(sh[i][k], w, t[i]);
    }
    float b1  = bf1v[c];
    float w20 = Wf2[c * 2 + 0];
    float w21 = Wf2[c * 2 + 1];
    float p0[R], p1[R];
#pragma unroll
    for (int i = 0; i < R; i++) {
        float tv = fmaxf(t[i] + b1, 0.0f);
        p0[i] = tv * w20;
        p1[i] = tv * w21;
    }
#pragma unroll
    for (int i = 0; i < R; i++) {
        for (int off = 32; off > 0; off >>= 1) {
            p0[i] += __shfl_down(p0[i], off, 64);
            p1[i] += __shfl_down(p1[i], off, 64);
        }
    }
    int wv   = threadIdx.x >> 6;
    int lane = threadIdx.x & 63;
    if (lane == 0) {
#pragma unroll
        for (int i = 0; i < R; i++) { part[wv][i][0] = p0[i]; part[wv][i][1] = p1[i]; }
    }
    __syncthreads();
    if (threadIdx.x < R) {
        int i = threadIdx.x;
        float s0 = part[0][i][0] + part[1][i][0] + bf2v[0];
        float s1 = part[0][i][1] + part[1][i][1] + bf2v[1];
        float m  = fmaxf(s0, s1);
        float e0 = expf(s0 - m), e1 = expf(s1 - m);
        float inv = 1.0f / (e0 + e1);
        attn[i][0] = e0 * inv;
        attn[i][1] = e1 * inv;
    }
    __syncthreads();
#pragma unroll
    for (int i = 0; i < R; i++) {
        int r = r0 + i;
        if (r < B_N) {
            float v = attn[i][0] * sc[i][c] + attn[i][1] * sh[i][c];
            fused16[(size_t)r * HD + c] = __float2bfloat16(v);
        }
    }
}

// 4 predictions per wave, 16 lanes x 16B (int4 of 8 bf16) per row
__global__ void k_score(const int* __restrict__ pu, const int* __restrict__ pb,
                        const bf16* __restrict__ uemb16, const bf16* __restrict__ fused16,
                        float* __restrict__ out) {
    int wid  = (blockIdx.x * blockDim.x + threadIdx.x) >> 6;
    int lane = threadIdx.x & 63;
    int g = lane >> 4;
    int l = lane & 15;
    int p = wid * 4 + g;
    if (p >= NP) return;
    int u = pu[p];
    int b = pb[p];
    int4 av = ((const int4*)(uemb16 + (size_t)u * HD))[l];
    int4 fv = ((const int4*)(fused16 + (size_t)b * HD))[l];
    const int* ap = (const int*)&av;
    const int* fp = (const int*)&fv;
    float s = 0.0f;
#pragma unroll
    for (int i = 0; i < 4; i++) {
        bf162 a2 = *(const bf162*)&ap[i];
        bf162 f2 = *(const bf162*)&fp[i];
        s = fmaf(b2f(a2.x), b2f(f2.x), s);
        s = fmaf(b2f(a2.y), b2f(f2.y), s);
    }
#pragma unroll
    for (int off = 8; off > 0; off >>= 1) s += __shfl_xor(s, off, 64);
    if (l == 0) out[p] = s;
}

extern "C" void kernel_launch(void* const* d_in, const int* in_sizes, int n_in,
                              void* d_out, int out_size, void* d_ws, size_t ws_size,
                              hipStream_t stream) {
    const float* user_x = (const float*)d_in[0];
    const float* book_x = (const float*)d_in[1];
    const int*   ub_src = (const int*)d_in[2];
    const int*   ub_dst = (const int*)d_in[3];
    const int*   bb_src = (const int*)d_in[4];
    const int*   bb_dst = (const int*)d_in[5];
    const int*   pred_u = (const int*)d_in[6];
    const int*   pred_b = (const int*)d_in[7];
    const float* Wu   = (const float*)d_in[8];
    const float* bu   = (const float*)d_in[9];
    const float* Wub  = (const float*)d_in[10];
    const float* bub  = (const float*)d_in[11];
    const float* Wbb  = (const float*)d_in[12];
    const float* bbb  = (const float*)d_in[13];
    const float* Wl1  = (const float*)d_in[14];
    const float* bl1  = (const float*)d_in[15];
    const float* Wr1  = (const float*)d_in[16];
    const float* Wl2  = (const float*)d_in[17];
    const float* bl2  = (const float*)d_in[18];
    const float* Wr2  = (const float*)d_in[19];
    const float* Wf1  = (const float*)d_in[20];
    const float* bf1v = (const float*)d_in[21];
    const float* Wf2  = (const float*)d_in[22];
    const float* bf2v = (const float*)d_in[23];
    float* out = (float*)d_out;

    // ---- workspace layout (4-byte words), total 30.96M words = 123.84 MB ----
    // [0,       560000)   aux: dinv | cnt_ub(dead->content W packs) | rs_ub |
    //                          cnt_bb | rs_bb | bsum
    // [560000, 2160000)   eidx
    // [2160000,11760000)  X016 bf16 N*H        | content: xb16c | h16a | h16b (3.2M words each)
    // [11760000,21360000) X1_16 bf16 N*H       | phase A: xu16 | xb16
    //                                          | content: agg16 | content16 | fused16
    // [21360000,30960000) XF16 bf16 N*H        | phase A head: WuP(4096w) WubP(8192w)
    float* ws = (float*)d_ws;
    const size_t need = 30960000ull * sizeof(float);
    if (ws_size < need) return;

    float* dinv    = ws;
    int*   cnt_ub  = (int*)(ws + 150000);
    int*   rs_ub   = (int*)(ws + 300000);
    int*   cnt_bb  = (int*)(ws + 450000);
    int*   rs_bb   = (int*)(ws + 500000);
    int*   bsum    = (int*)(ws + 550000);
    int*   eidx    = (int*)(ws + 560000);
    bf16*  X016    = (bf16*)(ws + 2160000);
    bf16*  X1_16   = (bf16*)(ws + 11760000);
    bf16*  XF16    = (bf16*)(ws + 21360000);

    // phase A aliases
    short* xu16  = (short*)(ws + 11760000);      // U_N*DU = 6.4M shorts
    short* xb16  = (short*)(ws + 14960000);      // B_N*DB = 6.4M shorts
    short* WuP   = (short*)(ws + 21360000);      // 8192 shorts
    short* WubP  = (short*)(ws + 21364096);      // 16384 shorts

    // content-phase aliases
    short* xb16c     = (short*)(ws + 2160000);
    bf16*  h16a      = (bf16*)(ws + 5360000);
    bf16*  h16b      = (bf16*)(ws + 8560000);
    bf16*  agg16     = (bf16*)(ws + 11760000);
    bf16*  content16 = (bf16*)(ws + 14960000);
    bf16*  fused16   = (bf16*)(ws + 18160000);
    bf16*  uemb16    = XF16;
    bf16*  collab16  = XF16 + (size_t)U_N * HD;
    // content W packs in dead cnt_ub region (needs 81920 shorts = 40960 words <= 150000)
    short* WbbP = (short*)(ws + 150000);
    short* Wl1P = WbbP + 16384;
    short* Wr1P = WbbP + 32768;
    short* Wl2P = WbbP + 49152;
    short* Wr2P = WbbP + 65536;

    hipMemsetAsync(ws + 150000, 0, 350000 * sizeof(float), stream);

    // ---- phase A: bf16 inputs + init weight packs + init GEMMs ----
    k_f2b<<<(U_N * DU / 8 + 255) / 256, 256, 0, stream>>>(user_x, xu16, U_N * DU);
    k_f2b<<<(B_N * DB / 8 + 255) / 256, 256, 0, stream>>>(book_x, xb16, B_N * DB);
    k_pack_w<DU><<<(2 * 8 * 64 + 255) / 256, 256, 0, stream>>>(Wu, WuP);
    k_pack_w<DB><<<(4 * 8 * 64 + 255) / 256, 256, 0, stream>>>(Wub, WubP);
    k_mgemm<2, 0, false><<<(U_N + 63) / 64, 256, 0, stream>>>(
        xu16, WuP, nullptr, nullptr, bu, X016, U_N);
    k_mgemm<4, 0, false><<<(B_N + 63) / 64, 256, 0, stream>>>(
        xb16, WubP, nullptr, nullptr, bub, X016 + (size_t)U_N * HD, B_N);

    // ---- CSR build (ub graph, bidirectional) ----
    k_cnt_ub<<<(NE_UB + 255) / 256, 256, 0, stream>>>(ub_src, ub_dst, cnt_ub);
    k_cnt_bb<<<(NE_BB + 255) / 256, 256, 0, stream>>>(bb_dst, cnt_bb);
    k_dinv<<<(N_TOT + 255) / 256, 256, 0, stream>>>(cnt_ub, dinv);
    {
        int nb = (N_TOT + 1023) / 1024;
        k_scan1<<<nb, 256, 0, stream>>>(cnt_ub, rs_ub, bsum, N_TOT);
        k_scan2<<<1, 256, 0, stream>>>(bsum, nb);
        k_scan3<<<(N_TOT + 255) / 256, 256, 0, stream>>>(rs_ub, bsum, N_TOT);
    }
    k_fill_ub2<<<NBU + NBB, 1024, 0, stream>>>(ub_src, ub_dst, rs_ub, eidx);
    // cnt_ub dead from here: pack content-phase weights into its region
    k_pack_w<DB><<<8, 256, 0, stream>>>(Wbb, WbbP);
    k_pack_w<DB><<<8, 256, 0, stream>>>(Wl1, Wl1P);
    k_pack_w<DB><<<8, 256, 0, stream>>>(Wr1, Wr1P);
    k_pack_w<DB><<<8, 256, 0, stream>>>(Wl2, Wl2P);
    k_pack_w<DB><<<8, 256, 0, stream>>>(Wr2, Wr2P);

    // ---- LightGCN propagation ----
    k_gather1<<<(N_TOT + 3) / 4, 256, 0, stream>>>(rs_ub, eidx, dinv, X016, X1_16);
    k_gather2<<<(N_TOT + 3) / 4, 256, 0, stream>>>(rs_ub, eidx, dinv, X016, X1_16, XF16);

    // ---- CSR build (bb graph) — ub CSR dead ----
    {
        int nb = (B_N + 1023) / 1024;
        k_scan1<<<nb, 256, 0, stream>>>(cnt_bb, rs_bb, bsum, B_N);
        k_scan2<<<1, 256, 0, stream>>>(bsum, nb);
        k_scan3<<<(B_N + 255) / 256, 256, 0, stream>>>(rs_bb, bsum, B_N);
    }
    k_fill_bb2<<<NB2, 1024, 0, stream>>>(bb_src, bb_dst, rs_bb, eidx);

    // ---- content network (all MFMA) ----
    k_f2b<<<(B_N * DB / 8 + 255) / 256, 256, 0, stream>>>(book_x, xb16c, B_N * DB);
    k_mgemm<4, 0, false><<<(B_N + 63) / 64, 256, 0, stream>>>(
        xb16c, WbbP, nullptr, nullptr, bbb, h16a, B_N);
    k_gather_bb<<<(B_N + 3) / 4, 256, 0, stream>>>(rs_bb, eidx, h16a, agg16);
    k_mgemm<4, 4, true><<<(B_N + 63) / 64, 256, 0, stream>>>(
        (const short*)agg16, Wl1P, (const short*)h16a, Wr1P, bl1, h16b, B_N);
    k_gather_bb<<<(B_N + 3) / 4, 256, 0, stream>>>(rs_bb, eidx, h16b, agg16);
    k_mgemm<4, 4, true><<<(B_N + 63) / 64, 256, 0, stream>>>(
        (const short*)agg16, Wl2P, (const short*)h16b, Wr2P, bl2, content16, B_N);

    // ---- fusion + scores ----
    k_fuse<<<(B_N + 3) / 4, 128, 0, stream>>>(collab16, content16,
                                              Wf1, bf1v, Wf2, bf2v, fused16);
    k_score<<<NP / 16, 256, 0, stream>>>(pred_u, pred_b, uemb16, fused16, out);
}

// Round 3
// 915.236 us; speedup vs baseline: 1.3507x; 1.0523x over previous
//
#include <hip/hip_runtime.h>
#include <hip/hip_bf16.h>

typedef __hip_bfloat16 bf16;
typedef __hip_bfloat162 bf162;

using short8 = __attribute__((ext_vector_type(8))) short;
using f32x4  = __attribute__((ext_vector_type(4))) float;

#define U_N   100000
#define B_N   50000
#define N_TOT 150000
#define NE_UB 800000
#define NE_BB 600000
#define NP    400000
#define DU    64
#define DB    128
#define HD    128

// bucketed-fill geometry
#define NBU 128
#define NBB 128
#define UPB ((U_N + NBU - 1) / NBU)
#define BPB ((B_N + NBB - 1) / NBB)
#define NB2 256
#define BPB2 ((B_N + NB2 - 1) / NB2)

__device__ __forceinline__ float b2f(bf16 v) { return __bfloat162float(v); }
__device__ __forceinline__ float2 ldb2(const bf16* row, int lane) {
    bf162 v = ((const bf162*)row)[lane];
    return make_float2(b2f(v.x), b2f(v.y));
}
__device__ __forceinline__ void stb2(bf16* row, int lane, float2 v) {
    bf162 o;
    o.x = __float2bfloat16(v.x);
    o.y = __float2bfloat16(v.y);
    ((bf162*)row)[lane] = o;
}
// f32 -> bf16 bits (RNE)
__device__ __forceinline__ short f2bs(float f) {
    unsigned u = __float_as_uint(f);
    unsigned r = (u + 0x7fffu + ((u >> 16) & 1u)) >> 16;
    return (short)r;
}

// ---------------- bf16 conversion + weight packing ----------------

__global__ void k_f2b(const float* __restrict__ in, short* __restrict__ out, int n) {
    int i = (blockIdx.x * blockDim.x + threadIdx.x) * 8;
    if (i >= n) return;
    float4 a = ((const float4*)(in + i))[0];
    float4 b = ((const float4*)(in + i))[1];
    short8 v;
    v[0] = f2bs(a.x); v[1] = f2bs(a.y); v[2] = f2bs(a.z); v[3] = f2bs(a.w);
    v[4] = f2bs(b.x); v[5] = f2bs(b.y); v[6] = f2bs(b.z); v[7] = f2bs(b.w);
    *(short8*)(out + i) = v;
}

// Pack W[KTOT][128] f32 into MFMA B-fragment order (bf16)
template<int KTOT>
__global__ void k_pack_w(const float* __restrict__ W, short* __restrict__ Wp) {
    int t = blockIdx.x * blockDim.x + threadIdx.x;
    if (t >= (KTOT / 32) * 8 * 64) return;
    int lane = t & 63;
    int n    = (t >> 6) & 7;
    int kk   = t >> 9;
    int lr = lane & 15, lg = lane >> 4;
    short8 v;
#pragma unroll
    for (int j = 0; j < 8; j++) {
        float f = W[(size_t)(kk * 32 + lg * 8 + j) * HD + (n * 16 + lr)];
        v[j] = f2bs(f);
    }
    *(short8*)(Wp + (size_t)t * 8) = v;
}

// ---------------- MFMA GEMM: out = [relu](A1@W1 [+ A2@W2] + bias), bf16 in/out ----
template<int KS1, int KS2, bool RELU>
__global__ __launch_bounds__(256) void k_mgemm(
    const short* __restrict__ A1, const short* __restrict__ Wp1,
    const short* __restrict__ A2, const short* __restrict__ Wp2,
    const float* __restrict__ bias, bf16* __restrict__ out, int nrows) {
    const int wv   = threadIdx.x >> 6;
    const int lane = threadIdx.x & 63;
    const int row0 = blockIdx.x * 64 + wv * 16;
    if (row0 >= nrows) return;
    const int lr = lane & 15, lg = lane >> 4;

    f32x4 acc[8];
#pragma unroll
    for (int n = 0; n < 8; n++) acc[n] = (f32x4){0.f, 0.f, 0.f, 0.f};

    {
        const short* a1p = A1 + (size_t)(row0 + lr) * (KS1 * 32) + lg * 8;
#pragma unroll
        for (int kk = 0; kk < KS1; kk++) {
            short8 af = *(const short8*)(a1p + kk * 32);
            const short* wp = Wp1 + ((size_t)(kk * 8) * 64 + lane) * 8;
#pragma unroll
            for (int n = 0; n < 8; n++) {
                short8 bfr = *(const short8*)(wp + (size_t)n * 64 * 8);
                acc[n] = __builtin_amdgcn_mfma_f32_16x16x32_bf16(af, bfr, acc[n], 0, 0, 0);
            }
        }
    }
    if constexpr (KS2 > 0) {
        const short* a2p = A2 + (size_t)(row0 + lr) * (KS2 * 32) + lg * 8;
#pragma unroll
        for (int kk = 0; kk < KS2; kk++) {
            short8 af = *(const short8*)(a2p + kk * 32);
            const short* wp = Wp2 + ((size_t)(kk * 8) * 64 + lane) * 8;
#pragma unroll
            for (int n = 0; n < 8; n++) {
                short8 bfr = *(const short8*)(wp + (size_t)n * 64 * 8);
                acc[n] = __builtin_amdgcn_mfma_f32_16x16x32_bf16(af, bfr, acc[n], 0, 0, 0);
            }
        }
    }
#pragma unroll
    for (int n = 0; n < 8; n++) {
        int col = n * 16 + lr;
        float bv = bias[col];
#pragma unroll
        for (int r = 0; r < 4; r++) {
            int row = row0 + lg * 4 + r;
            float v = acc[n][r] + bv;
            if (RELU) v = fmaxf(v, 0.0f);
            out[(size_t)row * HD + col] = __float2bfloat16(v);
        }
    }
}

// ---------------- CSR build: count -> scan -> bucketed fill ----------------

__global__ void k_cnt_ub(const int* __restrict__ us, const int* __restrict__ ud,
                         int* __restrict__ cnt) {
    int e = blockIdx.x * blockDim.x + threadIdx.x;
    if (e < NE_UB) {
        atomicAdd(&cnt[us[e]], 1);
        atomicAdd(&cnt[U_N + ud[e]], 1);
    }
}

__global__ void k_cnt_bb(const int* __restrict__ bd, int* __restrict__ cnt) {
    int e = blockIdx.x * blockDim.x + threadIdx.x;
    if (e < NE_BB) atomicAdd(&cnt[bd[e]], 1);
}

__global__ void k_dinv(const int* __restrict__ cnt, float* __restrict__ dinv) {
    int i = blockIdx.x * blockDim.x + threadIdx.x;
    if (i < N_TOT) {
        int d = cnt[i];
        dinv[i] = (d > 0) ? 1.0f / sqrtf((float)d) : 0.0f;
    }
}

__global__ void k_scan1(const int* __restrict__ cnt, int* __restrict__ rs,
                        int* __restrict__ bsum, int n) {
    __shared__ int ts[256];
    const int t = threadIdx.x;
    const int base = blockIdx.x * 1024 + t * 4;
    int v0 = (base + 0 < n) ? cnt[base + 0] : 0;
    int v1 = (base + 1 < n) ? cnt[base + 1] : 0;
    int v2 = (base + 2 < n) ? cnt[base + 2] : 0;
    int v3 = (base + 3 < n) ? cnt[base + 3] : 0;
    int local = v0 + v1 + v2 + v3;
    ts[t] = local;
    __syncthreads();
    for (int off = 1; off < 256; off <<= 1) {
        int x = (t >= off) ? ts[t - off] : 0;
        __syncthreads();
        ts[t] += x;
        __syncthreads();
    }
    int ex = ts[t] - local;
    if (base + 0 < n) rs[base + 0] = ex;
    if (base + 1 < n) rs[base + 1] = ex + v0;
    if (base + 2 < n) rs[base + 2] = ex + v0 + v1;
    if (base + 3 < n) rs[base + 3] = ex + v0 + v1 + v2;
    if (t == 0) bsum[blockIdx.x] = ts[255];
}

__global__ void k_scan2(int* __restrict__ bsum, int nb) {
    __shared__ int ts[256];
    const int t = threadIdx.x;
    const int base = t * 4;
    int v0 = (base + 0 < nb) ? bsum[base + 0] : 0;
    int v1 = (base + 1 < nb) ? bsum[base + 1] : 0;
    int v2 = (base + 2 < nb) ? bsum[base + 2] : 0;
    int v3 = (base + 3 < nb) ? bsum[base + 3] : 0;
    int local = v0 + v1 + v2 + v3;
    ts[t] = local;
    __syncthreads();
    for (int off = 1; off < 256; off <<= 1) {
        int x = (t >= off) ? ts[t - off] : 0;
        __syncthreads();
        ts[t] += x;
        __syncthreads();
    }
    int ex = ts[t] - local;
    if (base + 0 < nb) bsum[base + 0] = ex;
    if (base + 1 < nb) bsum[base + 1] = ex + v0;
    if (base + 2 < nb) bsum[base + 2] = ex + v0 + v1;
    if (base + 3 < nb) bsum[base + 3] = ex + v0 + v1 + v2;
}

__global__ void k_scan3(int* __restrict__ rs, const int* __restrict__ bsum, int n) {
    int i = blockIdx.x * blockDim.x + threadIdx.x;
    if (i < n) rs[i] += bsum[i >> 10];
}

// Bucketed fill, v3: stream key AND value arrays coalesced (int4 pairs) so the
// match-branch body is only {LDS atomic + store} — the scattered value load
// (200-400cy L2 latency, unhideable at 16 waves/CU) is gone from the chain.
__global__ __launch_bounds__(1024) void k_fill_ub3(const int* __restrict__ us,
                                                   const int* __restrict__ ud,
                                                   const int* __restrict__ rs,
                                                   int* __restrict__ eidx) {
    __shared__ int cur[UPB];
    const bool userSide = blockIdx.x < NBU;
    int node0, nn, rbase, add;
    const int *keys, *vals;
    if (userSide) {
        node0 = blockIdx.x * UPB;
        nn    = min(UPB, U_N - node0);
        rbase = node0;
        keys  = us;
        vals  = ud;
        add   = U_N;
    } else {
        int b = blockIdx.x - NBU;
        node0 = b * BPB;
        nn    = min(BPB, B_N - node0);
        rbase = U_N + node0;
        keys  = ud;
        vals  = us;
        add   = 0;
    }
    for (int i = threadIdx.x; i < nn; i += 1024) cur[i] = rs[rbase + i];
    __syncthreads();
    const int4* k4 = (const int4*)keys;
    const int4* v4 = (const int4*)vals;
    for (int q = threadIdx.x; q < NE_UB / 4; q += 1024) {
        int4 kv = k4[q];
        int4 vv = v4[q];
        int ka[4] = {kv.x, kv.y, kv.z, kv.w};
        int va[4] = {vv.x, vv.y, vv.z, vv.w};
#pragma unroll
        for (int i = 0; i < 4; i++) {
            unsigned rel = (unsigned)(ka[i] - node0);
            if (rel < (unsigned)nn) {
                int p = atomicAdd(&cur[rel], 1);
                eidx[p] = va[i] + add;
            }
        }
    }
}

__global__ __launch_bounds__(1024) void k_fill_bb3(const int* __restrict__ bs,
                                                   const int* __restrict__ bd,
                                                   const int* __restrict__ rs,
                                                   int* __restrict__ eidx) {
    __shared__ int cur[BPB2];
    const int node0 = blockIdx.x * BPB2;
    const int nn    = min(BPB2, B_N - node0);
    for (int i = threadIdx.x; i < nn; i += 1024) cur[i] = rs[node0 + i];
    __syncthreads();
    const int4* k4 = (const int4*)bd;
    const int4* v4 = (const int4*)bs;
    for (int q = threadIdx.x; q < NE_BB / 4; q += 1024) {
        int4 kv = k4[q];
        int4 vv = v4[q];
        int ka[4] = {kv.x, kv.y, kv.z, kv.w};
        int va[4] = {vv.x, vv.y, vv.z, vv.w};
#pragma unroll
        for (int i = 0; i < 4; i++) {
            unsigned rel = (unsigned)(ka[i] - node0);
            if (rel < (unsigned)nn) {
                int p = atomicAdd(&cur[rel], 1);
                eidx[p] = va[i];
            }
        }
    }
}

// ---------------- pull-mode propagation (bf16 tables, f32 accumulate) ----------------

__global__ void k_gather1(const int* __restrict__ rs, const int* __restrict__ eidx,
                          const float* __restrict__ dinv,
                          const bf16* __restrict__ x016, bf16* __restrict__ x116) {
    int w    = (blockIdx.x * blockDim.x + threadIdx.x) >> 6;
    int lane = threadIdx.x & 63;
    if (w >= N_TOT) return;
    int s = rs[w];
    int e = (w == N_TOT - 1) ? (2 * NE_UB) : rs[w + 1];
    s = __builtin_amdgcn_readfirstlane(s);
    e = __builtin_amdgcn_readfirstlane(e);
    float nd = dinv[w];
    float2 acc = make_float2(0.0f, 0.0f);
    for (int j = s; j < e; ++j) {
        int nb = eidx[j];
        float wgt = nd * dinv[nb];
        float2 v = ldb2(x016 + (size_t)nb * HD, lane);
        acc.x = fmaf(v.x, wgt, acc.x);
        acc.y = fmaf(v.y, wgt, acc.y);
    }
    stb2(x116 + (size_t)w * HD, lane, acc);
}

__global__ void k_gather2(const int* __restrict__ rs, const int* __restrict__ eidx,
                          const float* __restrict__ dinv,
                          const bf16* __restrict__ x016, const bf16* __restrict__ x116,
                          bf16* __restrict__ xf16) {
    int w    = (blockIdx.x * blockDim.x + threadIdx.x) >> 6;
    int lane = threadIdx.x & 63;
    if (w >= N_TOT) return;
    int s = rs[w];
    int e = (w == N_TOT - 1) ? (2 * NE_UB) : rs[w + 1];
    s = __builtin_amdgcn_readfirstlane(s);
    e = __builtin_amdgcn_readfirstlane(e);
    float nd = dinv[w];
    float2 acc = make_float2(0.0f, 0.0f);
    for (int j = s; j < e; ++j) {
        int nb = eidx[j];
        float wgt = nd * dinv[nb];
        float2 v = ldb2(x116 + (size_t)nb * HD, lane);
        acc.x = fmaf(v.x, wgt, acc.x);
        acc.y = fmaf(v.y, wgt, acc.y);
    }
    float2 a = ldb2(x016 + (size_t)w * HD, lane);
    float2 b = ldb2(x116 + (size_t)w * HD, lane);
    acc.x = (acc.x + a.x + b.x) * (1.0f / 3.0f);
    acc.y = (acc.y + a.y + b.y) * (1.0f / 3.0f);
    stb2(xf16 + (size_t)w * HD, lane, acc);
}

// agg[w] = (sum_nb h16[nb]) / max(deg,1)   (bf16 in, bf16 out)
__global__ void k_gather_bb(const int* __restrict__ rs, const int* __restrict__ eidx,
                            const bf16* __restrict__ h16, bf16* __restrict__ agg16) {
    int w    = (blockIdx.x * blockDim.x + threadIdx.x) >> 6;
    int lane = threadIdx.x & 63;
    if (w >= B_N) return;
    int s = rs[w];
    int e = (w == B_N - 1) ? NE_BB : rs[w + 1];
    s = __builtin_amdgcn_readfirstlane(s);
    e = __builtin_amdgcn_readfirstlane(e);
    float2 acc = make_float2(0.0f, 0.0f);
    for (int j = s; j < e; ++j) {
        int nb = eidx[j];
        float2 v = ldb2(h16 + (size_t)nb * HD, lane);
        acc.x += v.x;
        acc.y += v.y;
    }
    float inv = 1.0f / fmaxf((float)(e - s), 1.0f);
    acc.x *= inv;
    acc.y *= inv;
    stb2(agg16 + (size_t)w * HD, lane, acc);
}

// attention fusion head, 4 rows per 128-thread block (2 waves); bf16 in/out
__global__ void k_fuse(const bf16* __restrict__ collab16, const bf16* __restrict__ content16,
                       const float* __restrict__ Wf1, const float* __restrict__ bf1v,
                       const float* __restrict__ Wf2, const float* __restrict__ bf2v,
                       bf16* __restrict__ fused16) {
    const int R = 4;
    __shared__ float sc[R][HD];
    __shared__ float sh[R][HD];
    __shared__ float part[2][R][2];
    __shared__ float attn[R][2];
    const int c  = threadIdx.x;
    const int r0 = blockIdx.x * R;
#pragma unroll
    for (int i = 0; i < R; i++) {
        int r = r0 + i;
        sc[i][c] = (r < B_N) ? b2f(collab16[(size_t)r * HD + c]) : 0.0f;
        sh[i][c] = (r < B_N) ? b2f(content16[(size_t)r * HD + c]) : 0.0f;
    }
    __syncthreads();
    float t[R];
#pragma unroll
    for (int i = 0; i < R; i++) t[i] = 0.0f;
    for (int k = 0; k < HD; k++) {
        float w = Wf1[k * HD + c];
#pragma unroll
        for (int i = 0; i < R; i++) t[i] = fmaf(sc[i][k], w, t[i]);
    }
    for (int k = 0; k < HD; k++) {
        float w = Wf1[(size_t)(HD + k) * HD + c];
#pragma unroll
        for (int i = 0; i < R; i++) t[i] = fmaf(sh[i][k], w, t[i]);
    }
    float b1  = bf1v[c];
    float w20 = Wf2[c * 2 + 0];
    float w21 = Wf2[c * 2 + 1];
    float p0[R], p1[R];
#pragma unroll
    for (int i = 0; i < R; i++) {
        float tv = fmaxf(t[i] + b1, 0.0f);
        p0[i] = tv * w20;
        p1[i] = tv * w21;
    }
#pragma unroll
    for (int i = 0; i < R; i++) {
        for (int off = 32; off > 0; off >>= 1) {
            p0[i] += __shfl_down(p0[i], off, 64);
            p1[i] += __shfl_down(p1[i], off, 64);
        }
    }
    int wv   = threadIdx.x >> 6;
    int lane = threadIdx.x & 63;
    if (lane == 0) {
#pragma unroll
        for (int i = 0; i < R; i++) { part[wv][i][0] = p0[i]; part[wv][i][1] = p1[i]; }
    }
    __syncthreads();
    if (threadIdx.x < R) {
        int i = threadIdx.x;
        float s0 = part[0][i][0] + part[1][i][0] + bf2v[0];
        float s1 = part[0][i][1] + part[1][i][1] + bf2v[1];
        float m  = fmaxf(s0, s1);
        float e0 = expf(s0 - m), e1 = expf(s1 - m);
        float inv = 1.0f / (e0 + e1);
        attn[i][0] = e0 * inv;
        attn[i][1] = e1 * inv;
    }
    __syncthreads();
#pragma unroll
    for (int i = 0; i < R; i++) {
        int r = r0 + i;
        if (r < B_N) {
            float v = attn[i][0] * sc[i][c] + attn[i][1] * sh[i][c];
            fused16[(size_t)r * HD + c] = __float2bfloat16(v);
        }
    }
}

// 4 predictions per wave, 16 lanes x 16B (int4 of 8 bf16) per row
__global__ void k_score(const int* __restrict__ pu, const int* __restrict__ pb,
                        const bf16* __restrict__ uemb16, const bf16* __restrict__ fused16,
                        float* __restrict__ out) {
    int wid  = (blockIdx.x * blockDim.x + threadIdx.x) >> 6;
    int lane = threadIdx.x & 63;
    int g = lane >> 4;
    int l = lane & 15;
    int p = wid * 4 + g;
    if (p >= NP) return;
    int u = pu[p];
    int b = pb[p];
    int4 av = ((const int4*)(uemb16 + (size_t)u * HD))[l];
    int4 fv = ((const int4*)(fused16 + (size_t)b * HD))[l];
    const int* ap = (const int*)&av;
    const int* fp = (const int*)&fv;
    float s = 0.0f;
#pragma unroll
    for (int i = 0; i < 4; i++) {
        bf162 a2 = *(const bf162*)&ap[i];
        bf162 f2 = *(const bf162*)&fp[i];
        s = fmaf(b2f(a2.x), b2f(f2.x), s);
        s = fmaf(b2f(a2.y), b2f(f2.y), s);
    }
#pragma unroll
    for (int off = 8; off > 0; off >>= 1) s += __shfl_xor(s, off, 64);
    if (l == 0) out[p] = s;
}

extern "C" void kernel_launch(void* const* d_in, const int* in_sizes, int n_in,
                              void* d_out, int out_size, void* d_ws, size_t ws_size,
                              hipStream_t stream) {
    const float* user_x = (const float*)d_in[0];
    const float* book_x = (const float*)d_in[1];
    const int*   ub_src = (const int*)d_in[2];
    const int*   ub_dst = (const int*)d_in[3];
    const int*   bb_src = (const int*)d_in[4];
    const int*   bb_dst = (const int*)d_in[5];
    const int*   pred_u = (const int*)d_in[6];
    const int*   pred_b = (const int*)d_in[7];
    const float* Wu   = (const float*)d_in[8];
    const float* bu   = (const float*)d_in[9];
    const float* Wub  = (const float*)d_in[10];
    const float* bub  = (const float*)d_in[11];
    const float* Wbb  = (const float*)d_in[12];
    const float* bbb  = (const float*)d_in[13];
    const float* Wl1  = (const float*)d_in[14];
    const float* bl1  = (const float*)d_in[15];
    const float* Wr1  = (const float*)d_in[16];
    const float* Wl2  = (const float*)d_in[17];
    const float* bl2  = (const float*)d_in[18];
    const float* Wr2  = (const float*)d_in[19];
    const float* Wf1  = (const float*)d_in[20];
    const float* bf1v = (const float*)d_in[21];
    const float* Wf2  = (const float*)d_in[22];
    const float* bf2v = (const float*)d_in[23];
    float* out = (float*)d_out;

    // ---- workspace layout (4-byte words), total 30.96M words = 123.84 MB ----
    float* ws = (float*)d_ws;
    const size_t need = 30960000ull * sizeof(float);
    if (ws_size < need) return;

    float* dinv    = ws;
    int*   cnt_ub  = (int*)(ws + 150000);
    int*   rs_ub   = (int*)(ws + 300000);
    int*   cnt_bb  = (int*)(ws + 450000);
    int*   rs_bb   = (int*)(ws + 500000);
    int*   bsum    = (int*)(ws + 550000);
    int*   eidx    = (int*)(ws + 560000);
    bf16*  X016    = (bf16*)(ws + 2160000);
    bf16*  X1_16   = (bf16*)(ws + 11760000);
    bf16*  XF16    = (bf16*)(ws + 21360000);

    // phase A aliases
    short* xu16  = (short*)(ws + 11760000);
    short* xb16  = (short*)(ws + 14960000);
    short* WuP   = (short*)(ws + 21360000);
    short* WubP  = (short*)(ws + 21364096);

    // content-phase aliases
    short* xb16c     = (short*)(ws + 2160000);
    bf16*  h16a      = (bf16*)(ws + 5360000);
    bf16*  h16b      = (bf16*)(ws + 8560000);
    bf16*  agg16     = (bf16*)(ws + 11760000);
    bf16*  content16 = (bf16*)(ws + 14960000);
    bf16*  fused16   = (bf16*)(ws + 18160000);
    bf16*  uemb16    = XF16;
    bf16*  collab16  = XF16 + (size_t)U_N * HD;
    short* WbbP = (short*)(ws + 150000);
    short* Wl1P = WbbP + 16384;
    short* Wr1P = WbbP + 32768;
    short* Wl2P = WbbP + 49152;
    short* Wr2P = WbbP + 65536;

    hipMemsetAsync(ws + 150000, 0, 350000 * sizeof(float), stream);

    // ---- phase A: bf16 inputs + init weight packs + init GEMMs ----
    k_f2b<<<(U_N * DU / 8 + 255) / 256, 256, 0, stream>>>(user_x, xu16, U_N * DU);
    k_f2b<<<(B_N * DB / 8 + 255) / 256, 256, 0, stream>>>(book_x, xb16, B_N * DB);
    k_pack_w<DU><<<(2 * 8 * 64 + 255) / 256, 256, 0, stream>>>(Wu, WuP);
    k_pack_w<DB><<<(4 * 8 * 64 + 255) / 256, 256, 0, stream>>>(Wub, WubP);
    k_mgemm<2, 0, false><<<(U_N + 63) / 64, 256, 0, stream>>>(
        xu16, WuP, nullptr, nullptr, bu, X016, U_N);
    k_mgemm<4, 0, false><<<(B_N + 63) / 64, 256, 0, stream>>>(
        xb16, WubP, nullptr, nullptr, bub, X016 + (size_t)U_N * HD, B_N);

    // ---- CSR build (ub graph, bidirectional) ----
    k_cnt_ub<<<(NE_UB + 255) / 256, 256, 0, stream>>>(ub_src, ub_dst, cnt_ub);
    k_cnt_bb<<<(NE_BB + 255) / 256, 256, 0, stream>>>(bb_dst, cnt_bb);
    k_dinv<<<(N_TOT + 255) / 256, 256, 0, stream>>>(cnt_ub, dinv);
    {
        int nb = (N_TOT + 1023) / 1024;
        k_scan1<<<nb, 256, 0, stream>>>(cnt_ub, rs_ub, bsum, N_TOT);
        k_scan2<<<1, 256, 0, stream>>>(bsum, nb);
        k_scan3<<<(N_TOT + 255) / 256, 256, 0, stream>>>(rs_ub, bsum, N_TOT);
    }
    k_fill_ub3<<<NBU + NBB, 1024, 0, stream>>>(ub_src, ub_dst, rs_ub, eidx);
    // cnt_ub dead from here: pack content-phase weights into its region
    k_pack_w<DB><<<8, 256, 0, stream>>>(Wbb, WbbP);
    k_pack_w<DB><<<8, 256, 0, stream>>>(Wl1, Wl1P);
    k_pack_w<DB><<<8, 256, 0, stream>>>(Wr1, Wr1P);
    k_pack_w<DB><<<8, 256, 0, stream>>>(Wl2, Wl2P);
    k_pack_w<DB><<<8, 256, 0, stream>>>(Wr2, Wr2P);

    // ---- LightGCN propagation ----
    k_gather1<<<(N_TOT + 3) / 4, 256, 0, stream>>>(rs_ub, eidx, dinv, X016, X1_16);
    k_gather2<<<(N_TOT + 3) / 4, 256, 0, stream>>>(rs_ub, eidx, dinv, X016, X1_16, XF16);

    // ---- CSR build (bb graph) — ub CSR dead ----
    {
        int nb = (B_N + 1023) / 1024;
        k_scan1<<<nb, 256, 0, stream>>>(cnt_bb, rs_bb, bsum, B_N);
        k_scan2<<<1, 256, 0, stream>>>(bsum, nb);
        k_scan3<<<(B_N + 255) / 256, 256, 0, stream>>>(rs_bb, bsum, B_N);
    }
    k_fill_bb3<<<NB2, 1024, 0, stream>>>(bb_src, bb_dst, rs_bb, eidx);

    // ---- content network (all MFMA) ----
    k_f2b<<<(B_N * DB / 8 + 255) / 256, 256, 0, stream>>>(book_x, xb16c, B_N * DB);
    k_mgemm<4, 0, false><<<(B_N + 63) / 64, 256, 0, stream>>>(
        xb16c, WbbP, nullptr, nullptr, bbb, h16a, B_N);
    k_gather_bb<<<(B_N + 3) / 4, 256, 0, stream>>>(rs_bb, eidx, h16a, agg16);
    k_mgemm<4, 4, true><<<(B_N + 63) / 64, 256, 0, stream>>>(
        (const short*)agg16, Wl1P, (const short*)h16a, Wr1P, bl1, h16b, B_N);
    k_gather_bb<<<(B_N + 3) / 4, 256, 0, stream>>>(rs_bb, eidx, h16b, agg16);
    k_mgemm<4, 4, true><<<(B_N + 63) / 64, 256, 0, stream>>>(
        (const short*)agg16, Wl2P, (const short*)h16b, Wr2P, bl2, content16, B_N);

    // ---- fusion + scores ----
    k_fuse<<<(B_N + 3) / 4, 128, 0, stream>>>(collab16, content16,
                                              Wf1, bf1v, Wf2, bf2v, fused16);
    k_score<<<NP / 16, 256, 0, stream>>>(pred_u, pred_b, uemb16, fused16, out);
}

// Round 4
// 846.132 us; speedup vs baseline: 1.4610x; 1.0817x over previous
//
#include <hip/hip_runtime.h>
#include <hip/hip_bf16.h>

typedef __hip_bfloat16 bf16;
typedef __hip_bfloat162 bf162;

using short8 = __attribute__((ext_vector_type(8))) short;
using f32x4  = __attribute__((ext_vector_type(4))) float;

#define U_N   100000
#define B_N   50000
#define N_TOT 150000
#define NE_UB 800000
#define NE_BB 600000
#define NP    400000
#define DU    64
#define DB    128
#define HD    128

// bucketed-fill geometry
#define NBU 128
#define NBB 128
#define UPB ((U_N + NBU - 1) / NBU)
#define BPB ((B_N + NBB - 1) / NBB)
#define NB2 256
#define BPB2 ((B_N + NB2 - 1) / NB2)

__device__ __forceinline__ float b2f(bf16 v) { return __bfloat162float(v); }
__device__ __forceinline__ float2 ldb2(const bf16* row, int lane) {
    bf162 v = ((const bf162*)row)[lane];
    return make_float2(b2f(v.x), b2f(v.y));
}
// f32 -> bf16 bits (RNE)
__device__ __forceinline__ short f2bs(float f) {
    unsigned u = __float_as_uint(f);
    unsigned r = (u + 0x7fffu + ((u >> 16) & 1u)) >> 16;
    return (short)r;
}
// add 8 bf16 (packed in int4) into acc[8] (bf16->f32 = shift<<16, no cvt needed)
__device__ __forceinline__ void add8(float (&a)[8], int4 rv) {
    const unsigned* p = (const unsigned*)&rv;
#pragma unroll
    for (int i = 0; i < 4; i++) {
        unsigned v = p[i];
        a[2 * i]     += __uint_as_float(v << 16);
        a[2 * i + 1] += __uint_as_float(v & 0xffff0000u);
    }
}
__device__ __forceinline__ void unp8(int4 rv, float (&o)[8]) {
    const unsigned* p = (const unsigned*)&rv;
#pragma unroll
    for (int i = 0; i < 4; i++) {
        unsigned v = p[i];
        o[2 * i]     = __uint_as_float(v << 16);
        o[2 * i + 1] = __uint_as_float(v & 0xffff0000u);
    }
}
__device__ __forceinline__ int4 pack8bf(const float (&a)[8]) {
    unsigned r[4];
#pragma unroll
    for (int i = 0; i < 4; i++) {
        unsigned lo = (unsigned)(unsigned short)f2bs(a[2 * i]);
        unsigned hi = (unsigned)(unsigned short)f2bs(a[2 * i + 1]);
        r[i] = lo | (hi << 16);
    }
    int4 o; o.x = r[0]; o.y = r[1]; o.z = r[2]; o.w = r[3];
    return o;
}
// cross-group (16-lane groups) reduce over group bits 4,5
__device__ __forceinline__ void xgred(float (&a)[8]) {
#pragma unroll
    for (int i = 0; i < 8; i++) {
        a[i] += __shfl_xor(a[i], 16, 64);
        a[i] += __shfl_xor(a[i], 32, 64);
    }
}

// ---------------- bf16 conversion + weight packing ----------------

__global__ void k_f2b(const float* __restrict__ in, short* __restrict__ out, int n) {
    int i = (blockIdx.x * blockDim.x + threadIdx.x) * 8;
    if (i >= n) return;
    float4 a = ((const float4*)(in + i))[0];
    float4 b = ((const float4*)(in + i))[1];
    short8 v;
    v[0] = f2bs(a.x); v[1] = f2bs(a.y); v[2] = f2bs(a.z); v[3] = f2bs(a.w);
    v[4] = f2bs(b.x); v[5] = f2bs(b.y); v[6] = f2bs(b.z); v[7] = f2bs(b.w);
    *(short8*)(out + i) = v;
}

// Pack W[KTOT][128] f32 into MFMA B-fragment order (bf16)
template<int KTOT>
__global__ void k_pack_w(const float* __restrict__ W, short* __restrict__ Wp) {
    int t = blockIdx.x * blockDim.x + threadIdx.x;
    if (t >= (KTOT / 32) * 8 * 64) return;
    int lane = t & 63;
    int n    = (t >> 6) & 7;
    int kk   = t >> 9;
    int lr = lane & 15, lg = lane >> 4;
    short8 v;
#pragma unroll
    for (int j = 0; j < 8; j++) {
        float f = W[(size_t)(kk * 32 + lg * 8 + j) * HD + (n * 16 + lr)];
        v[j] = f2bs(f);
    }
    *(short8*)(Wp + (size_t)t * 8) = v;
}

// ---------------- MFMA GEMM: out = [relu](A1@W1 [+ A2@W2] + bias) [* scale] ----
template<int KS1, int KS2, bool RELU>
__global__ __launch_bounds__(256) void k_mgemm(
    const short* __restrict__ A1, const short* __restrict__ Wp1,
    const short* __restrict__ A2, const short* __restrict__ Wp2,
    const float* __restrict__ bias, const float* __restrict__ scale,
    bf16* __restrict__ out, int nrows) {
    const int wv   = threadIdx.x >> 6;
    const int lane = threadIdx.x & 63;
    const int row0 = blockIdx.x * 64 + wv * 16;
    if (row0 >= nrows) return;
    const int lr = lane & 15, lg = lane >> 4;

    f32x4 acc[8];
#pragma unroll
    for (int n = 0; n < 8; n++) acc[n] = (f32x4){0.f, 0.f, 0.f, 0.f};

    {
        const short* a1p = A1 + (size_t)(row0 + lr) * (KS1 * 32) + lg * 8;
#pragma unroll
        for (int kk = 0; kk < KS1; kk++) {
            short8 af = *(const short8*)(a1p + kk * 32);
            const short* wp = Wp1 + ((size_t)(kk * 8) * 64 + lane) * 8;
#pragma unroll
            for (int n = 0; n < 8; n++) {
                short8 bfr = *(const short8*)(wp + (size_t)n * 64 * 8);
                acc[n] = __builtin_amdgcn_mfma_f32_16x16x32_bf16(af, bfr, acc[n], 0, 0, 0);
            }
        }
    }
    if constexpr (KS2 > 0) {
        const short* a2p = A2 + (size_t)(row0 + lr) * (KS2 * 32) + lg * 8;
#pragma unroll
        for (int kk = 0; kk < KS2; kk++) {
            short8 af = *(const short8*)(a2p + kk * 32);
            const short* wp = Wp2 + ((size_t)(kk * 8) * 64 + lane) * 8;
#pragma unroll
            for (int n = 0; n < 8; n++) {
                short8 bfr = *(const short8*)(wp + (size_t)n * 64 * 8);
                acc[n] = __builtin_amdgcn_mfma_f32_16x16x32_bf16(af, bfr, acc[n], 0, 0, 0);
            }
        }
    }
    float scr[4] = {1.f, 1.f, 1.f, 1.f};
    if (scale) {
#pragma unroll
        for (int r = 0; r < 4; r++) scr[r] = scale[row0 + lg * 4 + r];
    }
#pragma unroll
    for (int n = 0; n < 8; n++) {
        int col = n * 16 + lr;
        float bv = bias[col];
#pragma unroll
        for (int r = 0; r < 4; r++) {
            int row = row0 + lg * 4 + r;
            float v = acc[n][r] + bv;
            if (RELU) v = fmaxf(v, 0.0f);
            v *= scr[r];
            out[(size_t)row * HD + col] = __float2bfloat16(v);
        }
    }
}

// ---------------- CSR build: count -> scan -> bucketed fill ----------------

__global__ void k_cnt_ub(const int* __restrict__ us, const int* __restrict__ ud,
                         int* __restrict__ cnt) {
    int e = blockIdx.x * blockDim.x + threadIdx.x;
    if (e < NE_UB) {
        atomicAdd(&cnt[us[e]], 1);
        atomicAdd(&cnt[U_N + ud[e]], 1);
    }
}

__global__ void k_cnt_bb(const int* __restrict__ bd, int* __restrict__ cnt) {
    int e = blockIdx.x * blockDim.x + threadIdx.x;
    if (e < NE_BB) atomicAdd(&cnt[bd[e]], 1);
}

// dsc[i] = 1/sqrt(max(deg,1))  (== dinv on every edge endpoint; ==1 for deg-0)
__global__ void k_dinv(const int* __restrict__ cnt, float* __restrict__ dsc) {
    int i = blockIdx.x * blockDim.x + threadIdx.x;
    if (i < N_TOT) {
        int d = cnt[i];
        dsc[i] = 1.0f / sqrtf((float)max(d, 1));
    }
}

__global__ void k_scan1(const int* __restrict__ cnt, int* __restrict__ rs,
                        int* __restrict__ bsum, int n) {
    __shared__ int ts[256];
    const int t = threadIdx.x;
    const int base = blockIdx.x * 1024 + t * 4;
    int v0 = (base + 0 < n) ? cnt[base + 0] : 0;
    int v1 = (base + 1 < n) ? cnt[base + 1] : 0;
    int v2 = (base + 2 < n) ? cnt[base + 2] : 0;
    int v3 = (base + 3 < n) ? cnt[base + 3] : 0;
    int local = v0 + v1 + v2 + v3;
    ts[t] = local;
    __syncthreads();
    for (int off = 1; off < 256; off <<= 1) {
        int x = (t >= off) ? ts[t - off] : 0;
        __syncthreads();
        ts[t] += x;
        __syncthreads();
    }
    int ex = ts[t] - local;
    if (base + 0 < n) rs[base + 0] = ex;
    if (base + 1 < n) rs[base + 1] = ex + v0;
    if (base + 2 < n) rs[base + 2] = ex + v0 + v1;
    if (base + 3 < n) rs[base + 3] = ex + v0 + v1 + v2;
    if (t == 0) bsum[blockIdx.x] = ts[255];
}

__global__ void k_scan2(int* __restrict__ bsum, int nb) {
    __shared__ int ts[256];
    const int t = threadIdx.x;
    const int base = t * 4;
    int v0 = (base + 0 < nb) ? bsum[base + 0] : 0;
    int v1 = (base + 1 < nb) ? bsum[base + 1] : 0;
    int v2 = (base + 2 < nb) ? bsum[base + 2] : 0;
    int v3 = (base + 3 < nb) ? bsum[base + 3] : 0;
    int local = v0 + v1 + v2 + v3;
    ts[t] = local;
    __syncthreads();
    for (int off = 1; off < 256; off <<= 1) {
        int x = (t >= off) ? ts[t - off] : 0;
        __syncthreads();
        ts[t] += x;
        __syncthreads();
    }
    int ex = ts[t] - local;
    if (base + 0 < nb) bsum[base + 0] = ex;
    if (base + 1 < nb) bsum[base + 1] = ex + v0;
    if (base + 2 < nb) bsum[base + 2] = ex + v0 + v1;
    if (base + 3 < nb) bsum[base + 3] = ex + v0 + v1 + v2;
}

__global__ void k_scan3(int* __restrict__ rs, const int* __restrict__ bsum, int n) {
    int i = blockIdx.x * blockDim.x + threadIdx.x;
    if (i < n) rs[i] += bsum[i >> 10];
}

// Bucketed fill: stream key AND value arrays coalesced; branch body is only
// {LDS atomic + packed store}. rs not mutated (exclusive prefix).
__global__ __launch_bounds__(1024) void k_fill_ub3(const int* __restrict__ us,
                                                   const int* __restrict__ ud,
                                                   const int* __restrict__ rs,
                                                   int* __restrict__ eidx) {
    __shared__ int cur[UPB];
    const bool userSide = blockIdx.x < NBU;
    int node0, nn, rbase, add;
    const int *keys, *vals;
    if (userSide) {
        node0 = blockIdx.x * UPB;
        nn    = min(UPB, U_N - node0);
        rbase = node0;
        keys  = us;
        vals  = ud;
        add   = U_N;
    } else {
        int b = blockIdx.x - NBU;
        node0 = b * BPB;
        nn    = min(BPB, B_N - node0);
        rbase = U_N + node0;
        keys  = ud;
        vals  = us;
        add   = 0;
    }
    for (int i = threadIdx.x; i < nn; i += 1024) cur[i] = rs[rbase + i];
    __syncthreads();
    const int4* k4 = (const int4*)keys;
    const int4* v4 = (const int4*)vals;
    for (int q = threadIdx.x; q < NE_UB / 4; q += 1024) {
        int4 kv = k4[q];
        int4 vv = v4[q];
        int ka[4] = {kv.x, kv.y, kv.z, kv.w};
        int va[4] = {vv.x, vv.y, vv.z, vv.w};
#pragma unroll
        for (int i = 0; i < 4; i++) {
            unsigned rel = (unsigned)(ka[i] - node0);
            if (rel < (unsigned)nn) {
                int p = atomicAdd(&cur[rel], 1);
                eidx[p] = va[i] + add;
            }
        }
    }
}

__global__ __launch_bounds__(1024) void k_fill_bb3(const int* __restrict__ bs,
                                                   const int* __restrict__ bd,
                                                   const int* __restrict__ rs,
                                                   int* __restrict__ eidx) {
    __shared__ int cur[BPB2];
    const int node0 = blockIdx.x * BPB2;
    const int nn    = min(BPB2, B_N - node0);
    for (int i = threadIdx.x; i < nn; i += 1024) cur[i] = rs[node0 + i];
    __syncthreads();
    const int4* k4 = (const int4*)bd;
    const int4* v4 = (const int4*)bs;
    for (int q = threadIdx.x; q < NE_BB / 4; q += 1024) {
        int4 kv = k4[q];
        int4 vv = v4[q];
        int ka[4] = {kv.x, kv.y, kv.z, kv.w};
        int va[4] = {vv.x, vv.y, vv.z, vv.w};
#pragma unroll
        for (int i = 0; i < 4; i++) {
            unsigned rel = (unsigned)(ka[i] - node0);
            if (rel < (unsigned)nn) {
                int p = atomicAdd(&cur[rel], 1);
                eidx[p] = va[i];
            }
        }
    }
}

// ---------------- pull-mode propagation ----------------
// Tables are degree-pre-scaled (x0s = x0*dsc, x1s = x1*dsc), so edge loops are
// pure row sums: chain is eidx -> row. Wave = 4 edges/iter (4 groups x 16 lanes
// x 16B), cross-group shuffle-reduce at the end.

// x1s[w] = dsc[w]^2 * sum_nb x0s[nb]
__global__ void k_gather1(const int* __restrict__ rs, const int* __restrict__ eidx,
                          const float* __restrict__ dsc,
                          const bf16* __restrict__ x0s, bf16* __restrict__ x1s) {
    int w    = (blockIdx.x * blockDim.x + threadIdx.x) >> 6;
    int lane = threadIdx.x & 63;
    if (w >= N_TOT) return;
    int g = lane >> 4, l = lane & 15;
    int s = rs[w];
    int e = (w == N_TOT - 1) ? (2 * NE_UB) : rs[w + 1];
    s = __builtin_amdgcn_readfirstlane(s);
    e = __builtin_amdgcn_readfirstlane(e);
    float acc[8] = {0.f, 0.f, 0.f, 0.f, 0.f, 0.f, 0.f, 0.f};
    for (int j0 = s; j0 < e; j0 += 4) {
        int j = j0 + g;
        if (j < e) {
            int nb = eidx[j];
            int4 rv = ((const int4*)(x0s + (size_t)nb * HD))[l];
            add8(acc, rv);
        }
    }
    xgred(acc);
    if (g == 0) {
        float nd = dsc[w];
        float s2 = nd * nd;
#pragma unroll
        for (int i = 0; i < 8; i++) acc[i] *= s2;
        ((int4*)(x1s + (size_t)w * HD))[l] = pack8bf(acc);
    }
}

// xf[w] = (x0s[w]*sd + x1s[w]*sd + dsc[w]*sum_nb x1s[nb]) / 3,  sd = 1/dsc[w]
__global__ void k_gather2(const int* __restrict__ rs, const int* __restrict__ eidx,
                          const float* __restrict__ dsc,
                          const bf16* __restrict__ x0s, const bf16* __restrict__ x1s,
                          bf16* __restrict__ xf16) {
    int w    = (blockIdx.x * blockDim.x + threadIdx.x) >> 6;
    int lane = threadIdx.x & 63;
    if (w >= N_TOT) return;
    int g = lane >> 4, l = lane & 15;
    int s = rs[w];
    int e = (w == N_TOT - 1) ? (2 * NE_UB) : rs[w + 1];
    s = __builtin_amdgcn_readfirstlane(s);
    e = __builtin_amdgcn_readfirstlane(e);
    float acc[8] = {0.f, 0.f, 0.f, 0.f, 0.f, 0.f, 0.f, 0.f};
    for (int j0 = s; j0 < e; j0 += 4) {
        int j = j0 + g;
        if (j < e) {
            int nb = eidx[j];
            int4 rv = ((const int4*)(x1s + (size_t)nb * HD))[l];
            add8(acc, rv);
        }
    }
    xgred(acc);
    if (g == 0) {
        float nd = dsc[w];
        float sd = 1.0f / nd;
        float d0[8], d1[8];
        unp8(((const int4*)(x0s + (size_t)w * HD))[l], d0);
        unp8(((const int4*)(x1s + (size_t)w * HD))[l], d1);
        float o[8];
#pragma unroll
        for (int i = 0; i < 8; i++)
            o[i] = (acc[i] * nd + (d0[i] + d1[i]) * sd) * (1.0f / 3.0f);
        ((int4*)(xf16 + (size_t)w * HD))[l] = pack8bf(o);
    }
}

// agg[w] = (sum_nb h16[nb]) / max(deg,1)
__global__ void k_gather_bb(const int* __restrict__ rs, const int* __restrict__ eidx,
                            const bf16* __restrict__ h16, bf16* __restrict__ agg16) {
    int w    = (blockIdx.x * blockDim.x + threadIdx.x) >> 6;
    int lane = threadIdx.x & 63;
    if (w >= B_N) return;
    int g = lane >> 4, l = lane & 15;
    int s = rs[w];
    int e = (w == B_N - 1) ? NE_BB : rs[w + 1];
    s = __builtin_amdgcn_readfirstlane(s);
    e = __builtin_amdgcn_readfirstlane(e);
    float acc[8] = {0.f, 0.f, 0.f, 0.f, 0.f, 0.f, 0.f, 0.f};
    for (int j0 = s; j0 < e; j0 += 4) {
        int j = j0 + g;
        if (j < e) {
            int nb = eidx[j];
            int4 rv = ((const int4*)(h16 + (size_t)nb * HD))[l];
            add8(acc, rv);
        }
    }
    xgred(acc);
    if (g == 0) {
        float inv = 1.0f / fmaxf((float)(e - s), 1.0f);
#pragma unroll
        for (int i = 0; i < 8; i++) acc[i] *= inv;
        ((int4*)(agg16 + (size_t)w * HD))[l] = pack8bf(acc);
    }
}

// attention fusion head, 4 rows per 128-thread block (2 waves); bf16 in/out
__global__ void k_fuse(const bf16* __restrict__ collab16, const bf16* __restrict__ content16,
                       const float* __restrict__ Wf1, const float* __restrict__ bf1v,
                       const float* __restrict__ Wf2, const float* __restrict__ bf2v,
                       bf16* __restrict__ fused16) {
    const int R = 4;
    __shared__ float sc[R][HD];
    __shared__ float sh[R][HD];
    __shared__ float part[2][R][2];
    __shared__ float attn[R][2];
    const int c  = threadIdx.x;
    const int r0 = blockIdx.x * R;
#pragma unroll
    for (int i = 0; i < R; i++) {
        int r = r0 + i;
        sc[i][c] = (r < B_N) ? b2f(collab16[(size_t)r * HD + c]) : 0.0f;
        sh[i][c] = (r < B_N) ? b2f(content16[(size_t)r * HD + c]) : 0.0f;
    }
    __syncthreads();
    float t[R];
#pragma unroll
    for (int i = 0; i < R; i++) t[i] = 0.0f;
    for (int k = 0; k < HD; k++) {
        float w = Wf1[k * HD + c];
#pragma unroll
        for (int i = 0; i < R; i++) t[i] = fmaf(sc[i][k], w, t[i]);
    }
    for (int k = 0; k < HD; k++) {
        float w = Wf1[(size_t)(HD + k) * HD + c];
#pragma unroll
        for (int i = 0; i < R; i++) t[i] = fmaf(sh[i][k], w, t[i]);
    }
    float b1  = bf1v[c];
    float w20 = Wf2[c * 2 + 0];
    float w21 = Wf2[c * 2 + 1];
    float p0[R], p1[R];
#pragma unroll
    for (int i = 0; i < R; i++) {
        float tv = fmaxf(t[i] + b1, 0.0f);
        p0[i] = tv * w20;
        p1[i] = tv * w21;
    }
#pragma unroll
    for (int i = 0; i < R; i++) {
        for (int off = 32; off > 0; off >>= 1) {
            p0[i] += __shfl_down(p0[i], off, 64);
            p1[i] += __shfl_down(p1[i], off, 64);
        }
    }
    int wv   = threadIdx.x >> 6;
    int lane = threadIdx.x & 63;
    if (lane == 0) {
#pragma unroll
        for (int i = 0; i < R; i++) { part[wv][i][0] = p0[i]; part[wv][i][1] = p1[i]; }
    }
    __syncthreads();
    if (threadIdx.x < R) {
        int i = threadIdx.x;
        float s0 = part[0][i][0] + part[1][i][0] + bf2v[0];
        float s1 = part[0][i][1] + part[1][i][1] + bf2v[1];
        float m  = fmaxf(s0, s1);
        float e0 = expf(s0 - m), e1 = expf(s1 - m);
        float inv = 1.0f / (e0 + e1);
        attn[i][0] = e0 * inv;
        attn[i][1] = e1 * inv;
    }
    __syncthreads();
#pragma unroll
    for (int i = 0; i < R; i++) {
        int r = r0 + i;
        if (r < B_N) {
            float v = attn[i][0] * sc[i][c] + attn[i][1] * sh[i][c];
            fused16[(size_t)r * HD + c] = __float2bfloat16(v);
        }
    }
}

// 4 predictions per wave, 16 lanes x 16B (int4 of 8 bf16) per row
__global__ void k_score(const int* __restrict__ pu, const int* __restrict__ pb,
                        const bf16* __restrict__ uemb16, const bf16* __restrict__ fused16,
                        float* __restrict__ out) {
    int wid  = (blockIdx.x * blockDim.x + threadIdx.x) >> 6;
    int lane = threadIdx.x & 63;
    int g = lane >> 4;
    int l = lane & 15;
    int p = wid * 4 + g;
    if (p >= NP) return;
    int u = pu[p];
    int b = pb[p];
    int4 av = ((const int4*)(uemb16 + (size_t)u * HD))[l];
    int4 fv = ((const int4*)(fused16 + (size_t)b * HD))[l];
    const int* ap = (const int*)&av;
    const int* fp = (const int*)&fv;
    float s = 0.0f;
#pragma unroll
    for (int i = 0; i < 4; i++) {
        bf162 a2 = *(const bf162*)&ap[i];
        bf162 f2 = *(const bf162*)&fp[i];
        s = fmaf(b2f(a2.x), b2f(f2.x), s);
        s = fmaf(b2f(a2.y), b2f(f2.y), s);
    }
#pragma unroll
    for (int off = 8; off > 0; off >>= 1) s += __shfl_xor(s, off, 64);
    if (l == 0) out[p] = s;
}

extern "C" void kernel_launch(void* const* d_in, const int* in_sizes, int n_in,
                              void* d_out, int out_size, void* d_ws, size_t ws_size,
                              hipStream_t stream) {
    const float* user_x = (const float*)d_in[0];
    const float* book_x = (const float*)d_in[1];
    const int*   ub_src = (const int*)d_in[2];
    const int*   ub_dst = (const int*)d_in[3];
    const int*   bb_src = (const int*)d_in[4];
    const int*   bb_dst = (const int*)d_in[5];
    const int*   pred_u = (const int*)d_in[6];
    const int*   pred_b = (const int*)d_in[7];
    const float* Wu   = (const float*)d_in[8];
    const float* bu   = (const float*)d_in[9];
    const float* Wub  = (const float*)d_in[10];
    const float* bub  = (const float*)d_in[11];
    const float* Wbb  = (const float*)d_in[12];
    const float* bbb  = (const float*)d_in[13];
    const float* Wl1  = (const float*)d_in[14];
    const float* bl1  = (const float*)d_in[15];
    const float* Wr1  = (const float*)d_in[16];
    const float* Wl2  = (const float*)d_in[17];
    const float* bl2  = (const float*)d_in[18];
    const float* Wr2  = (const float*)d_in[19];
    const float* Wf1  = (const float*)d_in[20];
    const float* bf1v = (const float*)d_in[21];
    const float* Wf2  = (const float*)d_in[22];
    const float* bf2v = (const float*)d_in[23];
    float* out = (float*)d_out;

    // ---- workspace layout (4-byte words), total 30.96M words = 123.84 MB ----
    float* ws = (float*)d_ws;
    const size_t need = 30960000ull * sizeof(float);
    if (ws_size < need) return;

    float* dsc     = ws;                      // [0,150000) degree scale
    int*   cnt_ub  = (int*)(ws + 150000);
    int*   rs_ub   = (int*)(ws + 300000);
    int*   cnt_bb  = (int*)(ws + 450000);
    int*   rs_bb   = (int*)(ws + 500000);
    int*   bsum    = (int*)(ws + 550000);
    int*   eidx    = (int*)(ws + 560000);
    bf16*  X0s     = (bf16*)(ws + 2160000);   // pre-scaled x0
    bf16*  X1s     = (bf16*)(ws + 11760000);  // pre-scaled x1
    bf16*  XF16    = (bf16*)(ws + 21360000);

    // phase A aliases (dead once gather1 writes X1s)
    short* xu16  = (short*)(ws + 11760000);
    short* xb16  = (short*)(ws + 14960000);
    short* WuP   = (short*)(ws + 21360000);
    short* WubP  = (short*)(ws + 21364096);

    // content-phase aliases
    short* xb16c     = (short*)(ws + 2160000);
    bf16*  h16a      = (bf16*)(ws + 5360000);
    bf16*  h16b      = (bf16*)(ws + 8560000);
    bf16*  agg16     = (bf16*)(ws + 11760000);
    bf16*  content16 = (bf16*)(ws + 14960000);
    bf16*  fused16   = (bf16*)(ws + 18160000);
    bf16*  uemb16    = XF16;
    bf16*  collab16  = XF16 + (size_t)U_N * HD;
    short* WbbP = (short*)(ws + 150000);      // cnt_ub dead after ub scan
    short* Wl1P = WbbP + 16384;
    short* Wr1P = WbbP + 32768;
    short* Wl2P = WbbP + 49152;
    short* Wr2P = WbbP + 65536;

    hipMemsetAsync(ws + 150000, 0, 350000 * sizeof(float), stream);

    // ---- phase A: bf16 inputs + init weight packs ----
    k_f2b<<<(U_N * DU / 8 + 255) / 256, 256, 0, stream>>>(user_x, xu16, U_N * DU);
    k_f2b<<<(B_N * DB / 8 + 255) / 256, 256, 0, stream>>>(book_x, xb16, B_N * DB);
    k_pack_w<DU><<<(2 * 8 * 64 + 255) / 256, 256, 0, stream>>>(Wu, WuP);
    k_pack_w<DB><<<(4 * 8 * 64 + 255) / 256, 256, 0, stream>>>(Wub, WubP);

    // ---- CSR build (ub graph) — must precede scaled init GEMMs ----
    k_cnt_ub<<<(NE_UB + 255) / 256, 256, 0, stream>>>(ub_src, ub_dst, cnt_ub);
    k_cnt_bb<<<(NE_BB + 255) / 256, 256, 0, stream>>>(bb_dst, cnt_bb);
    k_dinv<<<(N_TOT + 255) / 256, 256, 0, stream>>>(cnt_ub, dsc);
    {
        int nb = (N_TOT + 1023) / 1024;
        k_scan1<<<nb, 256, 0, stream>>>(cnt_ub, rs_ub, bsum, N_TOT);
        k_scan2<<<1, 256, 0, stream>>>(bsum, nb);
        k_scan3<<<(N_TOT + 255) / 256, 256, 0, stream>>>(rs_ub, bsum, N_TOT);
    }
    k_fill_ub3<<<NBU + NBB, 1024, 0, stream>>>(ub_src, ub_dst, rs_ub, eidx);
    // cnt_ub dead: pack content-phase weights into its region
    k_pack_w<DB><<<8, 256, 0, stream>>>(Wbb, WbbP);
    k_pack_w<DB><<<8, 256, 0, stream>>>(Wl1, Wl1P);
    k_pack_w<DB><<<8, 256, 0, stream>>>(Wr1, Wr1P);
    k_pack_w<DB><<<8, 256, 0, stream>>>(Wl2, Wl2P);
    k_pack_w<DB><<<8, 256, 0, stream>>>(Wr2, Wr2P);

    // ---- init GEMMs (degree-pre-scaled outputs) ----
    k_mgemm<2, 0, false><<<(U_N + 63) / 64, 256, 0, stream>>>(
        xu16, WuP, nullptr, nullptr, bu, dsc, X0s, U_N);
    k_mgemm<4, 0, false><<<(B_N + 63) / 64, 256, 0, stream>>>(
        xb16, WubP, nullptr, nullptr, bub, dsc + U_N, X0s + (size_t)U_N * HD, B_N);

    // ---- LightGCN propagation ----
    k_gather1<<<(N_TOT + 3) / 4, 256, 0, stream>>>(rs_ub, eidx, dsc, X0s, X1s);
    k_gather2<<<(N_TOT + 3) / 4, 256, 0, stream>>>(rs_ub, eidx, dsc, X0s, X1s, XF16);

    // ---- CSR build (bb graph) — ub CSR dead ----
    {
        int nb = (B_N + 1023) / 1024;
        k_scan1<<<nb, 256, 0, stream>>>(cnt_bb, rs_bb, bsum, B_N);
        k_scan2<<<1, 256, 0, stream>>>(bsum, nb);
        k_scan3<<<(B_N + 255) / 256, 256, 0, stream>>>(rs_bb, bsum, B_N);
    }
    k_fill_bb3<<<NB2, 1024, 0, stream>>>(bb_src, bb_dst, rs_bb, eidx);

    // ---- content network (all MFMA) ----
    k_f2b<<<(B_N * DB / 8 + 255) / 256, 256, 0, stream>>>(book_x, xb16c, B_N * DB);
    k_mgemm<4, 0, false><<<(B_N + 63) / 64, 256, 0, stream>>>(
        xb16c, WbbP, nullptr, nullptr, bbb, nullptr, h16a, B_N);
    k_gather_bb<<<(B_N + 3) / 4, 256, 0, stream>>>(rs_bb, eidx, h16a, agg16);
    k_mgemm<4, 4, true><<<(B_N + 63) / 64, 256, 0, stream>>>(
        (const short*)agg16, Wl1P, (const short*)h16a, Wr1P, bl1, nullptr, h16b, B_N);
    k_gather_bb<<<(B_N + 3) / 4, 256, 0, stream>>>(rs_bb, eidx, h16b, agg16);
    k_mgemm<4, 4, true><<<(B_N + 63) / 64, 256, 0, stream>>>(
        (const short*)agg16, Wl2P, (const short*)h16b, Wr2P, bl2, nullptr, content16, B_N);

    // ---- fusion + scores ----
    k_fuse<<<(B_N + 3) / 4, 128, 0, stream>>>(collab16, content16,
                                              Wf1, bf1v, Wf2, bf2v, fused16);
    k_score<<<NP / 16, 256, 0, stream>>>(pred_u, pred_b, uemb16, fused16, out);
}

// Round 6
// 751.114 us; speedup vs baseline: 1.6459x; 1.1265x over previous
//
#include <hip/hip_runtime.h>
#include <hip/hip_bf16.h>

typedef __hip_bfloat16 bf16;
typedef __hip_bfloat162 bf162;

using short8 = __attribute__((ext_vector_type(8))) short;
using f32x4  = __attribute__((ext_vector_type(4))) float;

#define U_N   100000
#define B_N   50000
#define N_TOT 150000
#define NE_UB 800000
#define NE_BB 600000
#define NP    400000
#define DU    64
#define DB    128
#define HD    128

// bucketed-fill geometry: big buckets + 4-way edge-stream split.
// Per-(node,split) CSR sub-offsets give each (bucket,split) WG private cursors.
#define SPL   4
#define NBU   32
#define NBB   32
#define UPB   ((U_N + NBU - 1) / NBU)      // 3125 users/bucket (12.5 KB LDS)
#define BPB   ((B_N + NBB - 1) / NBB)      // 1563 books/bucket
#define LE_UB (NE_UB / SPL)                // 200000 edges/slice
#define NB2   64
#define BPB2  ((B_N + NB2 - 1) / NB2)      // 782 books/bucket (bb)
#define LE_BB (NE_BB / SPL)                // 150000 edges/slice

__device__ __forceinline__ float b2f(bf16 v) { return __bfloat162float(v); }
// f32 -> bf16 bits (RNE)
__device__ __forceinline__ short f2bs(float f) {
    unsigned u = __float_as_uint(f);
    unsigned r = (u + 0x7fffu + ((u >> 16) & 1u)) >> 16;
    return (short)r;
}
// add 8 bf16 (packed in int4) into acc[8]
__device__ __forceinline__ void add8(float (&a)[8], int4 rv) {
    const unsigned* p = (const unsigned*)&rv;
#pragma unroll
    for (int i = 0; i < 4; i++) {
        unsigned v = p[i];
        a[2 * i]     += __uint_as_float(v << 16);
        a[2 * i + 1] += __uint_as_float(v & 0xffff0000u);
    }
}
__device__ __forceinline__ void unp8(int4 rv, float (&o)[8]) {
    const unsigned* p = (const unsigned*)&rv;
#pragma unroll
    for (int i = 0; i < 4; i++) {
        unsigned v = p[i];
        o[2 * i]     = __uint_as_float(v << 16);
        o[2 * i + 1] = __uint_as_float(v & 0xffff0000u);
    }
}
__device__ __forceinline__ int4 pack8bf(const float (&a)[8]) {
    unsigned r[4];
#pragma unroll
    for (int i = 0; i < 4; i++) {
        unsigned lo = (unsigned)(unsigned short)f2bs(a[2 * i]);
        unsigned hi = (unsigned)(unsigned short)f2bs(a[2 * i + 1]);
        r[i] = lo | (hi << 16);
    }
    int4 o; o.x = r[0]; o.y = r[1]; o.z = r[2]; o.w = r[3];
    return o;
}
__device__ __forceinline__ void xgred(float (&a)[8]) {
#pragma unroll
    for (int i = 0; i < 8; i++) {
        a[i] += __shfl_xor(a[i], 16, 64);
        a[i] += __shfl_xor(a[i], 32, 64);
    }
}

// ---------------- bf16 conversion + weight packing ----------------

__global__ void k_f2b(const float* __restrict__ in, short* __restrict__ out, int n) {
    int i = (blockIdx.x * blockDim.x + threadIdx.x) * 8;
    if (i >= n) return;
    float4 a = ((const float4*)(in + i))[0];
    float4 b = ((const float4*)(in + i))[1];
    short8 v;
    v[0] = f2bs(a.x); v[1] = f2bs(a.y); v[2] = f2bs(a.z); v[3] = f2bs(a.w);
    v[4] = f2bs(b.x); v[5] = f2bs(b.y); v[6] = f2bs(b.z); v[7] = f2bs(b.w);
    *(short8*)(out + i) = v;
}

template<int KTOT>
__global__ void k_pack_w(const float* __restrict__ W, short* __restrict__ Wp) {
    int t = blockIdx.x * blockDim.x + threadIdx.x;
    if (t >= (KTOT / 32) * 8 * 64) return;
    int lane = t & 63;
    int n    = (t >> 6) & 7;
    int kk   = t >> 9;
    int lr = lane & 15, lg = lane >> 4;
    short8 v;
#pragma unroll
    for (int j = 0; j < 8; j++) {
        float f = W[(size_t)(kk * 32 + lg * 8 + j) * HD + (n * 16 + lr)];
        v[j] = f2bs(f);
    }
    *(short8*)(Wp + (size_t)t * 8) = v;
}

// ---------------- MFMA GEMM: out = [relu](A1@W1 [+ A2@W2] + bias) [* scale] ----
template<int KS1, int KS2, bool RELU>
__global__ __launch_bounds__(256) void k_mgemm(
    const short* __restrict__ A1, const short* __restrict__ Wp1,
    const short* __restrict__ A2, const short* __restrict__ Wp2,
    const float* __restrict__ bias, const float* __restrict__ scale,
    bf16* __restrict__ out, int nrows) {
    const int wv   = threadIdx.x >> 6;
    const int lane = threadIdx.x & 63;
    const int row0 = blockIdx.x * 64 + wv * 16;
    if (row0 >= nrows) return;
    const int lr = lane & 15, lg = lane >> 4;

    f32x4 acc[8];
#pragma unroll
    for (int n = 0; n < 8; n++) acc[n] = (f32x4){0.f, 0.f, 0.f, 0.f};

    {
        const short* a1p = A1 + (size_t)(row0 + lr) * (KS1 * 32) + lg * 8;
#pragma unroll
        for (int kk = 0; kk < KS1; kk++) {
            short8 af = *(const short8*)(a1p + kk * 32);
            const short* wp = Wp1 + ((size_t)(kk * 8) * 64 + lane) * 8;
#pragma unroll
            for (int n = 0; n < 8; n++) {
                short8 bfr = *(const short8*)(wp + (size_t)n * 64 * 8);
                acc[n] = __builtin_amdgcn_mfma_f32_16x16x32_bf16(af, bfr, acc[n], 0, 0, 0);
            }
        }
    }
    if constexpr (KS2 > 0) {
        const short* a2p = A2 + (size_t)(row0 + lr) * (KS2 * 32) + lg * 8;
#pragma unroll
        for (int kk = 0; kk < KS2; kk++) {
            short8 af = *(const short8*)(a2p + kk * 32);
            const short* wp = Wp2 + ((size_t)(kk * 8) * 64 + lane) * 8;
#pragma unroll
            for (int n = 0; n < 8; n++) {
                short8 bfr = *(const short8*)(wp + (size_t)n * 64 * 8);
                acc[n] = __builtin_amdgcn_mfma_f32_16x16x32_bf16(af, bfr, acc[n], 0, 0, 0);
            }
        }
    }
    float scr[4] = {1.f, 1.f, 1.f, 1.f};
    if (scale) {
#pragma unroll
        for (int r = 0; r < 4; r++) scr[r] = scale[row0 + lg * 4 + r];
    }
#pragma unroll
    for (int n = 0; n < 8; n++) {
        int col = n * 16 + lr;
        float bv = bias[col];
#pragma unroll
        for (int r = 0; r < 4; r++) {
            int row = row0 + lg * 4 + r;
            float v = acc[n][r] + bv;
            if (RELU) v = fmaxf(v, 0.0f);
            v *= scr[r];
            out[(size_t)row * HD + col] = __float2bfloat16(v);
        }
    }
}

// ---------------- CSR build: per-(node,split) count -> scan -> bucketed fill ----

__global__ void k_cnt_ub2(const int* __restrict__ us, const int* __restrict__ ud,
                          int* __restrict__ cnt2) {
    int e = blockIdx.x * blockDim.x + threadIdx.x;
    if (e < NE_UB) {
        int sp = e / LE_UB;
        atomicAdd(&cnt2[us[e] * SPL + sp], 1);
        atomicAdd(&cnt2[(U_N + ud[e]) * SPL + sp], 1);
    }
}

__global__ void k_cnt_bb2(const int* __restrict__ bd, int* __restrict__ cnt2) {
    int e = blockIdx.x * blockDim.x + threadIdx.x;
    if (e < NE_BB) {
        int sp = e / LE_BB;
        atomicAdd(&cnt2[bd[e] * SPL + sp], 1);
    }
}

// dsc[i] = 1/sqrt(max(deg,1)) from rs2 boundaries; also extract compact rs
__global__ void k_dinv2(const int* __restrict__ rs2, float* __restrict__ dsc,
                        int* __restrict__ rsn) {
    int i = blockIdx.x * blockDim.x + threadIdx.x;
    if (i < N_TOT) {
        int s = rs2[i * SPL];
        int e = (i == N_TOT - 1) ? (2 * NE_UB) : rs2[(i + 1) * SPL];
        rsn[i] = s;
        dsc[i] = 1.0f / sqrtf((float)max(e - s, 1));
    }
}

__global__ void k_rsx_bb(const int* __restrict__ rs2, int* __restrict__ rsn) {
    int i = blockIdx.x * blockDim.x + threadIdx.x;
    if (i < B_N) rsn[i] = rs2[i * SPL];
}

__global__ void k_scan1(const int* __restrict__ cnt, int* __restrict__ rs,
                        int* __restrict__ bsum, int n) {
    __shared__ int ts[256];
    const int t = threadIdx.x;
    const int base = blockIdx.x * 1024 + t * 4;
    int v0 = (base + 0 < n) ? cnt[base + 0] : 0;
    int v1 = (base + 1 < n) ? cnt[base + 1] : 0;
    int v2 = (base + 2 < n) ? cnt[base + 2] : 0;
    int v3 = (base + 3 < n) ? cnt[base + 3] : 0;
    int local = v0 + v1 + v2 + v3;
    ts[t] = local;
    __syncthreads();
    for (int off = 1; off < 256; off <<= 1) {
        int x = (t >= off) ? ts[t - off] : 0;
        __syncthreads();
        ts[t] += x;
        __syncthreads();
    }
    int ex = ts[t] - local;
    if (base + 0 < n) rs[base + 0] = ex;
    if (base + 1 < n) rs[base + 1] = ex + v0;
    if (base + 2 < n) rs[base + 2] = ex + v0 + v1;
    if (base + 3 < n) rs[base + 3] = ex + v0 + v1 + v2;
    if (t == 0) bsum[blockIdx.x] = ts[255];
}

__global__ void k_scan2(int* __restrict__ bsum, int nb) {
    __shared__ int ts[256];
    const int t = threadIdx.x;
    const int base = t * 4;
    int v0 = (base + 0 < nb) ? bsum[base + 0] : 0;
    int v1 = (base + 1 < nb) ? bsum[base + 1] : 0;
    int v2 = (base + 2 < nb) ? bsum[base + 2] : 0;
    int v3 = (base + 3 < nb) ? bsum[base + 3] : 0;
    int local = v0 + v1 + v2 + v3;
    ts[t] = local;
    __syncthreads();
    for (int off = 1; off < 256; off <<= 1) {
        int x = (t >= off) ? ts[t - off] : 0;
        __syncthreads();
        ts[t] += x;
        __syncthreads();
    }
    int ex = ts[t] - local;
    if (base + 0 < nb) bsum[base + 0] = ex;
    if (base + 1 < nb) bsum[base + 1] = ex + v0;
    if (base + 2 < nb) bsum[base + 2] = ex + v0 + v1;
    if (base + 3 < nb) bsum[base + 3] = ex + v0 + v1 + v2;
}

__global__ void k_scan3(int* __restrict__ rs, const int* __restrict__ bsum, int n) {
    int i = blockIdx.x * blockDim.x + threadIdx.x;
    if (i < n) rs[i] += bsum[i >> 10];
}

// Bucketed fill v4: (bucket, split) WGs; each streams only its edge slice with
// private LDS cursors seeded from per-(node,split) scanned offsets.
__global__ __launch_bounds__(1024) void k_fill_ub4(const int* __restrict__ us,
                                                   const int* __restrict__ ud,
                                                   const int* __restrict__ rs2,
                                                   int* __restrict__ eidx) {
    __shared__ int cur[UPB];
    const int bk = blockIdx.x >> 2;      // bucket
    const int sp = blockIdx.x & 3;       // split
    const bool userSide = bk < NBU;
    int node0, nn, rbase, add;
    const int *keys, *vals;
    if (userSide) {
        node0 = bk * UPB;
        nn    = min(UPB, U_N - node0);
        rbase = node0;
        keys  = us;
        vals  = ud;
        add   = U_N;
    } else {
        int b = bk - NBU;
        node0 = b * BPB;
        nn    = min(BPB, B_N - node0);
        rbase = U_N + node0;
        keys  = ud;
        vals  = us;
        add   = 0;
    }
    for (int i = threadIdx.x; i < nn; i += 1024)
        cur[i] = rs2[(size_t)(rbase + i) * SPL + sp];
    __syncthreads();
    const int4* k4 = (const int4*)keys;
    const int4* v4 = (const int4*)vals;
    const int q0 = sp * (LE_UB / 4), q1 = q0 + LE_UB / 4;
    for (int q = q0 + threadIdx.x; q < q1; q += 1024) {
        int4 kv = k4[q];
        int4 vv = v4[q];
        int ka[4] = {kv.x, kv.y, kv.z, kv.w};
        int va[4] = {vv.x, vv.y, vv.z, vv.w};
#pragma unroll
        for (int i = 0; i < 4; i++) {
            unsigned rel = (unsigned)(ka[i] - node0);
            if (rel < (unsigned)nn) {
                int p = atomicAdd(&cur[rel], 1);
                eidx[p] = va[i] + add;
            }
        }
    }
}

__global__ __launch_bounds__(1024) void k_fill_bb4(const int* __restrict__ bs,
                                                   const int* __restrict__ bd,
                                                   const int* __restrict__ rs2,
                                                   int* __restrict__ eidx) {
    __shared__ int cur[BPB2];
    const int bk = blockIdx.x >> 2;
    const int sp = blockIdx.x & 3;
    const int node0 = bk * BPB2;
    const int nn    = min(BPB2, B_N - node0);
    for (int i = threadIdx.x; i < nn; i += 1024)
        cur[i] = rs2[(size_t)(node0 + i) * SPL + sp];
    __syncthreads();
    const int4* k4 = (const int4*)bd;
    const int4* v4 = (const int4*)bs;
    const int q0 = sp * (LE_BB / 4), q1 = q0 + LE_BB / 4;
    for (int q = q0 + threadIdx.x; q < q1; q += 1024) {
        int4 kv = k4[q];
        int4 vv = v4[q];
        int ka[4] = {kv.x, kv.y, kv.z, kv.w};
        int va[4] = {vv.x, vv.y, vv.z, vv.w};
#pragma unroll
        for (int i = 0; i < 4; i++) {
            unsigned rel = (unsigned)(ka[i] - node0);
            if (rel < (unsigned)nn) {
                int p = atomicAdd(&cur[rel], 1);
                eidx[p] = va[i];
            }
        }
    }
}

// ---------------- pull-mode propagation (pre-scaled tables) ----------------

__global__ void k_gather1(const int* __restrict__ rs, const int* __restrict__ eidx,
                          const float* __restrict__ dsc,
                          const bf16* __restrict__ x0s, bf16* __restrict__ x1s) {
    int w    = (blockIdx.x * blockDim.x + threadIdx.x) >> 6;
    int lane = threadIdx.x & 63;
    if (w >= N_TOT) return;
    int g = lane >> 4, l = lane & 15;
    int s = rs[w];
    int e = (w == N_TOT - 1) ? (2 * NE_UB) : rs[w + 1];
    s = __builtin_amdgcn_readfirstlane(s);
    e = __builtin_amdgcn_readfirstlane(e);
    float acc[8] = {0.f, 0.f, 0.f, 0.f, 0.f, 0.f, 0.f, 0.f};
    for (int j0 = s; j0 < e; j0 += 4) {
        int j = j0 + g;
        if (j < e) {
            int nb = eidx[j];
            int4 rv = ((const int4*)(x0s + (size_t)nb * HD))[l];
            add8(acc, rv);
        }
    }
    xgred(acc);
    if (g == 0) {
        float nd = dsc[w];
        float s2 = nd * nd;
#pragma unroll
        for (int i = 0; i < 8; i++) acc[i] *= s2;
        ((int4*)(x1s + (size_t)w * HD))[l] = pack8bf(acc);
    }
}

__global__ void k_gather2(const int* __restrict__ rs, const int* __restrict__ eidx,
                          const float* __restrict__ dsc,
                          const bf16* __restrict__ x0s, const bf16* __restrict__ x1s,
                          bf16* __restrict__ xf16) {
    int w    = (blockIdx.x * blockDim.x + threadIdx.x) >> 6;
    int lane = threadIdx.x & 63;
    if (w >= N_TOT) return;
    int g = lane >> 4, l = lane & 15;
    int s = rs[w];
    int e = (w == N_TOT - 1) ? (2 * NE_UB) : rs[w + 1];
    s = __builtin_amdgcn_readfirstlane(s);
    e = __builtin_amdgcn_readfirstlane(e);
    float acc[8] = {0.f, 0.f, 0.f, 0.f, 0.f, 0.f, 0.f, 0.f};
    for (int j0 = s; j0 < e; j0 += 4) {
        int j = j0 + g;
        if (j < e) {
            int nb = eidx[j];
            int4 rv = ((const int4*)(x1s + (size_t)nb * HD))[l];
            add8(acc, rv);
        }
    }
    xgred(acc);
    if (g == 0) {
        float nd = dsc[w];
        float sd = 1.0f / nd;
        float d0[8], d1[8];
        unp8(((const int4*)(x0s + (size_t)w * HD))[l], d0);
        unp8(((const int4*)(x1s + (size_t)w * HD))[l], d1);
        float o[8];
#pragma unroll
        for (int i = 0; i < 8; i++)
            o[i] = (acc[i] * nd + (d0[i] + d1[i]) * sd) * (1.0f / 3.0f);
        ((int4*)(xf16 + (size_t)w * HD))[l] = pack8bf(o);
    }
}

__global__ void k_gather_bb(const int* __restrict__ rs, const int* __restrict__ eidx,
                            const bf16* __restrict__ h16, bf16* __restrict__ agg16) {
    int w    = (blockIdx.x * blockDim.x + threadIdx.x) >> 6;
    int lane = threadIdx.x & 63;
    if (w >= B_N) return;
    int g = lane >> 4, l = lane & 15;
    int s = rs[w];
    int e = (w == B_N - 1) ? NE_BB : rs[w + 1];
    s = __builtin_amdgcn_readfirstlane(s);
    e = __builtin_amdgcn_readfirstlane(e);
    float acc[8] = {0.f, 0.f, 0.f, 0.f, 0.f, 0.f, 0.f, 0.f};
    for (int j0 = s; j0 < e; j0 += 4) {
        int j = j0 + g;
        if (j < e) {
            int nb = eidx[j];
            int4 rv = ((const int4*)(h16 + (size_t)nb * HD))[l];
            add8(acc, rv);
        }
    }
    xgred(acc);
    if (g == 0) {
        float inv = 1.0f / fmaxf((float)(e - s), 1.0f);
#pragma unroll
        for (int i = 0; i < 8; i++) acc[i] *= inv;
        ((int4*)(agg16 + (size_t)w * HD))[l] = pack8bf(acc);
    }
}

// attention fusion head, 4 rows per 128-thread block (2 waves); bf16 in/out
__global__ void k_fuse(const bf16* __restrict__ collab16, const bf16* __restrict__ content16,
                       const float* __restrict__ Wf1, const float* __restrict__ bf1v,
                       const float* __restrict__ Wf2, const float* __restrict__ bf2v,
                       bf16* __restrict__ fused16) {
    const int R = 4;
    __shared__ float sc[R][HD];
    __shared__ float sh[R][HD];
    __shared__ float part[2][R][2];
    __shared__ float attn[R][2];
    const int c  = threadIdx.x;
    const int r0 = blockIdx.x * R;
#pragma unroll
    for (int i = 0; i < R; i++) {
        int r = r0 + i;
        sc[i][c] = (r < B_N) ? b2f(collab16[(size_t)r * HD + c]) : 0.0f;
        sh[i][c] = (r < B_N) ? b2f(content16[(size_t)r * HD + c]) : 0.0f;
    }
    __syncthreads();
    float t[R];
#pragma unroll
    for (int i = 0; i < R; i++) t[i] = 0.0f;
    for (int k = 0; k < HD; k++) {
        float w = Wf1[k * HD + c];
#pragma unroll
        for (int i = 0; i < R; i++) t[i] = fmaf(sc[i][k], w, t[i]);
    }
    for (int k = 0; k < HD; k++) {
        float w = Wf1[(size_t)(HD + k) * HD + c];
#pragma unroll
        for (int i = 0; i < R; i++) t[i] = fmaf(sh[i][k], w, t[i]);
    }
    float b1  = bf1v[c];
    float w20 = Wf2[c * 2 + 0];
    float w21 = Wf2[c * 2 + 1];
    float p0[R], p1[R];
#pragma unroll
    for (int i = 0; i < R; i++) {
        float tv = fmaxf(t[i] + b1, 0.0f);
        p0[i] = tv * w20;
        p1[i] = tv * w21;
    }
#pragma unroll
    for (int i = 0; i < R; i++) {
        for (int off = 32; off > 0; off >>= 1) {
            p0[i] += __shfl_down(p0[i], off, 64);
            p1[i] += __shfl_down(p1[i], off, 64);
        }
    }
    int wv   = threadIdx.x >> 6;
    int lane = threadIdx.x & 63;
    if (lane == 0) {
#pragma unroll
        for (int i = 0; i < R; i++) { part[wv][i][0] = p0[i]; part[wv][i][1] = p1[i]; }
    }
    __syncthreads();
    if (threadIdx.x < R) {
        int i = threadIdx.x;
        float s0 = part[0][i][0] + part[1][i][0] + bf2v[0];
        float s1 = part[0][i][1] + part[1][i][1] + bf2v[1];
        float m  = fmaxf(s0, s1);
        float e0 = expf(s0 - m), e1 = expf(s1 - m);
        float inv = 1.0f / (e0 + e1);
        attn[i][0] = e0 * inv;
        attn[i][1] = e1 * inv;
    }
    __syncthreads();
#pragma unroll
    for (int i = 0; i < R; i++) {
        int r = r0 + i;
        if (r < B_N) {
            float v = attn[i][0] * sc[i][c] + attn[i][1] * sh[i][c];
            fused16[(size_t)r * HD + c] = __float2bfloat16(v);
        }
    }
}

// 4 predictions per wave, 16 lanes x 16B (int4 of 8 bf16) per row
__global__ void k_score(const int* __restrict__ pu, const int* __restrict__ pb,
                        const bf16* __restrict__ uemb16, const bf16* __restrict__ fused16,
                        float* __restrict__ out) {
    int wid  = (blockIdx.x * blockDim.x + threadIdx.x) >> 6;
    int lane = threadIdx.x & 63;
    int g = lane >> 4;
    int l = lane & 15;
    int p = wid * 4 + g;
    if (p >= NP) return;
    int u = pu[p];
    int b = pb[p];
    int4 av = ((const int4*)(uemb16 + (size_t)u * HD))[l];
    int4 fv = ((const int4*)(fused16 + (size_t)b * HD))[l];
    const int* ap = (const int*)&av;
    const int* fp = (const int*)&fv;
    float s = 0.0f;
#pragma unroll
    for (int i = 0; i < 4; i++) {
        bf162 a2 = *(const bf162*)&ap[i];
        bf162 f2 = *(const bf162*)&fp[i];
        s = fmaf(b2f(a2.x), b2f(f2.x), s);
        s = fmaf(b2f(a2.y), b2f(f2.y), s);
    }
#pragma unroll
    for (int off = 8; off > 0; off >>= 1) s += __shfl_xor(s, off, 64);
    if (l == 0) out[p] = s;
}

extern "C" void kernel_launch(void* const* d_in, const int* in_sizes, int n_in,
                              void* d_out, int out_size, void* d_ws, size_t ws_size,
                              hipStream_t stream) {
    const float* user_x = (const float*)d_in[0];
    const float* book_x = (const float*)d_in[1];
    const int*   ub_src = (const int*)d_in[2];
    const int*   ub_dst = (const int*)d_in[3];
    const int*   bb_src = (const int*)d_in[4];
    const int*   bb_dst = (const int*)d_in[5];
    const int*   pred_u = (const int*)d_in[6];
    const int*   pred_b = (const int*)d_in[7];
    const float* Wu   = (const float*)d_in[8];
    const float* bu   = (const float*)d_in[9];
    const float* Wub  = (const float*)d_in[10];
    const float* bub  = (const float*)d_in[11];
    const float* Wbb  = (const float*)d_in[12];
    const float* bbb  = (const float*)d_in[13];
    const float* Wl1  = (const float*)d_in[14];
    const float* bl1  = (const float*)d_in[15];
    const float* Wr1  = (const float*)d_in[16];
    const float* Wl2  = (const float*)d_in[17];
    const float* bl2  = (const float*)d_in[18];
    const float* Wr2  = (const float*)d_in[19];
    const float* Wf1  = (const float*)d_in[20];
    const float* bf1v = (const float*)d_in[21];
    const float* Wf2  = (const float*)d_in[22];
    const float* bf2v = (const float*)d_in[23];
    float* out = (float*)d_out;

    // ---- workspace layout (4-byte words), total 30.96M words = 123.84 MB ----
    // [0,150000)        dsc
    // [150000,300000)   content W packs (bf16, 81920 shorts = 40960 words)
    // [300000,450000)   rs_ub compact (N_TOT)
    // [500000,550000)   rs_bb compact (B_N)
    // [550000,560000)   bsum
    // [560000,2160000)  eidx
    // [2160000,11760000) X0s bf16 N*H | pre-init: cnt2_ub[600K]@2160000,
    //                                   rs2_ub[600K]@2760000 (both dead before
    //                                   init GEMMs write X0s)
    //                                 | content: xb16c@2160000 h16a@5360000
    //                                   h16b@8560000
    // [11760000,21360000) X1s bf16   | phase A: xu16@11760000 xb16@14960000
    //                                 | post-g2: cnt2_bb@11760000 rs2_bb@11960000
    //                                   (dead after fill_bb4)
    //                                 | content: agg16@11760000 content16@14960000
    //                                   fused16@18160000 (+3.2M = 21360000, flush
    //                                   against XF16 -- NO overlap; R5 bug was
    //                                   fused16@18760000 overrunning into uemb16)
    // [21360000,30960000) XF16       | phase A head: WuP WubP (dead before gather2)
    float* ws = (float*)d_ws;
    const size_t need = 30960000ull * sizeof(float);
    if (ws_size < need) return;

    float* dsc     = ws;
    int*   rs_ub   = (int*)(ws + 300000);
    int*   rs_bb   = (int*)(ws + 500000);
    int*   bsum    = (int*)(ws + 550000);
    int*   eidx    = (int*)(ws + 560000);
    int*   cnt2_ub = (int*)(ws + 2160000);     // 600K
    int*   rs2_ub  = (int*)(ws + 2760000);     // 600K
    int*   cnt2_bb = (int*)(ws + 11760000);    // 200K
    int*   rs2_bb  = (int*)(ws + 11960000);    // 200K
    bf16*  X0s     = (bf16*)(ws + 2160000);
    bf16*  X1s     = (bf16*)(ws + 11760000);
    bf16*  XF16    = (bf16*)(ws + 21360000);

    // phase A aliases
    short* xu16  = (short*)(ws + 11760000);
    short* xb16  = (short*)(ws + 14960000);
    short* WuP   = (short*)(ws + 21360000);
    short* WubP  = (short*)(ws + 21364096);

    // content-phase aliases (round-4 addresses; overlap with cnt2_bb/rs2_bb is
    // safe because those die before k_gather_bb first writes agg16)
    short* xb16c     = (short*)(ws + 2160000);
    bf16*  h16a      = (bf16*)(ws + 5360000);
    bf16*  h16b      = (bf16*)(ws + 8560000);
    bf16*  agg16     = (bf16*)(ws + 11760000);
    bf16*  content16 = (bf16*)(ws + 14960000);
    bf16*  fused16   = (bf16*)(ws + 18160000);
    bf16*  uemb16    = XF16;
    bf16*  collab16  = XF16 + (size_t)U_N * HD;
    short* WbbP = (short*)(ws + 150000);
    short* Wl1P = WbbP + 16384;
    short* Wr1P = WbbP + 32768;
    short* Wl2P = WbbP + 49152;
    short* Wr2P = WbbP + 65536;

    // ---- phase A: bf16 inputs + all weight packs ----
    k_f2b<<<(U_N * DU / 8 + 255) / 256, 256, 0, stream>>>(user_x, xu16, U_N * DU);
    k_f2b<<<(B_N * DB / 8 + 255) / 256, 256, 0, stream>>>(book_x, xb16, B_N * DB);
    k_pack_w<DU><<<(2 * 8 * 64 + 255) / 256, 256, 0, stream>>>(Wu, WuP);
    k_pack_w<DB><<<(4 * 8 * 64 + 255) / 256, 256, 0, stream>>>(Wub, WubP);
    k_pack_w<DB><<<8, 256, 0, stream>>>(Wbb, WbbP);
    k_pack_w<DB><<<8, 256, 0, stream>>>(Wl1, Wl1P);
    k_pack_w<DB><<<8, 256, 0, stream>>>(Wr1, Wr1P);
    k_pack_w<DB><<<8, 256, 0, stream>>>(Wl2, Wl2P);
    k_pack_w<DB><<<8, 256, 0, stream>>>(Wr2, Wr2P);

    // ---- CSR build (ub graph, split CSR) ----
    hipMemsetAsync(cnt2_ub, 0, (size_t)N_TOT * SPL * sizeof(int), stream);
    k_cnt_ub2<<<(NE_UB + 255) / 256, 256, 0, stream>>>(ub_src, ub_dst, cnt2_ub);
    {
        int n = N_TOT * SPL;
        int nb = (n + 1023) / 1024;
        k_scan1<<<nb, 256, 0, stream>>>(cnt2_ub, rs2_ub, bsum, n);
        k_scan2<<<1, 256, 0, stream>>>(bsum, nb);
        k_scan3<<<(n + 255) / 256, 256, 0, stream>>>(rs2_ub, bsum, n);
    }
    k_dinv2<<<(N_TOT + 255) / 256, 256, 0, stream>>>(rs2_ub, dsc, rs_ub);
    k_fill_ub4<<<(NBU + NBB) * SPL, 1024, 0, stream>>>(ub_src, ub_dst, rs2_ub, eidx);

    // ---- init GEMMs (degree-pre-scaled; overwrite cnt2/rs2_ub region) ----
    k_mgemm<2, 0, false><<<(U_N + 63) / 64, 256, 0, stream>>>(
        xu16, WuP, nullptr, nullptr, bu, dsc, X0s, U_N);
    k_mgemm<4, 0, false><<<(B_N + 63) / 64, 256, 0, stream>>>(
        xb16, WubP, nullptr, nullptr, bub, dsc + U_N, X0s + (size_t)U_N * HD, B_N);

    // ---- LightGCN propagation ----
    k_gather1<<<(N_TOT + 3) / 4, 256, 0, stream>>>(rs_ub, eidx, dsc, X0s, X1s);
    k_gather2<<<(N_TOT + 3) / 4, 256, 0, stream>>>(rs_ub, eidx, dsc, X0s, X1s, XF16);

    // ---- CSR build (bb graph, split CSR) — X1s region dead ----
    hipMemsetAsync(cnt2_bb, 0, (size_t)B_N * SPL * sizeof(int), stream);
    k_cnt_bb2<<<(NE_BB + 255) / 256, 256, 0, stream>>>(bb_dst, cnt2_bb);
    {
        int n = B_N * SPL;
        int nb = (n + 1023) / 1024;
        k_scan1<<<nb, 256, 0, stream>>>(cnt2_bb, rs2_bb, bsum, n);
        k_scan2<<<1, 256, 0, stream>>>(bsum, nb);
        k_scan3<<<(n + 255) / 256, 256, 0, stream>>>(rs2_bb, bsum, n);
    }
    k_rsx_bb<<<(B_N + 255) / 256, 256, 0, stream>>>(rs2_bb, rs_bb);
    k_fill_bb4<<<NB2 * SPL, 1024, 0, stream>>>(bb_src, bb_dst, rs2_bb, eidx);

    // ---- content network (all MFMA) ----
    k_f2b<<<(B_N * DB / 8 + 255) / 256, 256, 0, stream>>>(book_x, xb16c, B_N * DB);
    k_mgemm<4, 0, false><<<(B_N + 63) / 64, 256, 0, stream>>>(
        xb16c, WbbP, nullptr, nullptr, bbb, nullptr, h16a, B_N);
    k_gather_bb<<<(B_N + 3) / 4, 256, 0, stream>>>(rs_bb, eidx, h16a, agg16);
    k_mgemm<4, 4, true><<<(B_N + 63) / 64, 256, 0, stream>>>(
        (const short*)agg16, Wl1P, (const short*)h16a, Wr1P, bl1, nullptr, h16b, B_N);
    k_gather_bb<<<(B_N + 3) / 4, 256, 0, stream>>>(rs_bb, eidx, h16b, agg16);
    k_mgemm<4, 4, true><<<(B_N + 63) / 64, 256, 0, stream>>>(
        (const short*)agg16, Wl2P, (const short*)h16b, Wr2P, bl2, nullptr, content16, B_N);

    // ---- fusion + scores ----
    k_fuse<<<(B_N + 3) / 4, 128, 0, stream>>>(collab16, content16,
                                              Wf1, bf1v, Wf2, bf2v, fused16);
    k_score<<<NP / 16, 256, 0, stream>>>(pred_u, pred_b, uemb16, fused16, out);
}

// Round 7
// 695.437 us; speedup vs baseline: 1.7776x; 1.0801x over previous
//
#include <hip/hip_runtime.h>
#include <hip/hip_bf16.h>

typedef __hip_bfloat16 bf16;
typedef __hip_bfloat162 bf162;

using short8 = __attribute__((ext_vector_type(8))) short;
using f32x4  = __attribute__((ext_vector_type(4))) float;

#define U_N   100000
#define B_N   50000
#define N_TOT 150000
#define NE_UB 800000
#define NE_BB 600000
#define NP    400000
#define DU    64
#define DB    128
#define HD    128

// bucketed-fill geometry: big buckets + 4-way edge-stream split.
#define SPL   4
#define NBU   32
#define NBB   32
#define UPB   ((U_N + NBU - 1) / NBU)      // 3125 users/bucket (12.5 KB LDS)
#define BPB   ((B_N + NBB - 1) / NBB)      // 1563 books/bucket
#define LE_UB (NE_UB / SPL)                // 200000 edges/slice
#define NB2   64
#define BPB2  ((B_N + NB2 - 1) / NB2)      // 782 books/bucket (bb)
#define LE_BB (NE_BB / SPL)                // 150000 edges/slice

__device__ __forceinline__ float b2f(bf16 v) { return __bfloat162float(v); }
// f32 -> bf16 bits (RNE)
__device__ __forceinline__ short f2bs(float f) {
    unsigned u = __float_as_uint(f);
    unsigned r = (u + 0x7fffu + ((u >> 16) & 1u)) >> 16;
    return (short)r;
}
// add 8 bf16 (packed in int4) into acc[8]
__device__ __forceinline__ void add8(float (&a)[8], int4 rv) {
    const unsigned* p = (const unsigned*)&rv;
#pragma unroll
    for (int i = 0; i < 4; i++) {
        unsigned v = p[i];
        a[2 * i]     += __uint_as_float(v << 16);
        a[2 * i + 1] += __uint_as_float(v & 0xffff0000u);
    }
}
__device__ __forceinline__ void unp8(int4 rv, float (&o)[8]) {
    const unsigned* p = (const unsigned*)&rv;
#pragma unroll
    for (int i = 0; i < 4; i++) {
        unsigned v = p[i];
        o[2 * i]     = __uint_as_float(v << 16);
        o[2 * i + 1] = __uint_as_float(v & 0xffff0000u);
    }
}
__device__ __forceinline__ int4 pack8bf(const float (&a)[8]) {
    unsigned r[4];
#pragma unroll
    for (int i = 0; i < 4; i++) {
        unsigned lo = (unsigned)(unsigned short)f2bs(a[2 * i]);
        unsigned hi = (unsigned)(unsigned short)f2bs(a[2 * i + 1]);
        r[i] = lo | (hi << 16);
    }
    int4 o; o.x = r[0]; o.y = r[1]; o.z = r[2]; o.w = r[3];
    return o;
}
__device__ __forceinline__ void xgred(float (&a)[8]) {
#pragma unroll
    for (int i = 0; i < 8; i++) {
        a[i] += __shfl_xor(a[i], 16, 64);
        a[i] += __shfl_xor(a[i], 32, 64);
    }
}

// ---------------- bf16 conversion + weight packing ----------------

__global__ void k_f2b(const float* __restrict__ in, short* __restrict__ out, int n) {
    int i = (blockIdx.x * blockDim.x + threadIdx.x) * 8;
    if (i >= n) return;
    float4 a = ((const float4*)(in + i))[0];
    float4 b = ((const float4*)(in + i))[1];
    short8 v;
    v[0] = f2bs(a.x); v[1] = f2bs(a.y); v[2] = f2bs(a.z); v[3] = f2bs(a.w);
    v[4] = f2bs(b.x); v[5] = f2bs(b.y); v[6] = f2bs(b.z); v[7] = f2bs(b.w);
    *(short8*)(out + i) = v;
}

template<int KTOT>
__global__ void k_pack_w(const float* __restrict__ W, short* __restrict__ Wp) {
    int t = blockIdx.x * blockDim.x + threadIdx.x;
    if (t >= (KTOT / 32) * 8 * 64) return;
    int lane = t & 63;
    int n    = (t >> 6) & 7;
    int kk   = t >> 9;
    int lr = lane & 15, lg = lane >> 4;
    short8 v;
#pragma unroll
    for (int j = 0; j < 8; j++) {
        float f = W[(size_t)(kk * 32 + lg * 8 + j) * HD + (n * 16 + lr)];
        v[j] = f2bs(f);
    }
    *(short8*)(Wp + (size_t)t * 8) = v;
}

// ---------------- MFMA GEMM: out = [relu](A1@W1 [+ A2@W2] + bias) [* scale] ----
template<int KS1, int KS2, bool RELU>
__global__ __launch_bounds__(256) void k_mgemm(
    const short* __restrict__ A1, const short* __restrict__ Wp1,
    const short* __restrict__ A2, const short* __restrict__ Wp2,
    const float* __restrict__ bias, const float* __restrict__ scale,
    bf16* __restrict__ out, int nrows) {
    const int wv   = threadIdx.x >> 6;
    const int lane = threadIdx.x & 63;
    const int row0 = blockIdx.x * 64 + wv * 16;
    if (row0 >= nrows) return;
    const int lr = lane & 15, lg = lane >> 4;

    f32x4 acc[8];
#pragma unroll
    for (int n = 0; n < 8; n++) acc[n] = (f32x4){0.f, 0.f, 0.f, 0.f};

    {
        const short* a1p = A1 + (size_t)(row0 + lr) * (KS1 * 32) + lg * 8;
#pragma unroll
        for (int kk = 0; kk < KS1; kk++) {
            short8 af = *(const short8*)(a1p + kk * 32);
            const short* wp = Wp1 + ((size_t)(kk * 8) * 64 + lane) * 8;
#pragma unroll
            for (int n = 0; n < 8; n++) {
                short8 bfr = *(const short8*)(wp + (size_t)n * 64 * 8);
                acc[n] = __builtin_amdgcn_mfma_f32_16x16x32_bf16(af, bfr, acc[n], 0, 0, 0);
            }
        }
    }
    if constexpr (KS2 > 0) {
        const short* a2p = A2 + (size_t)(row0 + lr) * (KS2 * 32) + lg * 8;
#pragma unroll
        for (int kk = 0; kk < KS2; kk++) {
            short8 af = *(const short8*)(a2p + kk * 32);
            const short* wp = Wp2 + ((size_t)(kk * 8) * 64 + lane) * 8;
#pragma unroll
            for (int n = 0; n < 8; n++) {
                short8 bfr = *(const short8*)(wp + (size_t)n * 64 * 8);
                acc[n] = __builtin_amdgcn_mfma_f32_16x16x32_bf16(af, bfr, acc[n], 0, 0, 0);
            }
        }
    }
    float scr[4] = {1.f, 1.f, 1.f, 1.f};
    if (scale) {
#pragma unroll
        for (int r = 0; r < 4; r++) scr[r] = scale[row0 + lg * 4 + r];
    }
#pragma unroll
    for (int n = 0; n < 8; n++) {
        int col = n * 16 + lr;
        float bv = bias[col];
#pragma unroll
        for (int r = 0; r < 4; r++) {
            int row = row0 + lg * 4 + r;
            float v = acc[n][r] + bv;
            if (RELU) v = fmaxf(v, 0.0f);
            v *= scr[r];
            out[(size_t)row * HD + col] = __float2bfloat16(v);
        }
    }
}

// ---------------- MFMA attention head: attn = softmax(relu(comb@Wf1+b)@Wf2+b2) ----
// Dual-A GEMM (collab@Wf1_top + content@Wf1_bot) kept in registers; epilogue
// reduces t against the two Wf2 columns across the 16 lanes sharing each row,
// softmaxes the 2 logits, writes only attn[row] (float2). t never hits memory.
__global__ __launch_bounds__(256) void k_attn(
    const short* __restrict__ A1, const short* __restrict__ Wp1,
    const short* __restrict__ A2, const short* __restrict__ Wp2,
    const float* __restrict__ bias, const float* __restrict__ Wf2,
    const float* __restrict__ bf2v, float2* __restrict__ attn, int nrows) {
    const int wv   = threadIdx.x >> 6;
    const int lane = threadIdx.x & 63;
    const int row0 = blockIdx.x * 64 + wv * 16;
    if (row0 >= nrows) return;
    const int lr = lane & 15, lg = lane >> 4;

    f32x4 acc[8];
#pragma unroll
    for (int n = 0; n < 8; n++) acc[n] = (f32x4){0.f, 0.f, 0.f, 0.f};

    {
        const short* a1p = A1 + (size_t)(row0 + lr) * 128 + lg * 8;
#pragma unroll
        for (int kk = 0; kk < 4; kk++) {
            short8 af = *(const short8*)(a1p + kk * 32);
            const short* wp = Wp1 + ((size_t)(kk * 8) * 64 + lane) * 8;
#pragma unroll
            for (int n = 0; n < 8; n++) {
                short8 bfr = *(const short8*)(wp + (size_t)n * 64 * 8);
                acc[n] = __builtin_amdgcn_mfma_f32_16x16x32_bf16(af, bfr, acc[n], 0, 0, 0);
            }
        }
    }
    {
        const short* a2p = A2 + (size_t)(row0 + lr) * 128 + lg * 8;
#pragma unroll
        for (int kk = 0; kk < 4; kk++) {
            short8 af = *(const short8*)(a2p + kk * 32);
            const short* wp = Wp2 + ((size_t)(kk * 8) * 64 + lane) * 8;
#pragma unroll
            for (int n = 0; n < 8; n++) {
                short8 bfr = *(const short8*)(wp + (size_t)n * 64 * 8);
                acc[n] = __builtin_amdgcn_mfma_f32_16x16x32_bf16(af, bfr, acc[n], 0, 0, 0);
            }
        }
    }
    float q0[4] = {0.f, 0.f, 0.f, 0.f};
    float q1[4] = {0.f, 0.f, 0.f, 0.f};
#pragma unroll
    for (int n = 0; n < 8; n++) {
        int col = n * 16 + lr;
        float bv = bias[col];
        float2 w2 = ((const float2*)Wf2)[col];
#pragma unroll
        for (int r = 0; r < 4; r++) {
            float tv = fmaxf(acc[n][r] + bv, 0.0f);
            q0[r] = fmaf(tv, w2.x, q0[r]);
            q1[r] = fmaf(tv, w2.y, q1[r]);
        }
    }
#pragma unroll
    for (int off = 1; off <= 8; off <<= 1) {
#pragma unroll
        for (int r = 0; r < 4; r++) {
            q0[r] += __shfl_xor(q0[r], off, 64);
            q1[r] += __shfl_xor(q1[r], off, 64);
        }
    }
    if (lr == 0) {
        float b0 = bf2v[0], b1 = bf2v[1];
#pragma unroll
        for (int r = 0; r < 4; r++) {
            int row = row0 + lg * 4 + r;
            float s0 = q0[r] + b0;
            float s1 = q1[r] + b1;
            float m  = fmaxf(s0, s1);
            float e0 = expf(s0 - m), e1 = expf(s1 - m);
            float inv = 1.0f / (e0 + e1);
            attn[row] = make_float2(e0 * inv, e1 * inv);
        }
    }
}

// fused = attn.x*collab + attn.y*content  (elementwise, int4-vectorized)
__global__ void k_fuse2(const float2* __restrict__ attn,
                        const bf16* __restrict__ collab, const bf16* __restrict__ content,
                        bf16* __restrict__ fused) {
    int idx = blockIdx.x * blockDim.x + threadIdx.x;
    if (idx >= B_N * 16) return;
    int row = idx >> 4, l = idx & 15;
    float2 a = attn[row];
    float c[8], h[8], o[8];
    unp8(((const int4*)(collab + (size_t)row * HD))[l], c);
    unp8(((const int4*)(content + (size_t)row * HD))[l], h);
#pragma unroll
    for (int i = 0; i < 8; i++) o[i] = a.x * c[i] + a.y * h[i];
    ((int4*)(fused + (size_t)row * HD))[l] = pack8bf(o);
}

// ---------------- CSR build: per-(node,split) count -> scan -> bucketed fill ----

__global__ void k_cnt_ub2(const int* __restrict__ us, const int* __restrict__ ud,
                          int* __restrict__ cnt2) {
    int e = blockIdx.x * blockDim.x + threadIdx.x;
    if (e < NE_UB) {
        int sp = e / LE_UB;
        atomicAdd(&cnt2[us[e] * SPL + sp], 1);
        atomicAdd(&cnt2[(U_N + ud[e]) * SPL + sp], 1);
    }
}

__global__ void k_cnt_bb2(const int* __restrict__ bd, int* __restrict__ cnt2) {
    int e = blockIdx.x * blockDim.x + threadIdx.x;
    if (e < NE_BB) {
        int sp = e / LE_BB;
        atomicAdd(&cnt2[bd[e] * SPL + sp], 1);
    }
}

// dsc[i] = 1/sqrt(max(deg,1)) from rs2 boundaries; also extract compact rs
__global__ void k_dinv2(const int* __restrict__ rs2, float* __restrict__ dsc,
                        int* __restrict__ rsn) {
    int i = blockIdx.x * blockDim.x + threadIdx.x;
    if (i < N_TOT) {
        int s = rs2[i * SPL];
        int e = (i == N_TOT - 1) ? (2 * NE_UB) : rs2[(i + 1) * SPL];
        rsn[i] = s;
        dsc[i] = 1.0f / sqrtf((float)max(e - s, 1));
    }
}

__global__ void k_rsx_bb(const int* __restrict__ rs2, int* __restrict__ rsn) {
    int i = blockIdx.x * blockDim.x + threadIdx.x;
    if (i < B_N) rsn[i] = rs2[i * SPL];
}

__global__ void k_scan1(const int* __restrict__ cnt, int* __restrict__ rs,
                        int* __restrict__ bsum, int n) {
    __shared__ int ts[256];
    const int t = threadIdx.x;
    const int base = blockIdx.x * 1024 + t * 4;
    int v0 = (base + 0 < n) ? cnt[base + 0] : 0;
    int v1 = (base + 1 < n) ? cnt[base + 1] : 0;
    int v2 = (base + 2 < n) ? cnt[base + 2] : 0;
    int v3 = (base + 3 < n) ? cnt[base + 3] : 0;
    int local = v0 + v1 + v2 + v3;
    ts[t] = local;
    __syncthreads();
    for (int off = 1; off < 256; off <<= 1) {
        int x = (t >= off) ? ts[t - off] : 0;
        __syncthreads();
        ts[t] += x;
        __syncthreads();
    }
    int ex = ts[t] - local;
    if (base + 0 < n) rs[base + 0] = ex;
    if (base + 1 < n) rs[base + 1] = ex + v0;
    if (base + 2 < n) rs[base + 2] = ex + v0 + v1;
    if (base + 3 < n) rs[base + 3] = ex + v0 + v1 + v2;
    if (t == 0) bsum[blockIdx.x] = ts[255];
}

__global__ void k_scan2(int* __restrict__ bsum, int nb) {
    __shared__ int ts[256];
    const int t = threadIdx.x;
    const int base = t * 4;
    int v0 = (base + 0 < nb) ? bsum[base + 0] : 0;
    int v1 = (base + 1 < nb) ? bsum[base + 1] : 0;
    int v2 = (base + 2 < nb) ? bsum[base + 2] : 0;
    int v3 = (base + 3 < nb) ? bsum[base + 3] : 0;
    int local = v0 + v1 + v2 + v3;
    ts[t] = local;
    __syncthreads();
    for (int off = 1; off < 256; off <<= 1) {
        int x = (t >= off) ? ts[t - off] : 0;
        __syncthreads();
        ts[t] += x;
        __syncthreads();
    }
    int ex = ts[t] - local;
    if (base + 0 < nb) bsum[base + 0] = ex;
    if (base + 1 < nb) bsum[base + 1] = ex + v0;
    if (base + 2 < nb) bsum[base + 2] = ex + v0 + v1;
    if (base + 3 < nb) bsum[base + 3] = ex + v0 + v1 + v2;
}

__global__ void k_scan3(int* __restrict__ rs, const int* __restrict__ bsum, int n) {
    int i = blockIdx.x * blockDim.x + threadIdx.x;
    if (i < n) rs[i] += bsum[i >> 10];
}

// Bucketed fill v4: (bucket, split) WGs; each streams only its edge slice with
// private LDS cursors seeded from per-(node,split) scanned offsets.
__global__ __launch_bounds__(1024) void k_fill_ub4(const int* __restrict__ us,
                                                   const int* __restrict__ ud,
                                                   const int* __restrict__ rs2,
                                                   int* __restrict__ eidx) {
    __shared__ int cur[UPB];
    const int bk = blockIdx.x >> 2;      // bucket
    const int sp = blockIdx.x & 3;       // split
    const bool userSide = bk < NBU;
    int node0, nn, rbase, add;
    const int *keys, *vals;
    if (userSide) {
        node0 = bk * UPB;
        nn    = min(UPB, U_N - node0);
        rbase = node0;
        keys  = us;
        vals  = ud;
        add   = U_N;
    } else {
        int b = bk - NBU;
        node0 = b * BPB;
        nn    = min(BPB, B_N - node0);
        rbase = U_N + node0;
        keys  = ud;
        vals  = us;
        add   = 0;
    }
    for (int i = threadIdx.x; i < nn; i += 1024)
        cur[i] = rs2[(size_t)(rbase + i) * SPL + sp];
    __syncthreads();
    const int4* k4 = (const int4*)keys;
    const int4* v4 = (const int4*)vals;
    const int q0 = sp * (LE_UB / 4), q1 = q0 + LE_UB / 4;
    for (int q = q0 + threadIdx.x; q < q1; q += 1024) {
        int4 kv = k4[q];
        int4 vv = v4[q];
        int ka[4] = {kv.x, kv.y, kv.z, kv.w};
        int va[4] = {vv.x, vv.y, vv.z, vv.w};
#pragma unroll
        for (int i = 0; i < 4; i++) {
            unsigned rel = (unsigned)(ka[i] - node0);
            if (rel < (unsigned)nn) {
                int p = atomicAdd(&cur[rel], 1);
                eidx[p] = va[i] + add;
            }
        }
    }
}

__global__ __launch_bounds__(1024) void k_fill_bb4(const int* __restrict__ bs,
                                                   const int* __restrict__ bd,
                                                   const int* __restrict__ rs2,
                                                   int* __restrict__ eidx) {
    __shared__ int cur[BPB2];
    const int bk = blockIdx.x >> 2;
    const int sp = blockIdx.x & 3;
    const int node0 = bk * BPB2;
    const int nn    = min(BPB2, B_N - node0);
    for (int i = threadIdx.x; i < nn; i += 1024)
        cur[i] = rs2[(size_t)(node0 + i) * SPL + sp];
    __syncthreads();
    const int4* k4 = (const int4*)bd;
    const int4* v4 = (const int4*)bs;
    const int q0 = sp * (LE_BB / 4), q1 = q0 + LE_BB / 4;
    for (int q = q0 + threadIdx.x; q < q1; q += 1024) {
        int4 kv = k4[q];
        int4 vv = v4[q];
        int ka[4] = {kv.x, kv.y, kv.z, kv.w};
        int va[4] = {vv.x, vv.y, vv.z, vv.w};
#pragma unroll
        for (int i = 0; i < 4; i++) {
            unsigned rel = (unsigned)(ka[i] - node0);
            if (rel < (unsigned)nn) {
                int p = atomicAdd(&cur[rel], 1);
                eidx[p] = va[i];
            }
        }
    }
}

// ---------------- pull-mode propagation (pre-scaled tables) ----------------

__global__ void k_gather1(const int* __restrict__ rs, const int* __restrict__ eidx,
                          const float* __restrict__ dsc,
                          const bf16* __restrict__ x0s, bf16* __restrict__ x1s) {
    int w    = (blockIdx.x * blockDim.x + threadIdx.x) >> 6;
    int lane = threadIdx.x & 63;
    if (w >= N_TOT) return;
    int g = lane >> 4, l = lane & 15;
    int s = rs[w];
    int e = (w == N_TOT - 1) ? (2 * NE_UB) : rs[w + 1];
    s = __builtin_amdgcn_readfirstlane(s);
    e = __builtin_amdgcn_readfirstlane(e);
    float acc[8] = {0.f, 0.f, 0.f, 0.f, 0.f, 0.f, 0.f, 0.f};
    for (int j0 = s; j0 < e; j0 += 4) {
        int j = j0 + g;
        if (j < e) {
            int nb = eidx[j];
            int4 rv = ((const int4*)(x0s + (size_t)nb * HD))[l];
            add8(acc, rv);
        }
    }
    xgred(acc);
    if (g == 0) {
        float nd = dsc[w];
        float s2 = nd * nd;
#pragma unroll
        for (int i = 0; i < 8; i++) acc[i] *= s2;
        ((int4*)(x1s + (size_t)w * HD))[l] = pack8bf(acc);
    }
}

__global__ void k_gather2(const int* __restrict__ rs, const int* __restrict__ eidx,
                          const float* __restrict__ dsc,
                          const bf16* __restrict__ x0s, const bf16* __restrict__ x1s,
                          bf16* __restrict__ xf16) {
    int w    = (blockIdx.x * blockDim.x + threadIdx.x) >> 6;
    int lane = threadIdx.x & 63;
    if (w >= N_TOT) return;
    int g = lane >> 4, l = lane & 15;
    int s = rs[w];
    int e = (w == N_TOT - 1) ? (2 * NE_UB) : rs[w + 1];
    s = __builtin_amdgcn_readfirstlane(s);
    e = __builtin_amdgcn_readfirstlane(e);
    float acc[8] = {0.f, 0.f, 0.f, 0.f, 0.f, 0.f, 0.f, 0.f};
    for (int j0 = s; j0 < e; j0 += 4) {
        int j = j0 + g;
        if (j < e) {
            int nb = eidx[j];
            int4 rv = ((const int4*)(x1s + (size_t)nb * HD))[l];
            add8(acc, rv);
        }
    }
    xgred(acc);
    if (g == 0) {
        float nd = dsc[w];
        float sd = 1.0f / nd;
        float d0[8], d1[8];
        unp8(((const int4*)(x0s + (size_t)w * HD))[l], d0);
        unp8(((const int4*)(x1s + (size_t)w * HD))[l], d1);
        float o[8];
#pragma unroll
        for (int i = 0; i < 8; i++)
            o[i] = (acc[i] * nd + (d0[i] + d1[i]) * sd) * (1.0f / 3.0f);
        ((int4*)(xf16 + (size_t)w * HD))[l] = pack8bf(o);
    }
}

__global__ void k_gather_bb(const int* __restrict__ rs, const int* __restrict__ eidx,
                            const bf16* __restrict__ h16, bf16* __restrict__ agg16) {
    int w    = (blockIdx.x * blockDim.x + threadIdx.x) >> 6;
    int lane = threadIdx.x & 63;
    if (w >= B_N) return;
    int g = lane >> 4, l = lane & 15;
    int s = rs[w];
    int e = (w == B_N - 1) ? NE_BB : rs[w + 1];
    s = __builtin_amdgcn_readfirstlane(s);
    e = __builtin_amdgcn_readfirstlane(e);
    float acc[8] = {0.f, 0.f, 0.f, 0.f, 0.f, 0.f, 0.f, 0.f};
    for (int j0 = s; j0 < e; j0 += 4) {
        int j = j0 + g;
        if (j < e) {
            int nb = eidx[j];
            int4 rv = ((const int4*)(h16 + (size_t)nb * HD))[l];
            add8(acc, rv);
        }
    }
    xgred(acc);
    if (g == 0) {
        float inv = 1.0f / fmaxf((float)(e - s), 1.0f);
#pragma unroll
        for (int i = 0; i < 8; i++) acc[i] *= inv;
        ((int4*)(agg16 + (size_t)w * HD))[l] = pack8bf(acc);
    }
}

// 4 predictions per wave, 16 lanes x 16B (int4 of 8 bf16) per row
__global__ void k_score(const int* __restrict__ pu, const int* __restrict__ pb,
                        const bf16* __restrict__ uemb16, const bf16* __restrict__ fused16,
                        float* __restrict__ out) {
    int wid  = (blockIdx.x * blockDim.x + threadIdx.x) >> 6;
    int lane = threadIdx.x & 63;
    int g = lane >> 4;
    int l = lane & 15;
    int p = wid * 4 + g;
    if (p >= NP) return;
    int u = pu[p];
    int b = pb[p];
    int4 av = ((const int4*)(uemb16 + (size_t)u * HD))[l];
    int4 fv = ((const int4*)(fused16 + (size_t)b * HD))[l];
    const int* ap = (const int*)&av;
    const int* fp = (const int*)&fv;
    float s = 0.0f;
#pragma unroll
    for (int i = 0; i < 4; i++) {
        bf162 a2 = *(const bf162*)&ap[i];
        bf162 f2 = *(const bf162*)&fp[i];
        s = fmaf(b2f(a2.x), b2f(f2.x), s);
        s = fmaf(b2f(a2.y), b2f(f2.y), s);
    }
#pragma unroll
    for (int off = 8; off > 0; off >>= 1) s += __shfl_xor(s, off, 64);
    if (l == 0) out[p] = s;
}

extern "C" void kernel_launch(void* const* d_in, const int* in_sizes, int n_in,
                              void* d_out, int out_size, void* d_ws, size_t ws_size,
                              hipStream_t stream) {
    const float* user_x = (const float*)d_in[0];
    const float* book_x = (const float*)d_in[1];
    const int*   ub_src = (const int*)d_in[2];
    const int*   ub_dst = (const int*)d_in[3];
    const int*   bb_src = (const int*)d_in[4];
    const int*   bb_dst = (const int*)d_in[5];
    const int*   pred_u = (const int*)d_in[6];
    const int*   pred_b = (const int*)d_in[7];
    const float* Wu   = (const float*)d_in[8];
    const float* bu   = (const float*)d_in[9];
    const float* Wub  = (const float*)d_in[10];
    const float* bub  = (const float*)d_in[11];
    const float* Wbb  = (const float*)d_in[12];
    const float* bbb  = (const float*)d_in[13];
    const float* Wl1  = (const float*)d_in[14];
    const float* bl1  = (const float*)d_in[15];
    const float* Wr1  = (const float*)d_in[16];
    const float* Wl2  = (const float*)d_in[17];
    const float* bl2  = (const float*)d_in[18];
    const float* Wr2  = (const float*)d_in[19];
    const float* Wf1  = (const float*)d_in[20];
    const float* bf1v = (const float*)d_in[21];
    const float* Wf2  = (const float*)d_in[22];
    const float* bf2v = (const float*)d_in[23];
    float* out = (float*)d_out;

    // ---- workspace layout (4-byte words), total 30.96M words = 123.84 MB ----
    // [0,150000)        dsc
    // [150000,300000)   W packs: content (40960 w) + Wf1P (16384 w) = 57344 w
    // [300000,450000)   rs_ub compact (N_TOT)
    // [500000,550000)   rs_bb compact (B_N)
    // [550000,560000)   bsum
    // [560000,2160000)  eidx
    // [2160000,11760000) X0s bf16 N*H | pre-init: cnt2_ub@2160000 rs2_ub@2760000
    //                                 | content: xb16c@2160000 h16a@5360000 h16b@8560000
    // [11760000,21360000) X1s bf16   | phase A: xu16@11760000 xb16@14960000
    //                                 | post-g2: cnt2_bb@11760000 rs2_bb@11960000
    //                                 | content: agg16@11760000 content16@14960000
    //                                   fused16@18160000 (ends at 21360000, no overlap)
    //                                 | attn (float2[B_N]) @11760000 after agg16 dies
    // [21360000,30960000) XF16       | phase A head: WuP WubP (dead before gather2)
    float* ws = (float*)d_ws;
    const size_t need = 30960000ull * sizeof(float);
    if (ws_size < need) return;

    float* dsc     = ws;
    int*   rs_ub   = (int*)(ws + 300000);
    int*   rs_bb   = (int*)(ws + 500000);
    int*   bsum    = (int*)(ws + 550000);
    int*   eidx    = (int*)(ws + 560000);
    int*   cnt2_ub = (int*)(ws + 2160000);     // 600K
    int*   rs2_ub  = (int*)(ws + 2760000);     // 600K
    int*   cnt2_bb = (int*)(ws + 11760000);    // 200K
    int*   rs2_bb  = (int*)(ws + 11960000);    // 200K
    bf16*  X0s     = (bf16*)(ws + 2160000);
    bf16*  X1s     = (bf16*)(ws + 11760000);
    bf16*  XF16    = (bf16*)(ws + 21360000);

    // phase A aliases
    short* xu16  = (short*)(ws + 11760000);
    short* xb16  = (short*)(ws + 14960000);
    short* WuP   = (short*)(ws + 21360000);
    short* WubP  = (short*)(ws + 21364096);

    // content-phase aliases
    short* xb16c     = (short*)(ws + 2160000);
    bf16*  h16a      = (bf16*)(ws + 5360000);
    bf16*  h16b      = (bf16*)(ws + 8560000);
    bf16*  agg16     = (bf16*)(ws + 11760000);
    bf16*  content16 = (bf16*)(ws + 14960000);
    bf16*  fused16   = (bf16*)(ws + 18160000);
    float2* attnb    = (float2*)(ws + 11760000);  // over dead agg16 (after 2nd glayer)
    bf16*  uemb16    = XF16;
    bf16*  collab16  = XF16 + (size_t)U_N * HD;
    short* WbbP = (short*)(ws + 150000);
    short* Wl1P = WbbP + 16384;
    short* Wr1P = WbbP + 32768;
    short* Wl2P = WbbP + 49152;
    short* Wr2P = WbbP + 65536;
    short* Wf1P = WbbP + 81920;                   // 32768 shorts (KTOT=256)

    // ---- phase A: bf16 inputs + all weight packs ----
    k_f2b<<<(U_N * DU / 8 + 255) / 256, 256, 0, stream>>>(user_x, xu16, U_N * DU);
    k_f2b<<<(B_N * DB / 8 + 255) / 256, 256, 0, stream>>>(book_x, xb16, B_N * DB);
    k_pack_w<DU><<<(2 * 8 * 64 + 255) / 256, 256, 0, stream>>>(Wu, WuP);
    k_pack_w<DB><<<(4 * 8 * 64 + 255) / 256, 256, 0, stream>>>(Wub, WubP);
    k_pack_w<DB><<<8, 256, 0, stream>>>(Wbb, WbbP);
    k_pack_w<DB><<<8, 256, 0, stream>>>(Wl1, Wl1P);
    k_pack_w<DB><<<8, 256, 0, stream>>>(Wr1, Wr1P);
    k_pack_w<DB><<<8, 256, 0, stream>>>(Wl2, Wl2P);
    k_pack_w<DB><<<8, 256, 0, stream>>>(Wr2, Wr2P);
    k_pack_w<256><<<16, 256, 0, stream>>>(Wf1, Wf1P);

    // ---- CSR build (ub graph, split CSR) ----
    hipMemsetAsync(cnt2_ub, 0, (size_t)N_TOT * SPL * sizeof(int), stream);
    k_cnt_ub2<<<(NE_UB + 255) / 256, 256, 0, stream>>>(ub_src, ub_dst, cnt2_ub);
    {
        int n = N_TOT * SPL;
        int nb = (n + 1023) / 1024;
        k_scan1<<<nb, 256, 0, stream>>>(cnt2_ub, rs2_ub, bsum, n);
        k_scan2<<<1, 256, 0, stream>>>(bsum, nb);
        k_scan3<<<(n + 255) / 256, 256, 0, stream>>>(rs2_ub, bsum, n);
    }
    k_dinv2<<<(N_TOT + 255) / 256, 256, 0, stream>>>(rs2_ub, dsc, rs_ub);
    k_fill_ub4<<<(NBU + NBB) * SPL, 1024, 0, stream>>>(ub_src, ub_dst, rs2_ub, eidx);

    // ---- init GEMMs (degree-pre-scaled; overwrite cnt2/rs2_ub region) ----
    k_mgemm<2, 0, false><<<(U_N + 63) / 64, 256, 0, stream>>>(
        xu16, WuP, nullptr, nullptr, bu, dsc, X0s, U_N);
    k_mgemm<4, 0, false><<<(B_N + 63) / 64, 256, 0, stream>>>(
        xb16, WubP, nullptr, nullptr, bub, dsc + U_N, X0s + (size_t)U_N * HD, B_N);

    // ---- LightGCN propagation ----
    k_gather1<<<(N_TOT + 3) / 4, 256, 0, stream>>>(rs_ub, eidx, dsc, X0s, X1s);
    k_gather2<<<(N_TOT + 3) / 4, 256, 0, stream>>>(rs_ub, eidx, dsc, X0s, X1s, XF16);

    // ---- CSR build (bb graph, split CSR) — X1s region dead ----
    hipMemsetAsync(cnt2_bb, 0, (size_t)B_N * SPL * sizeof(int), stream);
    k_cnt_bb2<<<(NE_BB + 255) / 256, 256, 0, stream>>>(bb_dst, cnt2_bb);
    {
        int n = B_N * SPL;
        int nb = (n + 1023) / 1024;
        k_scan1<<<nb, 256, 0, stream>>>(cnt2_bb, rs2_bb, bsum, n);
        k_scan2<<<1, 256, 0, stream>>>(bsum, nb);
        k_scan3<<<(n + 255) / 256, 256, 0, stream>>>(rs2_bb, bsum, n);
    }
    k_rsx_bb<<<(B_N + 255) / 256, 256, 0, stream>>>(rs2_bb, rs_bb);
    k_fill_bb4<<<NB2 * SPL, 1024, 0, stream>>>(bb_src, bb_dst, rs2_bb, eidx);

    // ---- content network (all MFMA) ----
    k_f2b<<<(B_N * DB / 8 + 255) / 256, 256, 0, stream>>>(book_x, xb16c, B_N * DB);
    k_mgemm<4, 0, false><<<(B_N + 63) / 64, 256, 0, stream>>>(
        xb16c, WbbP, nullptr, nullptr, bbb, nullptr, h16a, B_N);
    k_gather_bb<<<(B_N + 3) / 4, 256, 0, stream>>>(rs_bb, eidx, h16a, agg16);
    k_mgemm<4, 4, true><<<(B_N + 63) / 64, 256, 0, stream>>>(
        (const short*)agg16, Wl1P, (const short*)h16a, Wr1P, bl1, nullptr, h16b, B_N);
    k_gather_bb<<<(B_N + 3) / 4, 256, 0, stream>>>(rs_bb, eidx, h16b, agg16);
    k_mgemm<4, 4, true><<<(B_N + 63) / 64, 256, 0, stream>>>(
        (const short*)agg16, Wl2P, (const short*)h16b, Wr2P, bl2, nullptr, content16, B_N);

    // ---- fusion (MFMA attn head + elementwise blend) + scores ----
    k_attn<<<(B_N + 63) / 64, 256, 0, stream>>>(
        (const short*)collab16, Wf1P, (const short*)content16, Wf1P + 32768 / 2,
        bf1v, Wf2, bf2v, attnb, B_N);
    k_fuse2<<<(B_N * 16 + 255) / 256, 256, 0, stream>>>(attnb, collab16, content16, fused16);
    k_score<<<NP / 16, 256, 0, stream>>>(pred_u, pred_b, uemb16, fused16, out);
}

// Round 8
// 689.779 us; speedup vs baseline: 1.7922x; 1.0082x over previous
//
#include <hip/hip_runtime.h>
#include <hip/hip_bf16.h>

typedef __hip_bfloat16 bf16;
typedef __hip_bfloat162 bf162;

using short8 = __attribute__((ext_vector_type(8))) short;
using f32x4  = __attribute__((ext_vector_type(4))) float;

#define U_N   100000
#define B_N   50000
#define N_TOT 150000
#define NE_UB 800000
#define NE_BB 600000
#define NP    400000
#define DU    64
#define DB    128
#define HD    128

// bucketed-fill geometry: big buckets + 4-way edge-stream split.
#define SPL   4
#define NBU   32
#define NBB   32
#define UPB   ((U_N + NBU - 1) / NBU)      // 3125 users/bucket (12.5 KB LDS)
#define BPB   ((B_N + NBB - 1) / NBB)      // 1563 books/bucket
#define LE_UB (NE_UB / SPL)                // 200000 edges/slice
#define NB2   64
#define BPB2  ((B_N + NB2 - 1) / NB2)      // 782 books/bucket (bb)
#define LE_BB (NE_BB / SPL)                // 150000 edges/slice

__device__ __forceinline__ float b2f(bf16 v) { return __bfloat162float(v); }
// f32 -> bf16 bits (RNE)
__device__ __forceinline__ short f2bs(float f) {
    unsigned u = __float_as_uint(f);
    unsigned r = (u + 0x7fffu + ((u >> 16) & 1u)) >> 16;
    return (short)r;
}
// add 8 bf16 (packed in int4) into acc[8]
__device__ __forceinline__ void add8(float (&a)[8], int4 rv) {
    const unsigned* p = (const unsigned*)&rv;
#pragma unroll
    for (int i = 0; i < 4; i++) {
        unsigned v = p[i];
        a[2 * i]     += __uint_as_float(v << 16);
        a[2 * i + 1] += __uint_as_float(v & 0xffff0000u);
    }
}
__device__ __forceinline__ void unp8(int4 rv, float (&o)[8]) {
    const unsigned* p = (const unsigned*)&rv;
#pragma unroll
    for (int i = 0; i < 4; i++) {
        unsigned v = p[i];
        o[2 * i]     = __uint_as_float(v << 16);
        o[2 * i + 1] = __uint_as_float(v & 0xffff0000u);
    }
}
__device__ __forceinline__ int4 pack8bf(const float (&a)[8]) {
    unsigned r[4];
#pragma unroll
    for (int i = 0; i < 4; i++) {
        unsigned lo = (unsigned)(unsigned short)f2bs(a[2 * i]);
        unsigned hi = (unsigned)(unsigned short)f2bs(a[2 * i + 1]);
        r[i] = lo | (hi << 16);
    }
    int4 o; o.x = r[0]; o.y = r[1]; o.z = r[2]; o.w = r[3];
    return o;
}
__device__ __forceinline__ void xgred(float (&a)[8]) {
#pragma unroll
    for (int i = 0; i < 8; i++) {
        a[i] += __shfl_xor(a[i], 16, 64);
        a[i] += __shfl_xor(a[i], 32, 64);
    }
}

// ---------------- bf16 conversion + weight packing ----------------

__global__ void k_f2b(const float* __restrict__ in, short* __restrict__ out, int n) {
    int i = (blockIdx.x * blockDim.x + threadIdx.x) * 8;
    if (i >= n) return;
    float4 a = ((const float4*)(in + i))[0];
    float4 b = ((const float4*)(in + i))[1];
    short8 v;
    v[0] = f2bs(a.x); v[1] = f2bs(a.y); v[2] = f2bs(a.z); v[3] = f2bs(a.w);
    v[4] = f2bs(b.x); v[5] = f2bs(b.y); v[6] = f2bs(b.z); v[7] = f2bs(b.w);
    *(short8*)(out + i) = v;
}

// merged: user_x -> xu16 and book_x -> xb16 in one launch
__global__ void k_f2b2(const float* __restrict__ A, short* __restrict__ Ao, int nA,
                       const float* __restrict__ B, short* __restrict__ Bo, int nB) {
    int i = (blockIdx.x * blockDim.x + threadIdx.x) * 8;
    const float* src; short* dst; int off;
    if (i < nA)            { src = A; dst = Ao; off = i; }
    else if (i < nA + nB)  { src = B; dst = Bo; off = i - nA; }
    else return;
    float4 a = ((const float4*)(src + off))[0];
    float4 b = ((const float4*)(src + off))[1];
    short8 v;
    v[0] = f2bs(a.x); v[1] = f2bs(a.y); v[2] = f2bs(a.z); v[3] = f2bs(a.w);
    v[4] = f2bs(b.x); v[5] = f2bs(b.y); v[6] = f2bs(b.z); v[7] = f2bs(b.w);
    *(short8*)(dst + off) = v;
}

// all 8 weight packs in one launch; thread ranges per weight.
// ranges (threads = KTOT/32*8*64): Wu 1024 | Wub 2048 | Wbb/Wl1/Wr1/Wl2/Wr2 2048 each | Wf1 4096
__global__ void k_pack_all(const float* __restrict__ Wu,  const float* __restrict__ Wub,
                           const float* __restrict__ Wbb, const float* __restrict__ Wl1,
                           const float* __restrict__ Wr1, const float* __restrict__ Wl2,
                           const float* __restrict__ Wr2, const float* __restrict__ Wf1,
                           short* WuP, short* WubP, short* WbbP, short* Wl1P,
                           short* Wr1P, short* Wl2P, short* Wr2P, short* Wf1P) {
    int t = blockIdx.x * blockDim.x + threadIdx.x;
    const float* W; short* Wp; int base;
    if      (t < 1024)  { W = Wu;  Wp = WuP;  base = 0; }
    else if (t < 3072)  { W = Wub; Wp = WubP; base = 1024; }
    else if (t < 5120)  { W = Wbb; Wp = WbbP; base = 3072; }
    else if (t < 7168)  { W = Wl1; Wp = Wl1P; base = 5120; }
    else if (t < 9216)  { W = Wr1; Wp = Wr1P; base = 7168; }
    else if (t < 11264) { W = Wl2; Wp = Wl2P; base = 9216; }
    else if (t < 13312) { W = Wr2; Wp = Wr2P; base = 11264; }
    else if (t < 17408) { W = Wf1; Wp = Wf1P; base = 13312; }
    else return;
    int tt = t - base;
    int lane = tt & 63;
    int n    = (tt >> 6) & 7;
    int kk   = tt >> 9;
    int lr = lane & 15, lg = lane >> 4;
    short8 v;
#pragma unroll
    for (int j = 0; j < 8; j++) {
        float f = W[(size_t)(kk * 32 + lg * 8 + j) * HD + (n * 16 + lr)];
        v[j] = f2bs(f);
    }
    *(short8*)(Wp + (size_t)tt * 8) = v;
}

// ---------------- MFMA GEMM: out = [relu](A1@W1 [+ A2@W2] + bias) [* scale] ----
template<int KS1, int KS2, bool RELU>
__global__ __launch_bounds__(256) void k_mgemm(
    const short* __restrict__ A1, const short* __restrict__ Wp1,
    const short* __restrict__ A2, const short* __restrict__ Wp2,
    const float* __restrict__ bias, const float* __restrict__ scale,
    bf16* __restrict__ out, int nrows) {
    const int wv   = threadIdx.x >> 6;
    const int lane = threadIdx.x & 63;
    const int row0 = blockIdx.x * 64 + wv * 16;
    if (row0 >= nrows) return;
    const int lr = lane & 15, lg = lane >> 4;

    f32x4 acc[8];
#pragma unroll
    for (int n = 0; n < 8; n++) acc[n] = (f32x4){0.f, 0.f, 0.f, 0.f};

    {
        const short* a1p = A1 + (size_t)(row0 + lr) * (KS1 * 32) + lg * 8;
#pragma unroll
        for (int kk = 0; kk < KS1; kk++) {
            short8 af = *(const short8*)(a1p + kk * 32);
            const short* wp = Wp1 + ((size_t)(kk * 8) * 64 + lane) * 8;
#pragma unroll
            for (int n = 0; n < 8; n++) {
                short8 bfr = *(const short8*)(wp + (size_t)n * 64 * 8);
                acc[n] = __builtin_amdgcn_mfma_f32_16x16x32_bf16(af, bfr, acc[n], 0, 0, 0);
            }
        }
    }
    if constexpr (KS2 > 0) {
        const short* a2p = A2 + (size_t)(row0 + lr) * (KS2 * 32) + lg * 8;
#pragma unroll
        for (int kk = 0; kk < KS2; kk++) {
            short8 af = *(const short8*)(a2p + kk * 32);
            const short* wp = Wp2 + ((size_t)(kk * 8) * 64 + lane) * 8;
#pragma unroll
            for (int n = 0; n < 8; n++) {
                short8 bfr = *(const short8*)(wp + (size_t)n * 64 * 8);
                acc[n] = __builtin_amdgcn_mfma_f32_16x16x32_bf16(af, bfr, acc[n], 0, 0, 0);
            }
        }
    }
    float scr[4] = {1.f, 1.f, 1.f, 1.f};
    if (scale) {
#pragma unroll
        for (int r = 0; r < 4; r++) scr[r] = scale[row0 + lg * 4 + r];
    }
#pragma unroll
    for (int n = 0; n < 8; n++) {
        int col = n * 16 + lr;
        float bv = bias[col];
#pragma unroll
        for (int r = 0; r < 4; r++) {
            int row = row0 + lg * 4 + r;
            float v = acc[n][r] + bv;
            if (RELU) v = fmaxf(v, 0.0f);
            v *= scr[r];
            out[(size_t)row * HD + col] = __float2bfloat16(v);
        }
    }
}

// ---------------- MFMA attention head ----------------
__global__ __launch_bounds__(256) void k_attn(
    const short* __restrict__ A1, const short* __restrict__ Wp1,
    const short* __restrict__ A2, const short* __restrict__ Wp2,
    const float* __restrict__ bias, const float* __restrict__ Wf2,
    const float* __restrict__ bf2v, float2* __restrict__ attn, int nrows) {
    const int wv   = threadIdx.x >> 6;
    const int lane = threadIdx.x & 63;
    const int row0 = blockIdx.x * 64 + wv * 16;
    if (row0 >= nrows) return;
    const int lr = lane & 15, lg = lane >> 4;

    f32x4 acc[8];
#pragma unroll
    for (int n = 0; n < 8; n++) acc[n] = (f32x4){0.f, 0.f, 0.f, 0.f};

    {
        const short* a1p = A1 + (size_t)(row0 + lr) * 128 + lg * 8;
#pragma unroll
        for (int kk = 0; kk < 4; kk++) {
            short8 af = *(const short8*)(a1p + kk * 32);
            const short* wp = Wp1 + ((size_t)(kk * 8) * 64 + lane) * 8;
#pragma unroll
            for (int n = 0; n < 8; n++) {
                short8 bfr = *(const short8*)(wp + (size_t)n * 64 * 8);
                acc[n] = __builtin_amdgcn_mfma_f32_16x16x32_bf16(af, bfr, acc[n], 0, 0, 0);
            }
        }
    }
    {
        const short* a2p = A2 + (size_t)(row0 + lr) * 128 + lg * 8;
#pragma unroll
        for (int kk = 0; kk < 4; kk++) {
            short8 af = *(const short8*)(a2p + kk * 32);
            const short* wp = Wp2 + ((size_t)(kk * 8) * 64 + lane) * 8;
#pragma unroll
            for (int n = 0; n < 8; n++) {
                short8 bfr = *(const short8*)(wp + (size_t)n * 64 * 8);
                acc[n] = __builtin_amdgcn_mfma_f32_16x16x32_bf16(af, bfr, acc[n], 0, 0, 0);
            }
        }
    }
    float q0[4] = {0.f, 0.f, 0.f, 0.f};
    float q1[4] = {0.f, 0.f, 0.f, 0.f};
#pragma unroll
    for (int n = 0; n < 8; n++) {
        int col = n * 16 + lr;
        float bv = bias[col];
        float2 w2 = ((const float2*)Wf2)[col];
#pragma unroll
        for (int r = 0; r < 4; r++) {
            float tv = fmaxf(acc[n][r] + bv, 0.0f);
            q0[r] = fmaf(tv, w2.x, q0[r]);
            q1[r] = fmaf(tv, w2.y, q1[r]);
        }
    }
#pragma unroll
    for (int off = 1; off <= 8; off <<= 1) {
#pragma unroll
        for (int r = 0; r < 4; r++) {
            q0[r] += __shfl_xor(q0[r], off, 64);
            q1[r] += __shfl_xor(q1[r], off, 64);
        }
    }
    if (lr == 0) {
        float b0 = bf2v[0], b1 = bf2v[1];
#pragma unroll
        for (int r = 0; r < 4; r++) {
            int row = row0 + lg * 4 + r;
            float s0 = q0[r] + b0;
            float s1 = q1[r] + b1;
            float m  = fmaxf(s0, s1);
            float e0 = expf(s0 - m), e1 = expf(s1 - m);
            float inv = 1.0f / (e0 + e1);
            attn[row] = make_float2(e0 * inv, e1 * inv);
        }
    }
}

// fused = attn.x*collab + attn.y*content  (elementwise, int4-vectorized)
__global__ void k_fuse2(const float2* __restrict__ attn,
                        const bf16* __restrict__ collab, const bf16* __restrict__ content,
                        bf16* __restrict__ fused) {
    int idx = blockIdx.x * blockDim.x + threadIdx.x;
    if (idx >= B_N * 16) return;
    int row = idx >> 4, l = idx & 15;
    float2 a = attn[row];
    float c[8], h[8], o[8];
    unp8(((const int4*)(collab + (size_t)row * HD))[l], c);
    unp8(((const int4*)(content + (size_t)row * HD))[l], h);
#pragma unroll
    for (int i = 0; i < 8; i++) o[i] = a.x * c[i] + a.y * h[i];
    ((int4*)(fused + (size_t)row * HD))[l] = pack8bf(o);
}

// ---------------- CSR build: per-(node,split) count -> scan -> bucketed fill ----

__global__ void k_cnt_ub2(const int* __restrict__ us, const int* __restrict__ ud,
                          int* __restrict__ cnt2) {
    int e = blockIdx.x * blockDim.x + threadIdx.x;
    if (e < NE_UB) {
        int sp = e / LE_UB;
        atomicAdd(&cnt2[us[e] * SPL + sp], 1);
        atomicAdd(&cnt2[(U_N + ud[e]) * SPL + sp], 1);
    }
}

__global__ void k_cnt_bb2(const int* __restrict__ bd, int* __restrict__ cnt2) {
    int e = blockIdx.x * blockDim.x + threadIdx.x;
    if (e < NE_BB) {
        int sp = e / LE_BB;
        atomicAdd(&cnt2[bd[e] * SPL + sp], 1);
    }
}

__global__ void k_dinv2(const int* __restrict__ rs2, float* __restrict__ dsc,
                        int* __restrict__ rsn) {
    int i = blockIdx.x * blockDim.x + threadIdx.x;
    if (i < N_TOT) {
        int s = rs2[i * SPL];
        int e = (i == N_TOT - 1) ? (2 * NE_UB) : rs2[(i + 1) * SPL];
        rsn[i] = s;
        dsc[i] = 1.0f / sqrtf((float)max(e - s, 1));
    }
}

__global__ void k_rsx_bb(const int* __restrict__ rs2, int* __restrict__ rsn) {
    int i = blockIdx.x * blockDim.x + threadIdx.x;
    if (i < B_N) rsn[i] = rs2[i * SPL];
}

__global__ void k_scan1(const int* __restrict__ cnt, int* __restrict__ rs,
                        int* __restrict__ bsum, int n) {
    __shared__ int ts[256];
    const int t = threadIdx.x;
    const int base = blockIdx.x * 1024 + t * 4;
    int v0 = (base + 0 < n) ? cnt[base + 0] : 0;
    int v1 = (base + 1 < n) ? cnt[base + 1] : 0;
    int v2 = (base + 2 < n) ? cnt[base + 2] : 0;
    int v3 = (base + 3 < n) ? cnt[base + 3] : 0;
    int local = v0 + v1 + v2 + v3;
    ts[t] = local;
    __syncthreads();
    for (int off = 1; off < 256; off <<= 1) {
        int x = (t >= off) ? ts[t - off] : 0;
        __syncthreads();
        ts[t] += x;
        __syncthreads();
    }
    int ex = ts[t] - local;
    if (base + 0 < n) rs[base + 0] = ex;
    if (base + 1 < n) rs[base + 1] = ex + v0;
    if (base + 2 < n) rs[base + 2] = ex + v0 + v1;
    if (base + 3 < n) rs[base + 3] = ex + v0 + v1 + v2;
    if (t == 0) bsum[blockIdx.x] = ts[255];
}

__global__ void k_scan2(int* __restrict__ bsum, int nb) {
    __shared__ int ts[256];
    const int t = threadIdx.x;
    const int base = t * 4;
    int v0 = (base + 0 < nb) ? bsum[base + 0] : 0;
    int v1 = (base + 1 < nb) ? bsum[base + 1] : 0;
    int v2 = (base + 2 < nb) ? bsum[base + 2] : 0;
    int v3 = (base + 3 < nb) ? bsum[base + 3] : 0;
    int local = v0 + v1 + v2 + v3;
    ts[t] = local;
    __syncthreads();
    for (int off = 1; off < 256; off <<= 1) {
        int x = (t >= off) ? ts[t - off] : 0;
        __syncthreads();
        ts[t] += x;
        __syncthreads();
    }
    int ex = ts[t] - local;
    if (base + 0 < nb) bsum[base + 0] = ex;
    if (base + 1 < nb) bsum[base + 1] = ex + v0;
    if (base + 2 < nb) bsum[base + 2] = ex + v0 + v1;
    if (base + 3 < nb) bsum[base + 3] = ex + v0 + v1 + v2;
}

__global__ void k_scan3(int* __restrict__ rs, const int* __restrict__ bsum, int n) {
    int i = blockIdx.x * blockDim.x + threadIdx.x;
    if (i < n) rs[i] += bsum[i >> 10];
}

__global__ __launch_bounds__(1024) void k_fill_ub4(const int* __restrict__ us,
                                                   const int* __restrict__ ud,
                                                   const int* __restrict__ rs2,
                                                   int* __restrict__ eidx) {
    __shared__ int cur[UPB];
    const int bk = blockIdx.x >> 2;      // bucket
    const int sp = blockIdx.x & 3;       // split
    const bool userSide = bk < NBU;
    int node0, nn, rbase, add;
    const int *keys, *vals;
    if (userSide) {
        node0 = bk * UPB;
        nn    = min(UPB, U_N - node0);
        rbase = node0;
        keys  = us;
        vals  = ud;
        add   = U_N;
    } else {
        int b = bk - NBU;
        node0 = b * BPB;
        nn    = min(BPB, B_N - node0);
        rbase = U_N + node0;
        keys  = ud;
        vals  = us;
        add   = 0;
    }
    for (int i = threadIdx.x; i < nn; i += 1024)
        cur[i] = rs2[(size_t)(rbase + i) * SPL + sp];
    __syncthreads();
    const int4* k4 = (const int4*)keys;
    const int4* v4 = (const int4*)vals;
    const int q0 = sp * (LE_UB / 4), q1 = q0 + LE_UB / 4;
    for (int q = q0 + threadIdx.x; q < q1; q += 1024) {
        int4 kv = k4[q];
        int4 vv = v4[q];
        int ka[4] = {kv.x, kv.y, kv.z, kv.w};
        int va[4] = {vv.x, vv.y, vv.z, vv.w};
#pragma unroll
        for (int i = 0; i < 4; i++) {
            unsigned rel = (unsigned)(ka[i] - node0);
            if (rel < (unsigned)nn) {
                int p = atomicAdd(&cur[rel], 1);
                eidx[p] = va[i] + add;
            }
        }
    }
}

__global__ __launch_bounds__(1024) void k_fill_bb4(const int* __restrict__ bs,
                                                   const int* __restrict__ bd,
                                                   const int* __restrict__ rs2,
                                                   int* __restrict__ eidx) {
    __shared__ int cur[BPB2];
    const int bk = blockIdx.x >> 2;
    const int sp = blockIdx.x & 3;
    const int node0 = bk * BPB2;
    const int nn    = min(BPB2, B_N - node0);
    for (int i = threadIdx.x; i < nn; i += 1024)
        cur[i] = rs2[(size_t)(node0 + i) * SPL + sp];
    __syncthreads();
    const int4* k4 = (const int4*)bd;
    const int4* v4 = (const int4*)bs;
    const int q0 = sp * (LE_BB / 4), q1 = q0 + LE_BB / 4;
    for (int q = q0 + threadIdx.x; q < q1; q += 1024) {
        int4 kv = k4[q];
        int4 vv = v4[q];
        int ka[4] = {kv.x, kv.y, kv.z, kv.w};
        int va[4] = {vv.x, vv.y, vv.z, vv.w};
#pragma unroll
        for (int i = 0; i < 4; i++) {
            unsigned rel = (unsigned)(ka[i] - node0);
            if (rel < (unsigned)nn) {
                int p = atomicAdd(&cur[rel], 1);
                eidx[p] = va[i];
            }
        }
    }
}

// ---------------- pull-mode propagation (pre-scaled tables) ----------------
// Side-phased: launched once for user nodes [0,U_N), once for books [U_N,N_TOT)
// so each phase's gather working set is one bipartite side (12.8 / 25.6 MB)
// instead of the full 38.4 MB table -> better per-XCD L2 hit rate.

__global__ void k_gather1(const int* __restrict__ rs, const int* __restrict__ eidx,
                          const float* __restrict__ dsc,
                          const bf16* __restrict__ x0s, bf16* __restrict__ x1s,
                          int wbase, int wcnt) {
    int wid  = (blockIdx.x * blockDim.x + threadIdx.x) >> 6;
    int lane = threadIdx.x & 63;
    if (wid >= wcnt) return;
    int w = wbase + wid;
    int g = lane >> 4, l = lane & 15;
    int s = rs[w];
    int e = (w == N_TOT - 1) ? (2 * NE_UB) : rs[w + 1];
    s = __builtin_amdgcn_readfirstlane(s);
    e = __builtin_amdgcn_readfirstlane(e);
    float acc[8] = {0.f, 0.f, 0.f, 0.f, 0.f, 0.f, 0.f, 0.f};
    for (int j0 = s; j0 < e; j0 += 4) {
        int j = j0 + g;
        if (j < e) {
            int nb = eidx[j];
            int4 rv = ((const int4*)(x0s + (size_t)nb * HD))[l];
            add8(acc, rv);
        }
    }
    xgred(acc);
    if (g == 0) {
        float nd = dsc[w];
        float s2 = nd * nd;
#pragma unroll
        for (int i = 0; i < 8; i++) acc[i] *= s2;
        ((int4*)(x1s + (size_t)w * HD))[l] = pack8bf(acc);
    }
}

__global__ void k_gather2(const int* __restrict__ rs, const int* __restrict__ eidx,
                          const float* __restrict__ dsc,
                          const bf16* __restrict__ x0s, const bf16* __restrict__ x1s,
                          bf16* __restrict__ xf16, int wbase, int wcnt) {
    int wid  = (blockIdx.x * blockDim.x + threadIdx.x) >> 6;
    int lane = threadIdx.x & 63;
    if (wid >= wcnt) return;
    int w = wbase + wid;
    int g = lane >> 4, l = lane & 15;
    int s = rs[w];
    int e = (w == N_TOT - 1) ? (2 * NE_UB) : rs[w + 1];
    s = __builtin_amdgcn_readfirstlane(s);
    e = __builtin_amdgcn_readfirstlane(e);
    float acc[8] = {0.f, 0.f, 0.f, 0.f, 0.f, 0.f, 0.f, 0.f};
    for (int j0 = s; j0 < e; j0 += 4) {
        int j = j0 + g;
        if (j < e) {
            int nb = eidx[j];
            int4 rv = ((const int4*)(x1s + (size_t)nb * HD))[l];
            add8(acc, rv);
        }
    }
    xgred(acc);
    if (g == 0) {
        float nd = dsc[w];
        float sd = 1.0f / nd;
        float d0[8], d1[8];
        unp8(((const int4*)(x0s + (size_t)w * HD))[l], d0);
        unp8(((const int4*)(x1s + (size_t)w * HD))[l], d1);
        float o[8];
#pragma unroll
        for (int i = 0; i < 8; i++)
            o[i] = (acc[i] * nd + (d0[i] + d1[i]) * sd) * (1.0f / 3.0f);
        ((int4*)(xf16 + (size_t)w * HD))[l] = pack8bf(o);
    }
}

__global__ void k_gather_bb(const int* __restrict__ rs, const int* __restrict__ eidx,
                            const bf16* __restrict__ h16, bf16* __restrict__ agg16) {
    int w    = (blockIdx.x * blockDim.x + threadIdx.x) >> 6;
    int lane = threadIdx.x & 63;
    if (w >= B_N) return;
    int g = lane >> 4, l = lane & 15;
    int s = rs[w];
    int e = (w == B_N - 1) ? NE_BB : rs[w + 1];
    s = __builtin_amdgcn_readfirstlane(s);
    e = __builtin_amdgcn_readfirstlane(e);
    float acc[8] = {0.f, 0.f, 0.f, 0.f, 0.f, 0.f, 0.f, 0.f};
    for (int j0 = s; j0 < e; j0 += 4) {
        int j = j0 + g;
        if (j < e) {
            int nb = eidx[j];
            int4 rv = ((const int4*)(h16 + (size_t)nb * HD))[l];
            add8(acc, rv);
        }
    }
    xgred(acc);
    if (g == 0) {
        float inv = 1.0f / fmaxf((float)(e - s), 1.0f);
#pragma unroll
        for (int i = 0; i < 8; i++) acc[i] *= inv;
        ((int4*)(agg16 + (size_t)w * HD))[l] = pack8bf(acc);
    }
}

// 4 predictions per wave, 16 lanes x 16B (int4 of 8 bf16) per row
__global__ void k_score(const int* __restrict__ pu, const int* __restrict__ pb,
                        const bf16* __restrict__ uemb16, const bf16* __restrict__ fused16,
                        float* __restrict__ out) {
    int wid  = (blockIdx.x * blockDim.x + threadIdx.x) >> 6;
    int lane = threadIdx.x & 63;
    int g = lane >> 4;
    int l = lane & 15;
    int p = wid * 4 + g;
    if (p >= NP) return;
    int u = pu[p];
    int b = pb[p];
    int4 av = ((const int4*)(uemb16 + (size_t)u * HD))[l];
    int4 fv = ((const int4*)(fused16 + (size_t)b * HD))[l];
    const int* ap = (const int*)&av;
    const int* fp = (const int*)&fv;
    float s = 0.0f;
#pragma unroll
    for (int i = 0; i < 4; i++) {
        bf162 a2 = *(const bf162*)&ap[i];
        bf162 f2 = *(const bf162*)&fp[i];
        s = fmaf(b2f(a2.x), b2f(f2.x), s);
        s = fmaf(b2f(a2.y), b2f(f2.y), s);
    }
#pragma unroll
    for (int off = 8; off > 0; off >>= 1) s += __shfl_xor(s, off, 64);
    if (l == 0) out[p] = s;
}

extern "C" void kernel_launch(void* const* d_in, const int* in_sizes, int n_in,
                              void* d_out, int out_size, void* d_ws, size_t ws_size,
                              hipStream_t stream) {
    const float* user_x = (const float*)d_in[0];
    const float* book_x = (const float*)d_in[1];
    const int*   ub_src = (const int*)d_in[2];
    const int*   ub_dst = (const int*)d_in[3];
    const int*   bb_src = (const int*)d_in[4];
    const int*   bb_dst = (const int*)d_in[5];
    const int*   pred_u = (const int*)d_in[6];
    const int*   pred_b = (const int*)d_in[7];
    const float* Wu   = (const float*)d_in[8];
    const float* bu   = (const float*)d_in[9];
    const float* Wub  = (const float*)d_in[10];
    const float* bub  = (const float*)d_in[11];
    const float* Wbb  = (const float*)d_in[12];
    const float* bbb  = (const float*)d_in[13];
    const float* Wl1  = (const float*)d_in[14];
    const float* bl1  = (const float*)d_in[15];
    const float* Wr1  = (const float*)d_in[16];
    const float* Wl2  = (const float*)d_in[17];
    const float* bl2  = (const float*)d_in[18];
    const float* Wr2  = (const float*)d_in[19];
    const float* Wf1  = (const float*)d_in[20];
    const float* bf1v = (const float*)d_in[21];
    const float* Wf2  = (const float*)d_in[22];
    const float* bf2v = (const float*)d_in[23];
    float* out = (float*)d_out;

    // ---- workspace layout: unchanged from round 7 (verified no-overlap) ----
    float* ws = (float*)d_ws;
    const size_t need = 30960000ull * sizeof(float);
    if (ws_size < need) return;

    float* dsc     = ws;
    int*   rs_ub   = (int*)(ws + 300000);
    int*   rs_bb   = (int*)(ws + 500000);
    int*   bsum    = (int*)(ws + 550000);
    int*   eidx    = (int*)(ws + 560000);
    int*   cnt2_ub = (int*)(ws + 2160000);     // 600K
    int*   rs2_ub  = (int*)(ws + 2760000);     // 600K
    int*   cnt2_bb = (int*)(ws + 11760000);    // 200K
    int*   rs2_bb  = (int*)(ws + 11960000);    // 200K
    bf16*  X0s     = (bf16*)(ws + 2160000);
    bf16*  X1s     = (bf16*)(ws + 11760000);
    bf16*  XF16    = (bf16*)(ws + 21360000);

    // phase A aliases
    short* xu16  = (short*)(ws + 11760000);
    short* xb16  = (short*)(ws + 14960000);
    short* WuP   = (short*)(ws + 21360000);
    short* WubP  = (short*)(ws + 21364096);

    // content-phase aliases
    short* xb16c     = (short*)(ws + 2160000);
    bf16*  h16a      = (bf16*)(ws + 5360000);
    bf16*  h16b      = (bf16*)(ws + 8560000);
    bf16*  agg16     = (bf16*)(ws + 11760000);
    bf16*  content16 = (bf16*)(ws + 14960000);
    bf16*  fused16   = (bf16*)(ws + 18160000);
    float2* attnb    = (float2*)(ws + 11760000);
    bf16*  uemb16    = XF16;
    bf16*  collab16  = XF16 + (size_t)U_N * HD;
    short* WbbP = (short*)(ws + 150000);
    short* Wl1P = WbbP + 16384;
    short* Wr1P = WbbP + 32768;
    short* Wl2P = WbbP + 49152;
    short* Wr2P = WbbP + 65536;
    short* Wf1P = WbbP + 81920;                   // 32768 shorts (KTOT=256)

    // ---- phase A: bf16 inputs (1 launch) + all weight packs (1 launch) ----
    {
        int nA = U_N * DU, nB = B_N * DB;
        k_f2b2<<<((nA + nB) / 8 + 255) / 256, 256, 0, stream>>>(
            user_x, xu16, nA, book_x, xb16, nB);
    }
    k_pack_all<<<(17408 + 255) / 256, 256, 0, stream>>>(
        Wu, Wub, Wbb, Wl1, Wr1, Wl2, Wr2, Wf1,
        WuP, WubP, WbbP, Wl1P, Wr1P, Wl2P, Wr2P, Wf1P);

    // ---- CSR build (ub graph, split CSR) ----
    hipMemsetAsync(cnt2_ub, 0, (size_t)N_TOT * SPL * sizeof(int), stream);
    k_cnt_ub2<<<(NE_UB + 255) / 256, 256, 0, stream>>>(ub_src, ub_dst, cnt2_ub);
    {
        int n = N_TOT * SPL;
        int nb = (n + 1023) / 1024;
        k_scan1<<<nb, 256, 0, stream>>>(cnt2_ub, rs2_ub, bsum, n);
        k_scan2<<<1, 256, 0, stream>>>(bsum, nb);
        k_scan3<<<(n + 255) / 256, 256, 0, stream>>>(rs2_ub, bsum, n);
    }
    k_dinv2<<<(N_TOT + 255) / 256, 256, 0, stream>>>(rs2_ub, dsc, rs_ub);
    k_fill_ub4<<<(NBU + NBB) * SPL, 1024, 0, stream>>>(ub_src, ub_dst, rs2_ub, eidx);

    // ---- init GEMMs (degree-pre-scaled; overwrite cnt2/rs2_ub region) ----
    k_mgemm<2, 0, false><<<(U_N + 63) / 64, 256, 0, stream>>>(
        xu16, WuP, nullptr, nullptr, bu, dsc, X0s, U_N);
    k_mgemm<4, 0, false><<<(B_N + 63) / 64, 256, 0, stream>>>(
        xb16, WubP, nullptr, nullptr, bub, dsc + U_N, X0s + (size_t)U_N * HD, B_N);

    // ---- LightGCN propagation (side-phased for L2 locality) ----
    k_gather1<<<(U_N + 3) / 4, 256, 0, stream>>>(rs_ub, eidx, dsc, X0s, X1s, 0, U_N);
    k_gather1<<<(B_N + 3) / 4, 256, 0, stream>>>(rs_ub, eidx, dsc, X0s, X1s, U_N, B_N);
    k_gather2<<<(U_N + 3) / 4, 256, 0, stream>>>(rs_ub, eidx, dsc, X0s, X1s, XF16, 0, U_N);
    k_gather2<<<(B_N + 3) / 4, 256, 0, stream>>>(rs_ub, eidx, dsc, X0s, X1s, XF16, U_N, B_N);

    // ---- CSR build (bb graph, split CSR) — X1s region dead ----
    hipMemsetAsync(cnt2_bb, 0, (size_t)B_N * SPL * sizeof(int), stream);
    k_cnt_bb2<<<(NE_BB + 255) / 256, 256, 0, stream>>>(bb_dst, cnt2_bb);
    {
        int n = B_N * SPL;
        int nb = (n + 1023) / 1024;
        k_scan1<<<nb, 256, 0, stream>>>(cnt2_bb, rs2_bb, bsum, n);
        k_scan2<<<1, 256, 0, stream>>>(bsum, nb);
        k_scan3<<<(n + 255) / 256, 256, 0, stream>>>(rs2_bb, bsum, n);
    }
    k_rsx_bb<<<(B_N + 255) / 256, 256, 0, stream>>>(rs2_bb, rs_bb);
    k_fill_bb4<<<NB2 * SPL, 1024, 0, stream>>>(bb_src, bb_dst, rs2_bb, eidx);

    // ---- content network (all MFMA) ----
    k_f2b<<<(B_N * DB / 8 + 255) / 256, 256, 0, stream>>>(book_x, xb16c, B_N * DB);
    k_mgemm<4, 0, false><<<(B_N + 63) / 64, 256, 0, stream>>>(
        xb16c, WbbP, nullptr, nullptr, bbb, nullptr, h16a, B_N);
    k_gather_bb<<<(B_N + 3) / 4, 256, 0, stream>>>(rs_bb, eidx, h16a, agg16);
    k_mgemm<4, 4, true><<<(B_N + 63) / 64, 256, 0, stream>>>(
        (const short*)agg16, Wl1P, (const short*)h16a, Wr1P, bl1, nullptr, h16b, B_N);
    k_gather_bb<<<(B_N + 3) / 4, 256, 0, stream>>>(rs_bb, eidx, h16b, agg16);
    k_mgemm<4, 4, true><<<(B_N + 63) / 64, 256, 0, stream>>>(
        (const short*)agg16, Wl2P, (const short*)h16b, Wr2P, bl2, nullptr, content16, B_N);

    // ---- fusion (MFMA attn head + elementwise blend) + scores ----
    k_attn<<<(B_N + 63) / 64, 256, 0, stream>>>(
        (const short*)collab16, Wf1P, (const short*)content16, Wf1P + 32768 / 2,
        bf1v, Wf2, bf2v, attnb, B_N);
    k_fuse2<<<(B_N * 16 + 255) / 256, 256, 0, stream>>>(attnb, collab16, content16, fused16);
    k_score<<<NP / 16, 256, 0, stream>>>(pred_u, pred_b, uemb16, fused16, out);
}

// Round 9
// 648.816 us; speedup vs baseline: 1.9054x; 1.0631x over previous
//
#include <hip/hip_runtime.h>
#include <hip/hip_bf16.h>

typedef __hip_bfloat16 bf16;
typedef __hip_bfloat162 bf162;

using short8 = __attribute__((ext_vector_type(8))) short;
using f32x4  = __attribute__((ext_vector_type(4))) float;

#define U_N   100000
#define B_N   50000
#define N_TOT 150000
#define NE_UB 800000
#define NE_BB 600000
#define NP    400000
#define DU    64
#define DB    128
#define HD    128

// bucketed geometry: big buckets + 4-way edge-stream split.
#define SPL   4
#define NBU   32
#define NBB   32
#define UPB   ((U_N + NBU - 1) / NBU)      // 3125 users/bucket (12.5 KB LDS)
#define BPB   ((B_N + NBB - 1) / NBB)      // 1563 books/bucket
#define LE_UB (NE_UB / SPL)                // 200000 edges/slice
#define NB2   64
#define BPB2  ((B_N + NB2 - 1) / NB2)      // 782 books/bucket (bb)
#define LE_BB (NE_BB / SPL)                // 150000 edges/slice

__device__ __forceinline__ float b2f(bf16 v) { return __bfloat162float(v); }
// f32 -> bf16 bits (RNE)
__device__ __forceinline__ short f2bs(float f) {
    unsigned u = __float_as_uint(f);
    unsigned r = (u + 0x7fffu + ((u >> 16) & 1u)) >> 16;
    return (short)r;
}
// add 8 bf16 (packed in int4) into acc[8]
__device__ __forceinline__ void add8(float (&a)[8], int4 rv) {
    const unsigned* p = (const unsigned*)&rv;
#pragma unroll
    for (int i = 0; i < 4; i++) {
        unsigned v = p[i];
        a[2 * i]     += __uint_as_float(v << 16);
        a[2 * i + 1] += __uint_as_float(v & 0xffff0000u);
    }
}
__device__ __forceinline__ void unp8(int4 rv, float (&o)[8]) {
    const unsigned* p = (const unsigned*)&rv;
#pragma unroll
    for (int i = 0; i < 4; i++) {
        unsigned v = p[i];
        o[2 * i]     = __uint_as_float(v << 16);
        o[2 * i + 1] = __uint_as_float(v & 0xffff0000u);
    }
}
__device__ __forceinline__ int4 pack8bf(const float (&a)[8]) {
    unsigned r[4];
#pragma unroll
    for (int i = 0; i < 4; i++) {
        unsigned lo = (unsigned)(unsigned short)f2bs(a[2 * i]);
        unsigned hi = (unsigned)(unsigned short)f2bs(a[2 * i + 1]);
        r[i] = lo | (hi << 16);
    }
    int4 o; o.x = r[0]; o.y = r[1]; o.z = r[2]; o.w = r[3];
    return o;
}
__device__ __forceinline__ void xgred(float (&a)[8]) {
#pragma unroll
    for (int i = 0; i < 8; i++) {
        a[i] += __shfl_xor(a[i], 16, 64);
        a[i] += __shfl_xor(a[i], 32, 64);
    }
}

// ---------------- bf16 conversion + weight packing ----------------

__global__ void k_f2b(const float* __restrict__ in, short* __restrict__ out, int n) {
    int i = (blockIdx.x * blockDim.x + threadIdx.x) * 8;
    if (i >= n) return;
    float4 a = ((const float4*)(in + i))[0];
    float4 b = ((const float4*)(in + i))[1];
    short8 v;
    v[0] = f2bs(a.x); v[1] = f2bs(a.y); v[2] = f2bs(a.z); v[3] = f2bs(a.w);
    v[4] = f2bs(b.x); v[5] = f2bs(b.y); v[6] = f2bs(b.z); v[7] = f2bs(b.w);
    *(short8*)(out + i) = v;
}

// merged: user_x -> xu16 and book_x -> xb16 in one launch
__global__ void k_f2b2(const float* __restrict__ A, short* __restrict__ Ao, int nA,
                       const float* __restrict__ B, short* __restrict__ Bo, int nB) {
    int i = (blockIdx.x * blockDim.x + threadIdx.x) * 8;
    const float* src; short* dst; int off;
    if (i < nA)            { src = A; dst = Ao; off = i; }
    else if (i < nA + nB)  { src = B; dst = Bo; off = i - nA; }
    else return;
    float4 a = ((const float4*)(src + off))[0];
    float4 b = ((const float4*)(src + off))[1];
    short8 v;
    v[0] = f2bs(a.x); v[1] = f2bs(a.y); v[2] = f2bs(a.z); v[3] = f2bs(a.w);
    v[4] = f2bs(b.x); v[5] = f2bs(b.y); v[6] = f2bs(b.z); v[7] = f2bs(b.w);
    *(short8*)(dst + off) = v;
}

// all 8 weight packs in one launch; thread ranges per weight.
__global__ void k_pack_all(const float* __restrict__ Wu,  const float* __restrict__ Wub,
                           const float* __restrict__ Wbb, const float* __restrict__ Wl1,
                           const float* __restrict__ Wr1, const float* __restrict__ Wl2,
                           const float* __restrict__ Wr2, const float* __restrict__ Wf1,
                           short* WuP, short* WubP, short* WbbP, short* Wl1P,
                           short* Wr1P, short* Wl2P, short* Wr2P, short* Wf1P) {
    int t = blockIdx.x * blockDim.x + threadIdx.x;
    const float* W; short* Wp; int base;
    if      (t < 1024)  { W = Wu;  Wp = WuP;  base = 0; }
    else if (t < 3072)  { W = Wub; Wp = WubP; base = 1024; }
    else if (t < 5120)  { W = Wbb; Wp = WbbP; base = 3072; }
    else if (t < 7168)  { W = Wl1; Wp = Wl1P; base = 5120; }
    else if (t < 9216)  { W = Wr1; Wp = Wr1P; base = 7168; }
    else if (t < 11264) { W = Wl2; Wp = Wl2P; base = 9216; }
    else if (t < 13312) { W = Wr2; Wp = Wr2P; base = 11264; }
    else if (t < 17408) { W = Wf1; Wp = Wf1P; base = 13312; }
    else return;
    int tt = t - base;
    int lane = tt & 63;
    int n    = (tt >> 6) & 7;
    int kk   = tt >> 9;
    int lr = lane & 15, lg = lane >> 4;
    short8 v;
#pragma unroll
    for (int j = 0; j < 8; j++) {
        float f = W[(size_t)(kk * 32 + lg * 8 + j) * HD + (n * 16 + lr)];
        v[j] = f2bs(f);
    }
    *(short8*)(Wp + (size_t)tt * 8) = v;
}

// ---------------- MFMA GEMM: out = [relu](A1@W1 [+ A2@W2] + bias) [* scale] ----
template<int KS1, int KS2, bool RELU>
__global__ __launch_bounds__(256) void k_mgemm(
    const short* __restrict__ A1, const short* __restrict__ Wp1,
    const short* __restrict__ A2, const short* __restrict__ Wp2,
    const float* __restrict__ bias, const float* __restrict__ scale,
    bf16* __restrict__ out, int nrows) {
    const int wv   = threadIdx.x >> 6;
    const int lane = threadIdx.x & 63;
    const int row0 = blockIdx.x * 64 + wv * 16;
    if (row0 >= nrows) return;
    const int lr = lane & 15, lg = lane >> 4;

    f32x4 acc[8];
#pragma unroll
    for (int n = 0; n < 8; n++) acc[n] = (f32x4){0.f, 0.f, 0.f, 0.f};

    {
        const short* a1p = A1 + (size_t)(row0 + lr) * (KS1 * 32) + lg * 8;
#pragma unroll
        for (int kk = 0; kk < KS1; kk++) {
            short8 af = *(const short8*)(a1p + kk * 32);
            const short* wp = Wp1 + ((size_t)(kk * 8) * 64 + lane) * 8;
#pragma unroll
            for (int n = 0; n < 8; n++) {
                short8 bfr = *(const short8*)(wp + (size_t)n * 64 * 8);
                acc[n] = __builtin_amdgcn_mfma_f32_16x16x32_bf16(af, bfr, acc[n], 0, 0, 0);
            }
        }
    }
    if constexpr (KS2 > 0) {
        const short* a2p = A2 + (size_t)(row0 + lr) * (KS2 * 32) + lg * 8;
#pragma unroll
        for (int kk = 0; kk < KS2; kk++) {
            short8 af = *(const short8*)(a2p + kk * 32);
            const short* wp = Wp2 + ((size_t)(kk * 8) * 64 + lane) * 8;
#pragma unroll
            for (int n = 0; n < 8; n++) {
                short8 bfr = *(const short8*)(wp + (size_t)n * 64 * 8);
                acc[n] = __builtin_amdgcn_mfma_f32_16x16x32_bf16(af, bfr, acc[n], 0, 0, 0);
            }
        }
    }
    float scr[4] = {1.f, 1.f, 1.f, 1.f};
    if (scale) {
#pragma unroll
        for (int r = 0; r < 4; r++) scr[r] = scale[row0 + lg * 4 + r];
    }
#pragma unroll
    for (int n = 0; n < 8; n++) {
        int col = n * 16 + lr;
        float bv = bias[col];
#pragma unroll
        for (int r = 0; r < 4; r++) {
            int row = row0 + lg * 4 + r;
            float v = acc[n][r] + bv;
            if (RELU) v = fmaxf(v, 0.0f);
            v *= scr[r];
            out[(size_t)row * HD + col] = __float2bfloat16(v);
        }
    }
}

// ---------------- MFMA attention head ----------------
__global__ __launch_bounds__(256) void k_attn(
    const short* __restrict__ A1, const short* __restrict__ Wp1,
    const short* __restrict__ A2, const short* __restrict__ Wp2,
    const float* __restrict__ bias, const float* __restrict__ Wf2,
    const float* __restrict__ bf2v, float2* __restrict__ attn, int nrows) {
    const int wv   = threadIdx.x >> 6;
    const int lane = threadIdx.x & 63;
    const int row0 = blockIdx.x * 64 + wv * 16;
    if (row0 >= nrows) return;
    const int lr = lane & 15, lg = lane >> 4;

    f32x4 acc[8];
#pragma unroll
    for (int n = 0; n < 8; n++) acc[n] = (f32x4){0.f, 0.f, 0.f, 0.f};

    {
        const short* a1p = A1 + (size_t)(row0 + lr) * 128 + lg * 8;
#pragma unroll
        for (int kk = 0; kk < 4; kk++) {
            short8 af = *(const short8*)(a1p + kk * 32);
            const short* wp = Wp1 + ((size_t)(kk * 8) * 64 + lane) * 8;
#pragma unroll
            for (int n = 0; n < 8; n++) {
                short8 bfr = *(const short8*)(wp + (size_t)n * 64 * 8);
                acc[n] = __builtin_amdgcn_mfma_f32_16x16x32_bf16(af, bfr, acc[n], 0, 0, 0);
            }
        }
    }
    {
        const short* a2p = A2 + (size_t)(row0 + lr) * 128 + lg * 8;
#pragma unroll
        for (int kk = 0; kk < 4; kk++) {
            short8 af = *(const short8*)(a2p + kk * 32);
            const short* wp = Wp2 + ((size_t)(kk * 8) * 64 + lane) * 8;
#pragma unroll
            for (int n = 0; n < 8; n++) {
                short8 bfr = *(const short8*)(wp + (size_t)n * 64 * 8);
                acc[n] = __builtin_amdgcn_mfma_f32_16x16x32_bf16(af, bfr, acc[n], 0, 0, 0);
            }
        }
    }
    float q0[4] = {0.f, 0.f, 0.f, 0.f};
    float q1[4] = {0.f, 0.f, 0.f, 0.f};
#pragma unroll
    for (int n = 0; n < 8; n++) {
        int col = n * 16 + lr;
        float bv = bias[col];
        float2 w2 = ((const float2*)Wf2)[col];
#pragma unroll
        for (int r = 0; r < 4; r++) {
            float tv = fmaxf(acc[n][r] + bv, 0.0f);
            q0[r] = fmaf(tv, w2.x, q0[r]);
            q1[r] = fmaf(tv, w2.y, q1[r]);
        }
    }
#pragma unroll
    for (int off = 1; off <= 8; off <<= 1) {
#pragma unroll
        for (int r = 0; r < 4; r++) {
            q0[r] += __shfl_xor(q0[r], off, 64);
            q1[r] += __shfl_xor(q1[r], off, 64);
        }
    }
    if (lr == 0) {
        float b0 = bf2v[0], b1 = bf2v[1];
#pragma unroll
        for (int r = 0; r < 4; r++) {
            int row = row0 + lg * 4 + r;
            float s0 = q0[r] + b0;
            float s1 = q1[r] + b1;
            float m  = fmaxf(s0, s1);
            float e0 = expf(s0 - m), e1 = expf(s1 - m);
            float inv = 1.0f / (e0 + e1);
            attn[row] = make_float2(e0 * inv, e1 * inv);
        }
    }
}

// fused = attn.x*collab + attn.y*content  (elementwise, int4-vectorized)
__global__ void k_fuse2(const float2* __restrict__ attn,
                        const bf16* __restrict__ collab, const bf16* __restrict__ content,
                        bf16* __restrict__ fused) {
    int idx = blockIdx.x * blockDim.x + threadIdx.x;
    if (idx >= B_N * 16) return;
    int row = idx >> 4, l = idx & 15;
    float2 a = attn[row];
    float c[8], h[8], o[8];
    unp8(((const int4*)(collab + (size_t)row * HD))[l], c);
    unp8(((const int4*)(content + (size_t)row * HD))[l], h);
#pragma unroll
    for (int i = 0; i < 8; i++) o[i] = a.x * c[i] + a.y * h[i];
    ((int4*)(fused + (size_t)row * HD))[l] = pack8bf(o);
}

// ---------------- CSR build: bucketed LDS count -> scan -> bucketed fill ----

// Bucketed count v3: (bucket,split) WGs stream their key slice, histogram into
// LDS, write cnt2 slice once. No global atomics (old version: 1.6M scattered
// device atomics = 50 MB of 32B-sector writebacks, 63 us).
__global__ __launch_bounds__(1024) void k_cnt_ub3(const int* __restrict__ us,
                                                  const int* __restrict__ ud,
                                                  int* __restrict__ cnt2) {
    __shared__ int cur[UPB];
    const int bk = blockIdx.x >> 2;
    const int sp = blockIdx.x & 3;
    const bool userSide = bk < NBU;
    int node0, nn, rbase;
    const int* keys;
    if (userSide) {
        node0 = bk * UPB;
        nn    = min(UPB, U_N - node0);
        rbase = node0;
        keys  = us;
    } else {
        int b = bk - NBU;
        node0 = b * BPB;
        nn    = min(BPB, B_N - node0);
        rbase = U_N + node0;
        keys  = ud;
    }
    for (int i = threadIdx.x; i < nn; i += 1024) cur[i] = 0;
    __syncthreads();
    const int4* k4 = (const int4*)keys;
    const int q0 = sp * (LE_UB / 4), q1 = q0 + LE_UB / 4;
    for (int q = q0 + threadIdx.x; q < q1; q += 1024) {
        int4 kv = k4[q];
        int ka[4] = {kv.x, kv.y, kv.z, kv.w};
#pragma unroll
        for (int i = 0; i < 4; i++) {
            unsigned rel = (unsigned)(ka[i] - node0);
            if (rel < (unsigned)nn) atomicAdd(&cur[rel], 1);
        }
    }
    __syncthreads();
    for (int i = threadIdx.x; i < nn; i += 1024)
        cnt2[(size_t)(rbase + i) * SPL + sp] = cur[i];
}

__global__ __launch_bounds__(1024) void k_cnt_bb3(const int* __restrict__ bd,
                                                  int* __restrict__ cnt2) {
    __shared__ int cur[BPB2];
    const int bk = blockIdx.x >> 2;
    const int sp = blockIdx.x & 3;
    const int node0 = bk * BPB2;
    const int nn    = min(BPB2, B_N - node0);
    for (int i = threadIdx.x; i < nn; i += 1024) cur[i] = 0;
    __syncthreads();
    const int4* k4 = (const int4*)bd;
    const int q0 = sp * (LE_BB / 4), q1 = q0 + LE_BB / 4;
    for (int q = q0 + threadIdx.x; q < q1; q += 1024) {
        int4 kv = k4[q];
        int ka[4] = {kv.x, kv.y, kv.z, kv.w};
#pragma unroll
        for (int i = 0; i < 4; i++) {
            unsigned rel = (unsigned)(ka[i] - node0);
            if (rel < (unsigned)nn) atomicAdd(&cur[rel], 1);
        }
    }
    __syncthreads();
    for (int i = threadIdx.x; i < nn; i += 1024)
        cnt2[(size_t)(node0 + i) * SPL + sp] = cur[i];
}

__global__ void k_dinv2(const int* __restrict__ rs2, float* __restrict__ dsc,
                        int* __restrict__ rsn) {
    int i = blockIdx.x * blockDim.x + threadIdx.x;
    if (i < N_TOT) {
        int s = rs2[i * SPL];
        int e = (i == N_TOT - 1) ? (2 * NE_UB) : rs2[(i + 1) * SPL];
        rsn[i] = s;
        dsc[i] = 1.0f / sqrtf((float)max(e - s, 1));
    }
}

__global__ void k_rsx_bb(const int* __restrict__ rs2, int* __restrict__ rsn) {
    int i = blockIdx.x * blockDim.x + threadIdx.x;
    if (i < B_N) rsn[i] = rs2[i * SPL];
}

__global__ void k_scan1(const int* __restrict__ cnt, int* __restrict__ rs,
                        int* __restrict__ bsum, int n) {
    __shared__ int ts[256];
    const int t = threadIdx.x;
    const int base = blockIdx.x * 1024 + t * 4;
    int v0 = (base + 0 < n) ? cnt[base + 0] : 0;
    int v1 = (base + 1 < n) ? cnt[base + 1] : 0;
    int v2 = (base + 2 < n) ? cnt[base + 2] : 0;
    int v3 = (base + 3 < n) ? cnt[base + 3] : 0;
    int local = v0 + v1 + v2 + v3;
    ts[t] = local;
    __syncthreads();
    for (int off = 1; off < 256; off <<= 1) {
        int x = (t >= off) ? ts[t - off] : 0;
        __syncthreads();
        ts[t] += x;
        __syncthreads();
    }
    int ex = ts[t] - local;
    if (base + 0 < n) rs[base + 0] = ex;
    if (base + 1 < n) rs[base + 1] = ex + v0;
    if (base + 2 < n) rs[base + 2] = ex + v0 + v1;
    if (base + 3 < n) rs[base + 3] = ex + v0 + v1 + v2;
    if (t == 0) bsum[blockIdx.x] = ts[255];
}

__global__ void k_scan2(int* __restrict__ bsum, int nb) {
    __shared__ int ts[256];
    const int t = threadIdx.x;
    const int base = t * 4;
    int v0 = (base + 0 < nb) ? bsum[base + 0] : 0;
    int v1 = (base + 1 < nb) ? bsum[base + 1] : 0;
    int v2 = (base + 2 < nb) ? bsum[base + 2] : 0;
    int v3 = (base + 3 < nb) ? bsum[base + 3] : 0;
    int local = v0 + v1 + v2 + v3;
    ts[t] = local;
    __syncthreads();
    for (int off = 1; off < 256; off <<= 1) {
        int x = (t >= off) ? ts[t - off] : 0;
        __syncthreads();
        ts[t] += x;
        __syncthreads();
    }
    int ex = ts[t] - local;
    if (base + 0 < nb) bsum[base + 0] = ex;
    if (base + 1 < nb) bsum[base + 1] = ex + v0;
    if (base + 2 < nb) bsum[base + 2] = ex + v0 + v1;
    if (base + 3 < nb) bsum[base + 3] = ex + v0 + v1 + v2;
}

__global__ void k_scan3(int* __restrict__ rs, const int* __restrict__ bsum, int n) {
    int i = blockIdx.x * blockDim.x + threadIdx.x;
    if (i < n) rs[i] += bsum[i >> 10];
}

__global__ __launch_bounds__(1024) void k_fill_ub4(const int* __restrict__ us,
                                                   const int* __restrict__ ud,
                                                   const int* __restrict__ rs2,
                                                   int* __restrict__ eidx) {
    __shared__ int cur[UPB];
    const int bk = blockIdx.x >> 2;      // bucket
    const int sp = blockIdx.x & 3;       // split
    const bool userSide = bk < NBU;
    int node0, nn, rbase, add;
    const int *keys, *vals;
    if (userSide) {
        node0 = bk * UPB;
        nn    = min(UPB, U_N - node0);
        rbase = node0;
        keys  = us;
        vals  = ud;
        add   = U_N;
    } else {
        int b = bk - NBU;
        node0 = b * BPB;
        nn    = min(BPB, B_N - node0);
        rbase = U_N + node0;
        keys  = ud;
        vals  = us;
        add   = 0;
    }
    for (int i = threadIdx.x; i < nn; i += 1024)
        cur[i] = rs2[(size_t)(rbase + i) * SPL + sp];
    __syncthreads();
    const int4* k4 = (const int4*)keys;
    const int4* v4 = (const int4*)vals;
    const int q0 = sp * (LE_UB / 4), q1 = q0 + LE_UB / 4;
    for (int q = q0 + threadIdx.x; q < q1; q += 1024) {
        int4 kv = k4[q];
        int4 vv = v4[q];
        int ka[4] = {kv.x, kv.y, kv.z, kv.w};
        int va[4] = {vv.x, vv.y, vv.z, vv.w};
#pragma unroll
        for (int i = 0; i < 4; i++) {
            unsigned rel = (unsigned)(ka[i] - node0);
            if (rel < (unsigned)nn) {
                int p = atomicAdd(&cur[rel], 1);
                eidx[p] = va[i] + add;
            }
        }
    }
}

__global__ __launch_bounds__(1024) void k_fill_bb4(const int* __restrict__ bs,
                                                   const int* __restrict__ bd,
                                                   const int* __restrict__ rs2,
                                                   int* __restrict__ eidx) {
    __shared__ int cur[BPB2];
    const int bk = blockIdx.x >> 2;
    const int sp = blockIdx.x & 3;
    const int node0 = bk * BPB2;
    const int nn    = min(BPB2, B_N - node0);
    for (int i = threadIdx.x; i < nn; i += 1024)
        cur[i] = rs2[(size_t)(node0 + i) * SPL + sp];
    __syncthreads();
    const int4* k4 = (const int4*)bd;
    const int4* v4 = (const int4*)bs;
    const int q0 = sp * (LE_BB / 4), q1 = q0 + LE_BB / 4;
    for (int q = q0 + threadIdx.x; q < q1; q += 1024) {
        int4 kv = k4[q];
        int4 vv = v4[q];
        int ka[4] = {kv.x, kv.y, kv.z, kv.w};
        int va[4] = {vv.x, vv.y, vv.z, vv.w};
#pragma unroll
        for (int i = 0; i < 4; i++) {
            unsigned rel = (unsigned)(ka[i] - node0);
            if (rel < (unsigned)nn) {
                int p = atomicAdd(&cur[rel], 1);
                eidx[p] = va[i];
            }
        }
    }
}

// ---------------- pull-mode propagation (pre-scaled tables, side-phased) ----

__global__ void k_gather1(const int* __restrict__ rs, const int* __restrict__ eidx,
                          const float* __restrict__ dsc,
                          const bf16* __restrict__ x0s, bf16* __restrict__ x1s,
                          int wbase, int wcnt) {
    int wid  = (blockIdx.x * blockDim.x + threadIdx.x) >> 6;
    int lane = threadIdx.x & 63;
    if (wid >= wcnt) return;
    int w = wbase + wid;
    int g = lane >> 4, l = lane & 15;
    int s = rs[w];
    int e = (w == N_TOT - 1) ? (2 * NE_UB) : rs[w + 1];
    s = __builtin_amdgcn_readfirstlane(s);
    e = __builtin_amdgcn_readfirstlane(e);
    float acc[8] = {0.f, 0.f, 0.f, 0.f, 0.f, 0.f, 0.f, 0.f};
    for (int j0 = s; j0 < e; j0 += 4) {
        int j = j0 + g;
        if (j < e) {
            int nb = eidx[j];
            int4 rv = ((const int4*)(x0s + (size_t)nb * HD))[l];
            add8(acc, rv);
        }
    }
    xgred(acc);
    if (g == 0) {
        float nd = dsc[w];
        float s2 = nd * nd;
#pragma unroll
        for (int i = 0; i < 8; i++) acc[i] *= s2;
        ((int4*)(x1s + (size_t)w * HD))[l] = pack8bf(acc);
    }
}

__global__ void k_gather2(const int* __restrict__ rs, const int* __restrict__ eidx,
                          const float* __restrict__ dsc,
                          const bf16* __restrict__ x0s, const bf16* __restrict__ x1s,
                          bf16* __restrict__ xf16, int wbase, int wcnt) {
    int wid  = (blockIdx.x * blockDim.x + threadIdx.x) >> 6;
    int lane = threadIdx.x & 63;
    if (wid >= wcnt) return;
    int w = wbase + wid;
    int g = lane >> 4, l = lane & 15;
    int s = rs[w];
    int e = (w == N_TOT - 1) ? (2 * NE_UB) : rs[w + 1];
    s = __builtin_amdgcn_readfirstlane(s);
    e = __builtin_amdgcn_readfirstlane(e);
    float acc[8] = {0.f, 0.f, 0.f, 0.f, 0.f, 0.f, 0.f, 0.f};
    for (int j0 = s; j0 < e; j0 += 4) {
        int j = j0 + g;
        if (j < e) {
            int nb = eidx[j];
            int4 rv = ((const int4*)(x1s + (size_t)nb * HD))[l];
            add8(acc, rv);
        }
    }
    xgred(acc);
    if (g == 0) {
        float nd = dsc[w];
        float sd = 1.0f / nd;
        float d0[8], d1[8];
        unp8(((const int4*)(x0s + (size_t)w * HD))[l], d0);
        unp8(((const int4*)(x1s + (size_t)w * HD))[l], d1);
        float o[8];
#pragma unroll
        for (int i = 0; i < 8; i++)
            o[i] = (acc[i] * nd + (d0[i] + d1[i]) * sd) * (1.0f / 3.0f);
        ((int4*)(xf16 + (size_t)w * HD))[l] = pack8bf(o);
    }
}

__global__ void k_gather_bb(const int* __restrict__ rs, const int* __restrict__ eidx,
                            const bf16* __restrict__ h16, bf16* __restrict__ agg16) {
    int w    = (blockIdx.x * blockDim.x + threadIdx.x) >> 6;
    int lane = threadIdx.x & 63;
    if (w >= B_N) return;
    int g = lane >> 4, l = lane & 15;
    int s = rs[w];
    int e = (w == B_N - 1) ? NE_BB : rs[w + 1];
    s = __builtin_amdgcn_readfirstlane(s);
    e = __builtin_amdgcn_readfirstlane(e);
    float acc[8] = {0.f, 0.f, 0.f, 0.f, 0.f, 0.f, 0.f, 0.f};
    for (int j0 = s; j0 < e; j0 += 4) {
        int j = j0 + g;
        if (j < e) {
            int nb = eidx[j];
            int4 rv = ((const int4*)(h16 + (size_t)nb * HD))[l];
            add8(acc, rv);
        }
    }
    xgred(acc);
    if (g == 0) {
        float inv = 1.0f / fmaxf((float)(e - s), 1.0f);
#pragma unroll
        for (int i = 0; i < 8; i++) acc[i] *= inv;
        ((int4*)(agg16 + (size_t)w * HD))[l] = pack8bf(acc);
    }
}

// 4 predictions per wave, 16 lanes x 16B (int4 of 8 bf16) per row
__global__ void k_score(const int* __restrict__ pu, const int* __restrict__ pb,
                        const bf16* __restrict__ uemb16, const bf16* __restrict__ fused16,
                        float* __restrict__ out) {
    int wid  = (blockIdx.x * blockDim.x + threadIdx.x) >> 6;
    int lane = threadIdx.x & 63;
    int g = lane >> 4;
    int l = lane & 15;
    int p = wid * 4 + g;
    if (p >= NP) return;
    int u = pu[p];
    int b = pb[p];
    int4 av = ((const int4*)(uemb16 + (size_t)u * HD))[l];
    int4 fv = ((const int4*)(fused16 + (size_t)b * HD))[l];
    const int* ap = (const int*)&av;
    const int* fp = (const int*)&fv;
    float s = 0.0f;
#pragma unroll
    for (int i = 0; i < 4; i++) {
        bf162 a2 = *(const bf162*)&ap[i];
        bf162 f2 = *(const bf162*)&fp[i];
        s = fmaf(b2f(a2.x), b2f(f2.x), s);
        s = fmaf(b2f(a2.y), b2f(f2.y), s);
    }
#pragma unroll
    for (int off = 8; off > 0; off >>= 1) s += __shfl_xor(s, off, 64);
    if (l == 0) out[p] = s;
}

extern "C" void kernel_launch(void* const* d_in, const int* in_sizes, int n_in,
                              void* d_out, int out_size, void* d_ws, size_t ws_size,
                              hipStream_t stream) {
    const float* user_x = (const float*)d_in[0];
    const float* book_x = (const float*)d_in[1];
    const int*   ub_src = (const int*)d_in[2];
    const int*   ub_dst = (const int*)d_in[3];
    const int*   bb_src = (const int*)d_in[4];
    const int*   bb_dst = (const int*)d_in[5];
    const int*   pred_u = (const int*)d_in[6];
    const int*   pred_b = (const int*)d_in[7];
    const float* Wu   = (const float*)d_in[8];
    const float* bu   = (const float*)d_in[9];
    const float* Wub  = (const float*)d_in[10];
    const float* bub  = (const float*)d_in[11];
    const float* Wbb  = (const float*)d_in[12];
    const float* bbb  = (const float*)d_in[13];
    const float* Wl1  = (const float*)d_in[14];
    const float* bl1  = (const float*)d_in[15];
    const float* Wr1  = (const float*)d_in[16];
    const float* Wl2  = (const float*)d_in[17];
    const float* bl2  = (const float*)d_in[18];
    const float* Wr2  = (const float*)d_in[19];
    const float* Wf1  = (const float*)d_in[20];
    const float* bf1v = (const float*)d_in[21];
    const float* Wf2  = (const float*)d_in[22];
    const float* bf2v = (const float*)d_in[23];
    float* out = (float*)d_out;

    // ---- workspace layout: unchanged from round 7 (verified no-overlap) ----
    float* ws = (float*)d_ws;
    const size_t need = 30960000ull * sizeof(float);
    if (ws_size < need) return;

    float* dsc     = ws;
    int*   rs_ub   = (int*)(ws + 300000);
    int*   rs_bb   = (int*)(ws + 500000);
    int*   bsum    = (int*)(ws + 550000);
    int*   eidx    = (int*)(ws + 560000);
    int*   cnt2_ub = (int*)(ws + 2160000);     // 600K
    int*   rs2_ub  = (int*)(ws + 2760000);     // 600K
    int*   cnt2_bb = (int*)(ws + 11760000);    // 200K
    int*   rs2_bb  = (int*)(ws + 11960000);    // 200K
    bf16*  X0s     = (bf16*)(ws + 2160000);
    bf16*  X1s     = (bf16*)(ws + 11760000);
    bf16*  XF16    = (bf16*)(ws + 21360000);

    // phase A aliases
    short* xu16  = (short*)(ws + 11760000);
    short* xb16  = (short*)(ws + 14960000);
    short* WuP   = (short*)(ws + 21360000);
    short* WubP  = (short*)(ws + 21364096);

    // content-phase aliases
    short* xb16c     = (short*)(ws + 2160000);
    bf16*  h16a      = (bf16*)(ws + 5360000);
    bf16*  h16b      = (bf16*)(ws + 8560000);
    bf16*  agg16     = (bf16*)(ws + 11760000);
    bf16*  content16 = (bf16*)(ws + 14960000);
    bf16*  fused16   = (bf16*)(ws + 18160000);
    float2* attnb    = (float2*)(ws + 11760000);
    bf16*  uemb16    = XF16;
    bf16*  collab16  = XF16 + (size_t)U_N * HD;
    short* WbbP = (short*)(ws + 150000);
    short* Wl1P = WbbP + 16384;
    short* Wr1P = WbbP + 32768;
    short* Wl2P = WbbP + 49152;
    short* Wr2P = WbbP + 65536;
    short* Wf1P = WbbP + 81920;                   // 32768 shorts (KTOT=256)

    // ---- phase A: bf16 inputs (1 launch) + all weight packs (1 launch) ----
    {
        int nA = U_N * DU, nB = B_N * DB;
        k_f2b2<<<((nA + nB) / 8 + 255) / 256, 256, 0, stream>>>(
            user_x, xu16, nA, book_x, xb16, nB);
    }
    k_pack_all<<<(17408 + 255) / 256, 256, 0, stream>>>(
        Wu, Wub, Wbb, Wl1, Wr1, Wl2, Wr2, Wf1,
        WuP, WubP, WbbP, Wl1P, Wr1P, Wl2P, Wr2P, Wf1P);

    // ---- CSR build (ub graph, split CSR; bucketed count, no global atomics) ----
    k_cnt_ub3<<<(NBU + NBB) * SPL, 1024, 0, stream>>>(ub_src, ub_dst, cnt2_ub);
    {
        int n = N_TOT * SPL;
        int nb = (n + 1023) / 1024;
        k_scan1<<<nb, 256, 0, stream>>>(cnt2_ub, rs2_ub, bsum, n);
        k_scan2<<<1, 256, 0, stream>>>(bsum, nb);
        k_scan3<<<(n + 255) / 256, 256, 0, stream>>>(rs2_ub, bsum, n);
    }
    k_dinv2<<<(N_TOT + 255) / 256, 256, 0, stream>>>(rs2_ub, dsc, rs_ub);
    k_fill_ub4<<<(NBU + NBB) * SPL, 1024, 0, stream>>>(ub_src, ub_dst, rs2_ub, eidx);

    // ---- init GEMMs (degree-pre-scaled; overwrite cnt2/rs2_ub region) ----
    k_mgemm<2, 0, false><<<(U_N + 63) / 64, 256, 0, stream>>>(
        xu16, WuP, nullptr, nullptr, bu, dsc, X0s, U_N);
    k_mgemm<4, 0, false><<<(B_N + 63) / 64, 256, 0, stream>>>(
        xb16, WubP, nullptr, nullptr, bub, dsc + U_N, X0s + (size_t)U_N * HD, B_N);

    // ---- LightGCN propagation (side-phased for L2 locality) ----
    k_gather1<<<(U_N + 3) / 4, 256, 0, stream>>>(rs_ub, eidx, dsc, X0s, X1s, 0, U_N);
    k_gather1<<<(B_N + 3) / 4, 256, 0, stream>>>(rs_ub, eidx, dsc, X0s, X1s, U_N, B_N);
    k_gather2<<<(U_N + 3) / 4, 256, 0, stream>>>(rs_ub, eidx, dsc, X0s, X1s, XF16, 0, U_N);
    k_gather2<<<(B_N + 3) / 4, 256, 0, stream>>>(rs_ub, eidx, dsc, X0s, X1s, XF16, U_N, B_N);

    // ---- CSR build (bb graph, split CSR) — X1s region dead ----
    k_cnt_bb3<<<NB2 * SPL, 1024, 0, stream>>>(bb_dst, cnt2_bb);
    {
        int n = B_N * SPL;
        int nb = (n + 1023) / 1024;
        k_scan1<<<nb, 256, 0, stream>>>(cnt2_bb, rs2_bb, bsum, n);
        k_scan2<<<1, 256, 0, stream>>>(bsum, nb);
        k_scan3<<<(n + 255) / 256, 256, 0, stream>>>(rs2_bb, bsum, n);
    }
    k_rsx_bb<<<(B_N + 255) / 256, 256, 0, stream>>>(rs2_bb, rs_bb);
    k_fill_bb4<<<NB2 * SPL, 1024, 0, stream>>>(bb_src, bb_dst, rs2_bb, eidx);

    // ---- content network (all MFMA) ----
    k_f2b<<<(B_N * DB / 8 + 255) / 256, 256, 0, stream>>>(book_x, xb16c, B_N * DB);
    k_mgemm<4, 0, false><<<(B_N + 63) / 64, 256, 0, stream>>>(
        xb16c, WbbP, nullptr, nullptr, bbb, nullptr, h16a, B_N);
    k_gather_bb<<<(B_N + 3) / 4, 256, 0, stream>>>(rs_bb, eidx, h16a, agg16);
    k_mgemm<4, 4, true><<<(B_N + 63) / 64, 256, 0, stream>>>(
        (const short*)agg16, Wl1P, (const short*)h16a, Wr1P, bl1, nullptr, h16b, B_N);
    k_gather_bb<<<(B_N + 3) / 4, 256, 0, stream>>>(rs_bb, eidx, h16b, agg16);
    k_mgemm<4, 4, true><<<(B_N + 63) / 64, 256, 0, stream>>>(
        (const short*)agg16, Wl2P, (const short*)h16b, Wr2P, bl2, nullptr, content16, B_N);

    // ---- fusion (MFMA attn head + elementwise blend) + scores ----
    k_attn<<<(B_N + 63) / 64, 256, 0, stream>>>(
        (const short*)collab16, Wf1P, (const short*)content16, Wf1P + 32768 / 2,
        bf1v, Wf2, bf2v, attnb, B_N);
    k_fuse2<<<(B_N * 16 + 255) / 256, 256, 0, stream>>>(attnb, collab16, content16, fused16);
    k_score<<<NP / 16, 256, 0, stream>>>(pred_u, pred_b, uemb16, fused16, out);
}

// Round 10
// 621.604 us; speedup vs baseline: 1.9888x; 1.0438x over previous
//
#include <hip/hip_runtime.h>
#include <hip/hip_bf16.h>

typedef __hip_bfloat16 bf16;
typedef __hip_bfloat162 bf162;

using short8 = __attribute__((ext_vector_type(8))) short;
using f32x4  = __attribute__((ext_vector_type(4))) float;

#define U_N   100000
#define B_N   50000
#define N_TOT 150000
#define NE_UB 800000
#define NE_BB 600000
#define NP    400000
#define DU    64
#define DB    128
#define HD    128

// bucketed geometry: big buckets + 4-way edge-stream split.
#define SPL   4
#define NBU   32
#define NBB   32
#define UPB   ((U_N + NBU - 1) / NBU)      // 3125 users/bucket (12.5 KB LDS)
#define BPB   ((B_N + NBB - 1) / NBB)      // 1563 books/bucket
#define LE_UB (NE_UB / SPL)                // 200000 edges/slice
#define NB2   64
#define BPB2  ((B_N + NB2 - 1) / NB2)      // 782 books/bucket (bb)
#define LE_BB (NE_BB / SPL)                // 150000 edges/slice

__device__ __forceinline__ float b2f(bf16 v) { return __bfloat162float(v); }
// f32 -> bf16 bits (RNE)
__device__ __forceinline__ short f2bs(float f) {
    unsigned u = __float_as_uint(f);
    unsigned r = (u + 0x7fffu + ((u >> 16) & 1u)) >> 16;
    return (short)r;
}
// add 8 bf16 (packed in int4) into acc[8]
__device__ __forceinline__ void add8(float (&a)[8], int4 rv) {
    const unsigned* p = (const unsigned*)&rv;
#pragma unroll
    for (int i = 0; i < 4; i++) {
        unsigned v = p[i];
        a[2 * i]     += __uint_as_float(v << 16);
        a[2 * i + 1] += __uint_as_float(v & 0xffff0000u);
    }
}
__device__ __forceinline__ void unp8(int4 rv, float (&o)[8]) {
    const unsigned* p = (const unsigned*)&rv;
#pragma unroll
    for (int i = 0; i < 4; i++) {
        unsigned v = p[i];
        o[2 * i]     = __uint_as_float(v << 16);
        o[2 * i + 1] = __uint_as_float(v & 0xffff0000u);
    }
}
__device__ __forceinline__ int4 pack8bf(const float (&a)[8]) {
    unsigned r[4];
#pragma unroll
    for (int i = 0; i < 4; i++) {
        unsigned lo = (unsigned)(unsigned short)f2bs(a[2 * i]);
        unsigned hi = (unsigned)(unsigned short)f2bs(a[2 * i + 1]);
        r[i] = lo | (hi << 16);
    }
    int4 o; o.x = r[0]; o.y = r[1]; o.z = r[2]; o.w = r[3];
    return o;
}
__device__ __forceinline__ void xgred(float (&a)[8]) {
#pragma unroll
    for (int i = 0; i < 8; i++) {
        a[i] += __shfl_xor(a[i], 16, 64);
        a[i] += __shfl_xor(a[i], 32, 64);
    }
}

// ---------------- bf16 conversion + weight packing ----------------

__global__ void k_f2b(const float* __restrict__ in, short* __restrict__ out, int n) {
    int i = (blockIdx.x * blockDim.x + threadIdx.x) * 8;
    if (i >= n) return;
    float4 a = ((const float4*)(in + i))[0];
    float4 b = ((const float4*)(in + i))[1];
    short8 v;
    v[0] = f2bs(a.x); v[1] = f2bs(a.y); v[2] = f2bs(a.z); v[3] = f2bs(a.w);
    v[4] = f2bs(b.x); v[5] = f2bs(b.y); v[6] = f2bs(b.z); v[7] = f2bs(b.w);
    *(short8*)(out + i) = v;
}

// merged: user_x -> xu16 and book_x -> xb16 in one launch
__global__ void k_f2b2(const float* __restrict__ A, short* __restrict__ Ao, int nA,
                       const float* __restrict__ B, short* __restrict__ Bo, int nB) {
    int i = (blockIdx.x * blockDim.x + threadIdx.x) * 8;
    const float* src; short* dst; int off;
    if (i < nA)            { src = A; dst = Ao; off = i; }
    else if (i < nA + nB)  { src = B; dst = Bo; off = i - nA; }
    else return;
    float4 a = ((const float4*)(src + off))[0];
    float4 b = ((const float4*)(src + off))[1];
    short8 v;
    v[0] = f2bs(a.x); v[1] = f2bs(a.y); v[2] = f2bs(a.z); v[3] = f2bs(a.w);
    v[4] = f2bs(b.x); v[5] = f2bs(b.y); v[6] = f2bs(b.z); v[7] = f2bs(b.w);
    *(short8*)(dst + off) = v;
}

// all 8 weight packs in one launch; thread ranges per weight.
__global__ void k_pack_all(const float* __restrict__ Wu,  const float* __restrict__ Wub,
                           const float* __restrict__ Wbb, const float* __restrict__ Wl1,
                           const float* __restrict__ Wr1, const float* __restrict__ Wl2,
                           const float* __restrict__ Wr2, const float* __restrict__ Wf1,
                           short* WuP, short* WubP, short* WbbP, short* Wl1P,
                           short* Wr1P, short* Wl2P, short* Wr2P, short* Wf1P) {
    int t = blockIdx.x * blockDim.x + threadIdx.x;
    const float* W; short* Wp; int base;
    if      (t < 1024)  { W = Wu;  Wp = WuP;  base = 0; }
    else if (t < 3072)  { W = Wub; Wp = WubP; base = 1024; }
    else if (t < 5120)  { W = Wbb; Wp = WbbP; base = 3072; }
    else if (t < 7168)  { W = Wl1; Wp = Wl1P; base = 5120; }
    else if (t < 9216)  { W = Wr1; Wp = Wr1P; base = 7168; }
    else if (t < 11264) { W = Wl2; Wp = Wl2P; base = 9216; }
    else if (t < 13312) { W = Wr2; Wp = Wr2P; base = 11264; }
    else if (t < 17408) { W = Wf1; Wp = Wf1P; base = 13312; }
    else return;
    int tt = t - base;
    int lane = tt & 63;
    int n    = (tt >> 6) & 7;
    int kk   = tt >> 9;
    int lr = lane & 15, lg = lane >> 4;
    short8 v;
#pragma unroll
    for (int j = 0; j < 8; j++) {
        float f = W[(size_t)(kk * 32 + lg * 8 + j) * HD + (n * 16 + lr)];
        v[j] = f2bs(f);
    }
    *(short8*)(Wp + (size_t)tt * 8) = v;
}

// ---------------- MFMA GEMM: out = [relu](A1@W1 [+ A2@W2] + bias) [* scale] ----
template<int KS1, int KS2, bool RELU>
__global__ __launch_bounds__(256) void k_mgemm(
    const short* __restrict__ A1, const short* __restrict__ Wp1,
    const short* __restrict__ A2, const short* __restrict__ Wp2,
    const float* __restrict__ bias, const float* __restrict__ scale,
    bf16* __restrict__ out, int nrows) {
    const int wv   = threadIdx.x >> 6;
    const int lane = threadIdx.x & 63;
    const int row0 = blockIdx.x * 64 + wv * 16;
    if (row0 >= nrows) return;
    const int lr = lane & 15, lg = lane >> 4;

    f32x4 acc[8];
#pragma unroll
    for (int n = 0; n < 8; n++) acc[n] = (f32x4){0.f, 0.f, 0.f, 0.f};

    {
        const short* a1p = A1 + (size_t)(row0 + lr) * (KS1 * 32) + lg * 8;
#pragma unroll
        for (int kk = 0; kk < KS1; kk++) {
            short8 af = *(const short8*)(a1p + kk * 32);
            const short* wp = Wp1 + ((size_t)(kk * 8) * 64 + lane) * 8;
#pragma unroll
            for (int n = 0; n < 8; n++) {
                short8 bfr = *(const short8*)(wp + (size_t)n * 64 * 8);
                acc[n] = __builtin_amdgcn_mfma_f32_16x16x32_bf16(af, bfr, acc[n], 0, 0, 0);
            }
        }
    }
    if constexpr (KS2 > 0) {
        const short* a2p = A2 + (size_t)(row0 + lr) * (KS2 * 32) + lg * 8;
#pragma unroll
        for (int kk = 0; kk < KS2; kk++) {
            short8 af = *(const short8*)(a2p + kk * 32);
            const short* wp = Wp2 + ((size_t)(kk * 8) * 64 + lane) * 8;
#pragma unroll
            for (int n = 0; n < 8; n++) {
                short8 bfr = *(const short8*)(wp + (size_t)n * 64 * 8);
                acc[n] = __builtin_amdgcn_mfma_f32_16x16x32_bf16(af, bfr, acc[n], 0, 0, 0);
            }
        }
    }
    float scr[4] = {1.f, 1.f, 1.f, 1.f};
    if (scale) {
#pragma unroll
        for (int r = 0; r < 4; r++) scr[r] = scale[row0 + lg * 4 + r];
    }
#pragma unroll
    for (int n = 0; n < 8; n++) {
        int col = n * 16 + lr;
        float bv = bias[col];
#pragma unroll
        for (int r = 0; r < 4; r++) {
            int row = row0 + lg * 4 + r;
            float v = acc[n][r] + bv;
            if (RELU) v = fmaxf(v, 0.0f);
            v *= scr[r];
            out[(size_t)row * HD + col] = __float2bfloat16(v);
        }
    }
}

// ---------------- MFMA attention head ----------------
__global__ __launch_bounds__(256) void k_attn(
    const short* __restrict__ A1, const short* __restrict__ Wp1,
    const short* __restrict__ A2, const short* __restrict__ Wp2,
    const float* __restrict__ bias, const float* __restrict__ Wf2,
    const float* __restrict__ bf2v, float2* __restrict__ attn, int nrows) {
    const int wv   = threadIdx.x >> 6;
    const int lane = threadIdx.x & 63;
    const int row0 = blockIdx.x * 64 + wv * 16;
    if (row0 >= nrows) return;
    const int lr = lane & 15, lg = lane >> 4;

    f32x4 acc[8];
#pragma unroll
    for (int n = 0; n < 8; n++) acc[n] = (f32x4){0.f, 0.f, 0.f, 0.f};

    {
        const short* a1p = A1 + (size_t)(row0 + lr) * 128 + lg * 8;
#pragma unroll
        for (int kk = 0; kk < 4; kk++) {
            short8 af = *(const short8*)(a1p + kk * 32);
            const short* wp = Wp1 + ((size_t)(kk * 8) * 64 + lane) * 8;
#pragma unroll
            for (int n = 0; n < 8; n++) {
                short8 bfr = *(const short8*)(wp + (size_t)n * 64 * 8);
                acc[n] = __builtin_amdgcn_mfma_f32_16x16x32_bf16(af, bfr, acc[n], 0, 0, 0);
            }
        }
    }
    {
        const short* a2p = A2 + (size_t)(row0 + lr) * 128 + lg * 8;
#pragma unroll
        for (int kk = 0; kk < 4; kk++) {
            short8 af = *(const short8*)(a2p + kk * 32);
            const short* wp = Wp2 + ((size_t)(kk * 8) * 64 + lane) * 8;
#pragma unroll
            for (int n = 0; n < 8; n++) {
                short8 bfr = *(const short8*)(wp + (size_t)n * 64 * 8);
                acc[n] = __builtin_amdgcn_mfma_f32_16x16x32_bf16(af, bfr, acc[n], 0, 0, 0);
            }
        }
    }
    float q0[4] = {0.f, 0.f, 0.f, 0.f};
    float q1[4] = {0.f, 0.f, 0.f, 0.f};
#pragma unroll
    for (int n = 0; n < 8; n++) {
        int col = n * 16 + lr;
        float bv = bias[col];
        float2 w2 = ((const float2*)Wf2)[col];
#pragma unroll
        for (int r = 0; r < 4; r++) {
            float tv = fmaxf(acc[n][r] + bv, 0.0f);
            q0[r] = fmaf(tv, w2.x, q0[r]);
            q1[r] = fmaf(tv, w2.y, q1[r]);
        }
    }
#pragma unroll
    for (int off = 1; off <= 8; off <<= 1) {
#pragma unroll
        for (int r = 0; r < 4; r++) {
            q0[r] += __shfl_xor(q0[r], off, 64);
            q1[r] += __shfl_xor(q1[r], off, 64);
        }
    }
    if (lr == 0) {
        float b0 = bf2v[0], b1 = bf2v[1];
#pragma unroll
        for (int r = 0; r < 4; r++) {
            int row = row0 + lg * 4 + r;
            float s0 = q0[r] + b0;
            float s1 = q1[r] + b1;
            float m  = fmaxf(s0, s1);
            float e0 = expf(s0 - m), e1 = expf(s1 - m);
            float inv = 1.0f / (e0 + e1);
            attn[row] = make_float2(e0 * inv, e1 * inv);
        }
    }
}

// fused = attn.x*collab + attn.y*content  (elementwise, int4-vectorized)
__global__ void k_fuse2(const float2* __restrict__ attn,
                        const bf16* __restrict__ collab, const bf16* __restrict__ content,
                        bf16* __restrict__ fused) {
    int idx = blockIdx.x * blockDim.x + threadIdx.x;
    if (idx >= B_N * 16) return;
    int row = idx >> 4, l = idx & 15;
    float2 a = attn[row];
    float c[8], h[8], o[8];
    unp8(((const int4*)(collab + (size_t)row * HD))[l], c);
    unp8(((const int4*)(content + (size_t)row * HD))[l], h);
#pragma unroll
    for (int i = 0; i < 8; i++) o[i] = a.x * c[i] + a.y * h[i];
    ((int4*)(fused + (size_t)row * HD))[l] = pack8bf(o);
}

// ---------------- CSR build: bucketed LDS count -> scan -> bucketed fill ----

__global__ __launch_bounds__(1024) void k_cnt_ub3(const int* __restrict__ us,
                                                  const int* __restrict__ ud,
                                                  int* __restrict__ cnt2) {
    __shared__ int cur[UPB];
    const int bk = blockIdx.x >> 2;
    const int sp = blockIdx.x & 3;
    const bool userSide = bk < NBU;
    int node0, nn, rbase;
    const int* keys;
    if (userSide) {
        node0 = bk * UPB;
        nn    = min(UPB, U_N - node0);
        rbase = node0;
        keys  = us;
    } else {
        int b = bk - NBU;
        node0 = b * BPB;
        nn    = min(BPB, B_N - node0);
        rbase = U_N + node0;
        keys  = ud;
    }
    for (int i = threadIdx.x; i < nn; i += 1024) cur[i] = 0;
    __syncthreads();
    const int4* k4 = (const int4*)keys;
    const int q0 = sp * (LE_UB / 4), q1 = q0 + LE_UB / 4;
    for (int q = q0 + threadIdx.x; q < q1; q += 1024) {
        int4 kv = k4[q];
        int ka[4] = {kv.x, kv.y, kv.z, kv.w};
#pragma unroll
        for (int i = 0; i < 4; i++) {
            unsigned rel = (unsigned)(ka[i] - node0);
            if (rel < (unsigned)nn) atomicAdd(&cur[rel], 1);
        }
    }
    __syncthreads();
    for (int i = threadIdx.x; i < nn; i += 1024)
        cnt2[(size_t)(rbase + i) * SPL + sp] = cur[i];
}

__global__ __launch_bounds__(1024) void k_cnt_bb3(const int* __restrict__ bd,
                                                  int* __restrict__ cnt2) {
    __shared__ int cur[BPB2];
    const int bk = blockIdx.x >> 2;
    const int sp = blockIdx.x & 3;
    const int node0 = bk * BPB2;
    const int nn    = min(BPB2, B_N - node0);
    for (int i = threadIdx.x; i < nn; i += 1024) cur[i] = 0;
    __syncthreads();
    const int4* k4 = (const int4*)bd;
    const int q0 = sp * (LE_BB / 4), q1 = q0 + LE_BB / 4;
    for (int q = q0 + threadIdx.x; q < q1; q += 1024) {
        int4 kv = k4[q];
        int ka[4] = {kv.x, kv.y, kv.z, kv.w};
#pragma unroll
        for (int i = 0; i < 4; i++) {
            unsigned rel = (unsigned)(ka[i] - node0);
            if (rel < (unsigned)nn) atomicAdd(&cur[rel], 1);
        }
    }
    __syncthreads();
    for (int i = threadIdx.x; i < nn; i += 1024)
        cnt2[(size_t)(node0 + i) * SPL + sp] = cur[i];
}

__global__ void k_dinv2(const int* __restrict__ rs2, float* __restrict__ dsc,
                        int* __restrict__ rsn) {
    int i = blockIdx.x * blockDim.x + threadIdx.x;
    if (i < N_TOT) {
        int s = rs2[i * SPL];
        int e = (i == N_TOT - 1) ? (2 * NE_UB) : rs2[(i + 1) * SPL];
        rsn[i] = s;
        dsc[i] = 1.0f / sqrtf((float)max(e - s, 1));
    }
}

__global__ void k_rsx_bb(const int* __restrict__ rs2, int* __restrict__ rsn) {
    int i = blockIdx.x * blockDim.x + threadIdx.x;
    if (i < B_N) rsn[i] = rs2[i * SPL];
}

__global__ void k_scan1(const int* __restrict__ cnt, int* __restrict__ rs,
                        int* __restrict__ bsum, int n) {
    __shared__ int ts[256];
    const int t = threadIdx.x;
    const int base = blockIdx.x * 1024 + t * 4;
    int v0 = (base + 0 < n) ? cnt[base + 0] : 0;
    int v1 = (base + 1 < n) ? cnt[base + 1] : 0;
    int v2 = (base + 2 < n) ? cnt[base + 2] : 0;
    int v3 = (base + 3 < n) ? cnt[base + 3] : 0;
    int local = v0 + v1 + v2 + v3;
    ts[t] = local;
    __syncthreads();
    for (int off = 1; off < 256; off <<= 1) {
        int x = (t >= off) ? ts[t - off] : 0;
        __syncthreads();
        ts[t] += x;
        __syncthreads();
    }
    int ex = ts[t] - local;
    if (base + 0 < n) rs[base + 0] = ex;
    if (base + 1 < n) rs[base + 1] = ex + v0;
    if (base + 2 < n) rs[base + 2] = ex + v0 + v1;
    if (base + 3 < n) rs[base + 3] = ex + v0 + v1 + v2;
    if (t == 0) bsum[blockIdx.x] = ts[255];
}

__global__ void k_scan2(int* __restrict__ bsum, int nb) {
    __shared__ int ts[256];
    const int t = threadIdx.x;
    const int base = t * 4;
    int v0 = (base + 0 < nb) ? bsum[base + 0] : 0;
    int v1 = (base + 1 < nb) ? bsum[base + 1] : 0;
    int v2 = (base + 2 < nb) ? bsum[base + 2] : 0;
    int v3 = (base + 3 < nb) ? bsum[base + 3] : 0;
    int local = v0 + v1 + v2 + v3;
    ts[t] = local;
    __syncthreads();
    for (int off = 1; off < 256; off <<= 1) {
        int x = (t >= off) ? ts[t - off] : 0;
        __syncthreads();
        ts[t] += x;
        __syncthreads();
    }
    int ex = ts[t] - local;
    if (base + 0 < nb) bsum[base + 0] = ex;
    if (base + 1 < nb) bsum[base + 1] = ex + v0;
    if (base + 2 < nb) bsum[base + 2] = ex + v0 + v1;
    if (base + 3 < nb) bsum[base + 3] = ex + v0 + v1 + v2;
}

__global__ void k_scan3(int* __restrict__ rs, const int* __restrict__ bsum, int n) {
    int i = blockIdx.x * blockDim.x + threadIdx.x;
    if (i < n) rs[i] += bsum[i >> 10];
}

__global__ __launch_bounds__(1024) void k_fill_ub4(const int* __restrict__ us,
                                                   const int* __restrict__ ud,
                                                   const int* __restrict__ rs2,
                                                   int* __restrict__ eidx) {
    __shared__ int cur[UPB];
    const int bk = blockIdx.x >> 2;      // bucket
    const int sp = blockIdx.x & 3;       // split
    const bool userSide = bk < NBU;
    int node0, nn, rbase, add;
    const int *keys, *vals;
    if (userSide) {
        node0 = bk * UPB;
        nn    = min(UPB, U_N - node0);
        rbase = node0;
        keys  = us;
        vals  = ud;
        add   = U_N;
    } else {
        int b = bk - NBU;
        node0 = b * BPB;
        nn    = min(BPB, B_N - node0);
        rbase = U_N + node0;
        keys  = ud;
        vals  = us;
        add   = 0;
    }
    for (int i = threadIdx.x; i < nn; i += 1024)
        cur[i] = rs2[(size_t)(rbase + i) * SPL + sp];
    __syncthreads();
    const int4* k4 = (const int4*)keys;
    const int4* v4 = (const int4*)vals;
    const int q0 = sp * (LE_UB / 4), q1 = q0 + LE_UB / 4;
    for (int q = q0 + threadIdx.x; q < q1; q += 1024) {
        int4 kv = k4[q];
        int4 vv = v4[q];
        int ka[4] = {kv.x, kv.y, kv.z, kv.w};
        int va[4] = {vv.x, vv.y, vv.z, vv.w};
#pragma unroll
        for (int i = 0; i < 4; i++) {
            unsigned rel = (unsigned)(ka[i] - node0);
            if (rel < (unsigned)nn) {
                int p = atomicAdd(&cur[rel], 1);
                eidx[p] = va[i] + add;
            }
        }
    }
}

__global__ __launch_bounds__(1024) void k_fill_bb4(const int* __restrict__ bs,
                                                   const int* __restrict__ bd,
                                                   const int* __restrict__ rs2,
                                                   int* __restrict__ eidx) {
    __shared__ int cur[BPB2];
    const int bk = blockIdx.x >> 2;
    const int sp = blockIdx.x & 3;
    const int node0 = bk * BPB2;
    const int nn    = min(BPB2, B_N - node0);
    for (int i = threadIdx.x; i < nn; i += 1024)
        cur[i] = rs2[(size_t)(node0 + i) * SPL + sp];
    __syncthreads();
    const int4* k4 = (const int4*)bd;
    const int4* v4 = (const int4*)bs;
    const int q0 = sp * (LE_BB / 4), q1 = q0 + LE_BB / 4;
    for (int q = q0 + threadIdx.x; q < q1; q += 1024) {
        int4 kv = k4[q];
        int4 vv = v4[q];
        int ka[4] = {kv.x, kv.y, kv.z, kv.w};
        int va[4] = {vv.x, vv.y, vv.z, vv.w};
#pragma unroll
        for (int i = 0; i < 4; i++) {
            unsigned rel = (unsigned)(ka[i] - node0);
            if (rel < (unsigned)nn) {
                int p = atomicAdd(&cur[rel], 1);
                eidx[p] = va[i];
            }
        }
    }
}

// ---------------- pull-mode propagation (pre-scaled tables, side-phased) ----
// Edge loops unrolled x2: each 16-lane group issues 2 independent eidx+row
// loads before accumulating -> 8 row-loads in flight per wave (was 4).

__global__ void k_gather1(const int* __restrict__ rs, const int* __restrict__ eidx,
                          const float* __restrict__ dsc,
                          const bf16* __restrict__ x0s, bf16* __restrict__ x1s,
                          int wbase, int wcnt) {
    int wid  = (blockIdx.x * blockDim.x + threadIdx.x) >> 6;
    int lane = threadIdx.x & 63;
    if (wid >= wcnt) return;
    int w = wbase + wid;
    int g = lane >> 4, l = lane & 15;
    int s = rs[w];
    int e = (w == N_TOT - 1) ? (2 * NE_UB) : rs[w + 1];
    s = __builtin_amdgcn_readfirstlane(s);
    e = __builtin_amdgcn_readfirstlane(e);
    float acc[8] = {0.f, 0.f, 0.f, 0.f, 0.f, 0.f, 0.f, 0.f};
    int j0 = s;
    for (; j0 + 8 <= e; j0 += 8) {
        int nb1 = eidx[j0 + g];
        int nb2 = eidx[j0 + 4 + g];
        int4 rv1 = ((const int4*)(x0s + (size_t)nb1 * HD))[l];
        int4 rv2 = ((const int4*)(x0s + (size_t)nb2 * HD))[l];
        add8(acc, rv1);
        add8(acc, rv2);
    }
    for (; j0 < e; j0 += 4) {
        int j = j0 + g;
        if (j < e) {
            int nb = eidx[j];
            int4 rv = ((const int4*)(x0s + (size_t)nb * HD))[l];
            add8(acc, rv);
        }
    }
    xgred(acc);
    if (g == 0) {
        float nd = dsc[w];
        float s2 = nd * nd;
#pragma unroll
        for (int i = 0; i < 8; i++) acc[i] *= s2;
        ((int4*)(x1s + (size_t)w * HD))[l] = pack8bf(acc);
    }
}

__global__ void k_gather2(const int* __restrict__ rs, const int* __restrict__ eidx,
                          const float* __restrict__ dsc,
                          const bf16* __restrict__ x0s, const bf16* __restrict__ x1s,
                          bf16* __restrict__ xf16, int wbase, int wcnt) {
    int wid  = (blockIdx.x * blockDim.x + threadIdx.x) >> 6;
    int lane = threadIdx.x & 63;
    if (wid >= wcnt) return;
    int w = wbase + wid;
    int g = lane >> 4, l = lane & 15;
    int s = rs[w];
    int e = (w == N_TOT - 1) ? (2 * NE_UB) : rs[w + 1];
    s = __builtin_amdgcn_readfirstlane(s);
    e = __builtin_amdgcn_readfirstlane(e);
    float acc[8] = {0.f, 0.f, 0.f, 0.f, 0.f, 0.f, 0.f, 0.f};
    int j0 = s;
    for (; j0 + 8 <= e; j0 += 8) {
        int nb1 = eidx[j0 + g];
        int nb2 = eidx[j0 + 4 + g];
        int4 rv1 = ((const int4*)(x1s + (size_t)nb1 * HD))[l];
        int4 rv2 = ((const int4*)(x1s + (size_t)nb2 * HD))[l];
        add8(acc, rv1);
        add8(acc, rv2);
    }
    for (; j0 < e; j0 += 4) {
        int j = j0 + g;
        if (j < e) {
            int nb = eidx[j];
            int4 rv = ((const int4*)(x1s + (size_t)nb * HD))[l];
            add8(acc, rv);
        }
    }
    xgred(acc);
    if (g == 0) {
        float nd = dsc[w];
        float sd = 1.0f / nd;
        float d0[8], d1[8];
        unp8(((const int4*)(x0s + (size_t)w * HD))[l], d0);
        unp8(((const int4*)(x1s + (size_t)w * HD))[l], d1);
        float o[8];
#pragma unroll
        for (int i = 0; i < 8; i++)
            o[i] = (acc[i] * nd + (d0[i] + d1[i]) * sd) * (1.0f / 3.0f);
        ((int4*)(xf16 + (size_t)w * HD))[l] = pack8bf(o);
    }
}

__global__ void k_gather_bb(const int* __restrict__ rs, const int* __restrict__ eidx,
                            const bf16* __restrict__ h16, bf16* __restrict__ agg16) {
    int w    = (blockIdx.x * blockDim.x + threadIdx.x) >> 6;
    int lane = threadIdx.x & 63;
    if (w >= B_N) return;
    int g = lane >> 4, l = lane & 15;
    int s = rs[w];
    int e = (w == B_N - 1) ? NE_BB : rs[w + 1];
    s = __builtin_amdgcn_readfirstlane(s);
    e = __builtin_amdgcn_readfirstlane(e);
    float acc[8] = {0.f, 0.f, 0.f, 0.f, 0.f, 0.f, 0.f, 0.f};
    int j0 = s;
    for (; j0 + 8 <= e; j0 += 8) {
        int nb1 = eidx[j0 + g];
        int nb2 = eidx[j0 + 4 + g];
        int4 rv1 = ((const int4*)(h16 + (size_t)nb1 * HD))[l];
        int4 rv2 = ((const int4*)(h16 + (size_t)nb2 * HD))[l];
        add8(acc, rv1);
        add8(acc, rv2);
    }
    for (; j0 < e; j0 += 4) {
        int j = j0 + g;
        if (j < e) {
            int nb = eidx[j];
            int4 rv = ((const int4*)(h16 + (size_t)nb * HD))[l];
            add8(acc, rv);
        }
    }
    xgred(acc);
    if (g == 0) {
        float inv = 1.0f / fmaxf((float)(e - s), 1.0f);
#pragma unroll
        for (int i = 0; i < 8; i++) acc[i] *= inv;
        ((int4*)(agg16 + (size_t)w * HD))[l] = pack8bf(acc);
    }
}

// 4 predictions per wave, 16 lanes x 16B (int4 of 8 bf16) per row
__global__ void k_score(const int* __restrict__ pu, const int* __restrict__ pb,
                        const bf16* __restrict__ uemb16, const bf16* __restrict__ fused16,
                        float* __restrict__ out) {
    int wid  = (blockIdx.x * blockDim.x + threadIdx.x) >> 6;
    int lane = threadIdx.x & 63;
    int g = lane >> 4;
    int l = lane & 15;
    int p = wid * 4 + g;
    if (p >= NP) return;
    int u = pu[p];
    int b = pb[p];
    int4 av = ((const int4*)(uemb16 + (size_t)u * HD))[l];
    int4 fv = ((const int4*)(fused16 + (size_t)b * HD))[l];
    const int* ap = (const int*)&av;
    const int* fp = (const int*)&fv;
    float s = 0.0f;
#pragma unroll
    for (int i = 0; i < 4; i++) {
        bf162 a2 = *(const bf162*)&ap[i];
        bf162 f2 = *(const bf162*)&fp[i];
        s = fmaf(b2f(a2.x), b2f(f2.x), s);
        s = fmaf(b2f(a2.y), b2f(f2.y), s);
    }
#pragma unroll
    for (int off = 8; off > 0; off >>= 1) s += __shfl_xor(s, off, 64);
    if (l == 0) out[p] = s;
}

extern "C" void kernel_launch(void* const* d_in, const int* in_sizes, int n_in,
                              void* d_out, int out_size, void* d_ws, size_t ws_size,
                              hipStream_t stream) {
    const float* user_x = (const float*)d_in[0];
    const float* book_x = (const float*)d_in[1];
    const int*   ub_src = (const int*)d_in[2];
    const int*   ub_dst = (const int*)d_in[3];
    const int*   bb_src = (const int*)d_in[4];
    const int*   bb_dst = (const int*)d_in[5];
    const int*   pred_u = (const int*)d_in[6];
    const int*   pred_b = (const int*)d_in[7];
    const float* Wu   = (const float*)d_in[8];
    const float* bu   = (const float*)d_in[9];
    const float* Wub  = (const float*)d_in[10];
    const float* bub  = (const float*)d_in[11];
    const float* Wbb  = (const float*)d_in[12];
    const float* bbb  = (const float*)d_in[13];
    const float* Wl1  = (const float*)d_in[14];
    const float* bl1  = (const float*)d_in[15];
    const float* Wr1  = (const float*)d_in[16];
    const float* Wl2  = (const float*)d_in[17];
    const float* bl2  = (const float*)d_in[18];
    const float* Wr2  = (const float*)d_in[19];
    const float* Wf1  = (const float*)d_in[20];
    const float* bf1v = (const float*)d_in[21];
    const float* Wf2  = (const float*)d_in[22];
    const float* bf2v = (const float*)d_in[23];
    float* out = (float*)d_out;

    // ---- workspace layout: unchanged from round 7 (verified no-overlap) ----
    float* ws = (float*)d_ws;
    const size_t need = 30960000ull * sizeof(float);
    if (ws_size < need) return;

    float* dsc     = ws;
    int*   rs_ub   = (int*)(ws + 300000);
    int*   rs_bb   = (int*)(ws + 500000);
    int*   bsum    = (int*)(ws + 550000);
    int*   eidx    = (int*)(ws + 560000);
    int*   cnt2_ub = (int*)(ws + 2160000);     // 600K
    int*   rs2_ub  = (int*)(ws + 2760000);     // 600K
    int*   cnt2_bb = (int*)(ws + 11760000);    // 200K
    int*   rs2_bb  = (int*)(ws + 11960000);    // 200K
    bf16*  X0s     = (bf16*)(ws + 2160000);
    bf16*  X1s     = (bf16*)(ws + 11760000);
    bf16*  XF16    = (bf16*)(ws + 21360000);

    // phase A aliases
    short* xu16  = (short*)(ws + 11760000);
    short* xb16  = (short*)(ws + 14960000);
    short* WuP   = (short*)(ws + 21360000);
    short* WubP  = (short*)(ws + 21364096);

    // content-phase aliases
    short* xb16c     = (short*)(ws + 2160000);
    bf16*  h16a      = (bf16*)(ws + 5360000);
    bf16*  h16b      = (bf16*)(ws + 8560000);
    bf16*  agg16     = (bf16*)(ws + 11760000);
    bf16*  content16 = (bf16*)(ws + 14960000);
    bf16*  fused16   = (bf16*)(ws + 18160000);
    float2* attnb    = (float2*)(ws + 11760000);
    bf16*  uemb16    = XF16;
    bf16*  collab16  = XF16 + (size_t)U_N * HD;
    short* WbbP = (short*)(ws + 150000);
    short* Wl1P = WbbP + 16384;
    short* Wr1P = WbbP + 32768;
    short* Wl2P = WbbP + 49152;
    short* Wr2P = WbbP + 65536;
    short* Wf1P = WbbP + 81920;                   // 32768 shorts (KTOT=256)

    // ---- phase A: bf16 inputs (1 launch) + all weight packs (1 launch) ----
    {
        int nA = U_N * DU, nB = B_N * DB;
        k_f2b2<<<((nA + nB) / 8 + 255) / 256, 256, 0, stream>>>(
            user_x, xu16, nA, book_x, xb16, nB);
    }
    k_pack_all<<<(17408 + 255) / 256, 256, 0, stream>>>(
        Wu, Wub, Wbb, Wl1, Wr1, Wl2, Wr2, Wf1,
        WuP, WubP, WbbP, Wl1P, Wr1P, Wl2P, Wr2P, Wf1P);

    // ---- CSR build (ub graph, split CSR; bucketed count, no global atomics) ----
    k_cnt_ub3<<<(NBU + NBB) * SPL, 1024, 0, stream>>>(ub_src, ub_dst, cnt2_ub);
    {
        int n = N_TOT * SPL;
        int nb = (n + 1023) / 1024;
        k_scan1<<<nb, 256, 0, stream>>>(cnt2_ub, rs2_ub, bsum, n);
        k_scan2<<<1, 256, 0, stream>>>(bsum, nb);
        k_scan3<<<(n + 255) / 256, 256, 0, stream>>>(rs2_ub, bsum, n);
    }
    k_dinv2<<<(N_TOT + 255) / 256, 256, 0, stream>>>(rs2_ub, dsc, rs_ub);
    k_fill_ub4<<<(NBU + NBB) * SPL, 1024, 0, stream>>>(ub_src, ub_dst, rs2_ub, eidx);

    // ---- init GEMMs (degree-pre-scaled; overwrite cnt2/rs2_ub region) ----
    k_mgemm<2, 0, false><<<(U_N + 63) / 64, 256, 0, stream>>>(
        xu16, WuP, nullptr, nullptr, bu, dsc, X0s, U_N);
    k_mgemm<4, 0, false><<<(B_N + 63) / 64, 256, 0, stream>>>(
        xb16, WubP, nullptr, nullptr, bub, dsc + U_N, X0s + (size_t)U_N * HD, B_N);

    // ---- LightGCN propagation (side-phased for L2 locality) ----
    k_gather1<<<(U_N + 3) / 4, 256, 0, stream>>>(rs_ub, eidx, dsc, X0s, X1s, 0, U_N);
    k_gather1<<<(B_N + 3) / 4, 256, 0, stream>>>(rs_ub, eidx, dsc, X0s, X1s, U_N, B_N);
    k_gather2<<<(U_N + 3) / 4, 256, 0, stream>>>(rs_ub, eidx, dsc, X0s, X1s, XF16, 0, U_N);
    k_gather2<<<(B_N + 3) / 4, 256, 0, stream>>>(rs_ub, eidx, dsc, X0s, X1s, XF16, U_N, B_N);

    // ---- CSR build (bb graph, split CSR) — X1s region dead ----
    k_cnt_bb3<<<NB2 * SPL, 1024, 0, stream>>>(bb_dst, cnt2_bb);
    {
        int n = B_N * SPL;
        int nb = (n + 1023) / 1024;
        k_scan1<<<nb, 256, 0, stream>>>(cnt2_bb, rs2_bb, bsum, n);
        k_scan2<<<1, 256, 0, stream>>>(bsum, nb);
        k_scan3<<<(n + 255) / 256, 256, 0, stream>>>(rs2_bb, bsum, n);
    }
    k_rsx_bb<<<(B_N + 255) / 256, 256, 0, stream>>>(rs2_bb, rs_bb);
    k_fill_bb4<<<NB2 * SPL, 1024, 0, stream>>>(bb_src, bb_dst, rs2_bb, eidx);

    // ---- content network (all MFMA) ----
    k_f2b<<<(B_N * DB / 8 + 255) / 256, 256, 0, stream>>>(book_x, xb16c, B_N * DB);
    k_mgemm<4, 0, false><<<(B_N + 63) / 64, 256, 0, stream>>>(
        xb16c, WbbP, nullptr, nullptr, bbb, nullptr, h16a, B_N);
    k_gather_bb<<<(B_N + 3) / 4, 256, 0, stream>>>(rs_bb, eidx, h16a, agg16);
    k_mgemm<4, 4, true><<<(B_N + 63) / 64, 256, 0, stream>>>(
        (const short*)agg16, Wl1P, (const short*)h16a, Wr1P, bl1, nullptr, h16b, B_N);
    k_gather_bb<<<(B_N + 3) / 4, 256, 0, stream>>>(rs_bb, eidx, h16b, agg16);
    k_mgemm<4, 4, true><<<(B_N + 63) / 64, 256, 0, stream>>>(
        (const short*)agg16, Wl2P, (const short*)h16b, Wr2P, bl2, nullptr, content16, B_N);

    // ---- fusion (MFMA attn head + elementwise blend) + scores ----
    k_attn<<<(B_N + 63) / 64, 256, 0, stream>>>(
        (const short*)collab16, Wf1P, (const short*)content16, Wf1P + 32768 / 2,
        bf1v, Wf2, bf2v, attnb, B_N);
    k_fuse2<<<(B_N * 16 + 255) / 256, 256, 0, stream>>>(attnb, collab16, content16, fused16);
    k_score<<<NP / 16, 256, 0, stream>>>(pred_u, pred_b, uemb16, fused16, out);
}

// Round 11
// 618.679 us; speedup vs baseline: 1.9982x; 1.0047x over previous
//
#include <hip/hip_runtime.h>
#include <hip/hip_bf16.h>

typedef __hip_bfloat16 bf16;
typedef __hip_bfloat162 bf162;

using short8 = __attribute__((ext_vector_type(8))) short;
using f32x4  = __attribute__((ext_vector_type(4))) float;

#define U_N   100000
#define B_N   50000
#define N_TOT 150000
#define NE_UB 800000
#define NE_BB 600000
#define NP    400000
#define DU    64
#define DB    128
#define HD    128

// bucketed geometry: big buckets + 4-way edge-stream split.
#define SPL   4
#define NBU   32
#define NBB   32
#define UPB   ((U_N + NBU - 1) / NBU)      // 3125 users/bucket (12.5 KB LDS)
#define BPB   ((B_N + NBB - 1) / NBB)      // 1563 books/bucket
#define LE_UB (NE_UB / SPL)                // 200000 edges/slice
#define NB2   64
#define BPB2  ((B_N + NB2 - 1) / NB2)      // 782 books/bucket (bb)
#define LE_BB (NE_BB / SPL)                // 150000 edges/slice

__device__ __forceinline__ float b2f(bf16 v) { return __bfloat162float(v); }
// f32 -> bf16 bits (RNE)
__device__ __forceinline__ short f2bs(float f) {
    unsigned u = __float_as_uint(f);
    unsigned r = (u + 0x7fffu + ((u >> 16) & 1u)) >> 16;
    return (short)r;
}
// add 8 bf16 (packed in int4) into acc[8]
__device__ __forceinline__ void add8(float (&a)[8], int4 rv) {
    const unsigned* p = (const unsigned*)&rv;
#pragma unroll
    for (int i = 0; i < 4; i++) {
        unsigned v = p[i];
        a[2 * i]     += __uint_as_float(v << 16);
        a[2 * i + 1] += __uint_as_float(v & 0xffff0000u);
    }
}
__device__ __forceinline__ void unp8(int4 rv, float (&o)[8]) {
    const unsigned* p = (const unsigned*)&rv;
#pragma unroll
    for (int i = 0; i < 4; i++) {
        unsigned v = p[i];
        o[2 * i]     = __uint_as_float(v << 16);
        o[2 * i + 1] = __uint_as_float(v & 0xffff0000u);
    }
}
__device__ __forceinline__ int4 pack8bf(const float (&a)[8]) {
    unsigned r[4];
#pragma unroll
    for (int i = 0; i < 4; i++) {
        unsigned lo = (unsigned)(unsigned short)f2bs(a[2 * i]);
        unsigned hi = (unsigned)(unsigned short)f2bs(a[2 * i + 1]);
        r[i] = lo | (hi << 16);
    }
    int4 o; o.x = r[0]; o.y = r[1]; o.z = r[2]; o.w = r[3];
    return o;
}
__device__ __forceinline__ void xgred(float (&a)[8]) {
#pragma unroll
    for (int i = 0; i < 8; i++) {
        a[i] += __shfl_xor(a[i], 16, 64);
        a[i] += __shfl_xor(a[i], 32, 64);
    }
}

// ---------------- bf16 conversion + weight packing ----------------

__global__ void k_f2b(const float* __restrict__ in, short* __restrict__ out, int n) {
    int i = (blockIdx.x * blockDim.x + threadIdx.x) * 8;
    if (i >= n) return;
    float4 a = ((const float4*)(in + i))[0];
    float4 b = ((const float4*)(in + i))[1];
    short8 v;
    v[0] = f2bs(a.x); v[1] = f2bs(a.y); v[2] = f2bs(a.z); v[3] = f2bs(a.w);
    v[4] = f2bs(b.x); v[5] = f2bs(b.y); v[6] = f2bs(b.z); v[7] = f2bs(b.w);
    *(short8*)(out + i) = v;
}

// merged: user_x -> xu16 and book_x -> xb16 in one launch
__global__ void k_f2b2(const float* __restrict__ A, short* __restrict__ Ao, int nA,
                       const float* __restrict__ B, short* __restrict__ Bo, int nB) {
    int i = (blockIdx.x * blockDim.x + threadIdx.x) * 8;
    const float* src; short* dst; int off;
    if (i < nA)            { src = A; dst = Ao; off = i; }
    else if (i < nA + nB)  { src = B; dst = Bo; off = i - nA; }
    else return;
    float4 a = ((const float4*)(src + off))[0];
    float4 b = ((const float4*)(src + off))[1];
    short8 v;
    v[0] = f2bs(a.x); v[1] = f2bs(a.y); v[2] = f2bs(a.z); v[3] = f2bs(a.w);
    v[4] = f2bs(b.x); v[5] = f2bs(b.y); v[6] = f2bs(b.z); v[7] = f2bs(b.w);
    *(short8*)(dst + off) = v;
}

// all 8 weight packs in one launch; thread ranges per weight.
__global__ void k_pack_all(const float* __restrict__ Wu,  const float* __restrict__ Wub,
                           const float* __restrict__ Wbb, const float* __restrict__ Wl1,
                           const float* __restrict__ Wr1, const float* __restrict__ Wl2,
                           const float* __restrict__ Wr2, const float* __restrict__ Wf1,
                           short* WuP, short* WubP, short* WbbP, short* Wl1P,
                           short* Wr1P, short* Wl2P, short* Wr2P, short* Wf1P) {
    int t = blockIdx.x * blockDim.x + threadIdx.x;
    const float* W; short* Wp; int base;
    if      (t < 1024)  { W = Wu;  Wp = WuP;  base = 0; }
    else if (t < 3072)  { W = Wub; Wp = WubP; base = 1024; }
    else if (t < 5120)  { W = Wbb; Wp = WbbP; base = 3072; }
    else if (t < 7168)  { W = Wl1; Wp = Wl1P; base = 5120; }
    else if (t < 9216)  { W = Wr1; Wp = Wr1P; base = 7168; }
    else if (t < 11264) { W = Wl2; Wp = Wl2P; base = 9216; }
    else if (t < 13312) { W = Wr2; Wp = Wr2P; base = 11264; }
    else if (t < 17408) { W = Wf1; Wp = Wf1P; base = 13312; }
    else return;
    int tt = t - base;
    int lane = tt & 63;
    int n    = (tt >> 6) & 7;
    int kk   = tt >> 9;
    int lr = lane & 15, lg = lane >> 4;
    short8 v;
#pragma unroll
    for (int j = 0; j < 8; j++) {
        float f = W[(size_t)(kk * 32 + lg * 8 + j) * HD + (n * 16 + lr)];
        v[j] = f2bs(f);
    }
    *(short8*)(Wp + (size_t)tt * 8) = v;
}

// ---------------- MFMA GEMM: out = [relu](A1@W1 [+ A2@W2] + bias) [* scale] ----
template<int KS1, int KS2, bool RELU>
__global__ __launch_bounds__(256) void k_mgemm(
    const short* __restrict__ A1, const short* __restrict__ Wp1,
    const short* __restrict__ A2, const short* __restrict__ Wp2,
    const float* __restrict__ bias, const float* __restrict__ scale,
    bf16* __restrict__ out, int nrows) {
    const int wv   = threadIdx.x >> 6;
    const int lane = threadIdx.x & 63;
    const int row0 = blockIdx.x * 64 + wv * 16;
    if (row0 >= nrows) return;
    const int lr = lane & 15, lg = lane >> 4;

    f32x4 acc[8];
#pragma unroll
    for (int n = 0; n < 8; n++) acc[n] = (f32x4){0.f, 0.f, 0.f, 0.f};

    {
        const short* a1p = A1 + (size_t)(row0 + lr) * (KS1 * 32) + lg * 8;
#pragma unroll
        for (int kk = 0; kk < KS1; kk++) {
            short8 af = *(const short8*)(a1p + kk * 32);
            const short* wp = Wp1 + ((size_t)(kk * 8) * 64 + lane) * 8;
#pragma unroll
            for (int n = 0; n < 8; n++) {
                short8 bfr = *(const short8*)(wp + (size_t)n * 64 * 8);
                acc[n] = __builtin_amdgcn_mfma_f32_16x16x32_bf16(af, bfr, acc[n], 0, 0, 0);
            }
        }
    }
    if constexpr (KS2 > 0) {
        const short* a2p = A2 + (size_t)(row0 + lr) * (KS2 * 32) + lg * 8;
#pragma unroll
        for (int kk = 0; kk < KS2; kk++) {
            short8 af = *(const short8*)(a2p + kk * 32);
            const short* wp = Wp2 + ((size_t)(kk * 8) * 64 + lane) * 8;
#pragma unroll
            for (int n = 0; n < 8; n++) {
                short8 bfr = *(const short8*)(wp + (size_t)n * 64 * 8);
                acc[n] = __builtin_amdgcn_mfma_f32_16x16x32_bf16(af, bfr, acc[n], 0, 0, 0);
            }
        }
    }
    float scr[4] = {1.f, 1.f, 1.f, 1.f};
    if (scale) {
#pragma unroll
        for (int r = 0; r < 4; r++) scr[r] = scale[row0 + lg * 4 + r];
    }
#pragma unroll
    for (int n = 0; n < 8; n++) {
        int col = n * 16 + lr;
        float bv = bias[col];
#pragma unroll
        for (int r = 0; r < 4; r++) {
            int row = row0 + lg * 4 + r;
            float v = acc[n][r] + bv;
            if (RELU) v = fmaxf(v, 0.0f);
            v *= scr[r];
            out[(size_t)row * HD + col] = __float2bfloat16(v);
        }
    }
}

// ---------------- MFMA attention head + fused blend (merged epilogue) ----------
// Computes attn = softmax(relu([collab|content]@Wf1+b)@Wf2+b2) per row, then
// directly writes fused = a0*collab + a1*content (fragments reloaded L2-hot,
// attn broadcast via a 512B LDS table). Replaces the separate k_fuse2 pass.
__global__ __launch_bounds__(256) void k_attn(
    const short* __restrict__ A1, const short* __restrict__ Wp1,
    const short* __restrict__ A2, const short* __restrict__ Wp2,
    const float* __restrict__ bias, const float* __restrict__ Wf2,
    const float* __restrict__ bf2v, bf16* __restrict__ fused, int nrows) {
    __shared__ float2 sat[4][16];
    const int wv   = threadIdx.x >> 6;
    const int lane = threadIdx.x & 63;
    const int row0 = blockIdx.x * 64 + wv * 16;
    if (row0 >= nrows) return;
    const int lr = lane & 15, lg = lane >> 4;

    f32x4 acc[8];
#pragma unroll
    for (int n = 0; n < 8; n++) acc[n] = (f32x4){0.f, 0.f, 0.f, 0.f};

    const short* a1p = A1 + (size_t)(row0 + lr) * 128 + lg * 8;
    const short* a2p = A2 + (size_t)(row0 + lr) * 128 + lg * 8;
    {
#pragma unroll
        for (int kk = 0; kk < 4; kk++) {
            short8 af = *(const short8*)(a1p + kk * 32);
            const short* wp = Wp1 + ((size_t)(kk * 8) * 64 + lane) * 8;
#pragma unroll
            for (int n = 0; n < 8; n++) {
                short8 bfr = *(const short8*)(wp + (size_t)n * 64 * 8);
                acc[n] = __builtin_amdgcn_mfma_f32_16x16x32_bf16(af, bfr, acc[n], 0, 0, 0);
            }
        }
    }
    {
#pragma unroll
        for (int kk = 0; kk < 4; kk++) {
            short8 af = *(const short8*)(a2p + kk * 32);
            const short* wp = Wp2 + ((size_t)(kk * 8) * 64 + lane) * 8;
#pragma unroll
            for (int n = 0; n < 8; n++) {
                short8 bfr = *(const short8*)(wp + (size_t)n * 64 * 8);
                acc[n] = __builtin_amdgcn_mfma_f32_16x16x32_bf16(af, bfr, acc[n], 0, 0, 0);
            }
        }
    }
    float q0[4] = {0.f, 0.f, 0.f, 0.f};
    float q1[4] = {0.f, 0.f, 0.f, 0.f};
#pragma unroll
    for (int n = 0; n < 8; n++) {
        int col = n * 16 + lr;
        float bv = bias[col];
        float2 w2 = ((const float2*)Wf2)[col];
#pragma unroll
        for (int r = 0; r < 4; r++) {
            float tv = fmaxf(acc[n][r] + bv, 0.0f);
            q0[r] = fmaf(tv, w2.x, q0[r]);
            q1[r] = fmaf(tv, w2.y, q1[r]);
        }
    }
#pragma unroll
    for (int off = 1; off <= 8; off <<= 1) {
#pragma unroll
        for (int r = 0; r < 4; r++) {
            q0[r] += __shfl_xor(q0[r], off, 64);
            q1[r] += __shfl_xor(q1[r], off, 64);
        }
    }
    if (lr == 0) {
        float b0 = bf2v[0], b1 = bf2v[1];
#pragma unroll
        for (int r = 0; r < 4; r++) {
            float s0 = q0[r] + b0;
            float s1 = q1[r] + b1;
            float m  = fmaxf(s0, s1);
            float e0 = expf(s0 - m), e1 = expf(s1 - m);
            float inv = 1.0f / (e0 + e1);
            sat[wv][lg * 4 + r] = make_float2(e0 * inv, e1 * inv);
        }
    }
    __syncthreads();
    float2 a = sat[wv][lr];       // attn for this lane's fragment row (row0+lr)
    bf16* fr = fused + (size_t)(row0 + lr) * HD + lg * 8;
#pragma unroll
    for (int kk = 0; kk < 4; kk++) {
        float c[8], h[8], o[8];
        unp8(*(const int4*)(a1p + kk * 32), c);
        unp8(*(const int4*)(a2p + kk * 32), h);
#pragma unroll
        for (int i = 0; i < 8; i++) o[i] = a.x * c[i] + a.y * h[i];
        *(int4*)(fr + kk * 32) = pack8bf(o);
    }
}

// ---------------- CSR build: bucketed LDS count -> scan -> bucketed fill ----

__global__ __launch_bounds__(1024) void k_cnt_ub3(const int* __restrict__ us,
                                                  const int* __restrict__ ud,
                                                  int* __restrict__ cnt2) {
    __shared__ int cur[UPB];
    const int bk = blockIdx.x >> 2;
    const int sp = blockIdx.x & 3;
    const bool userSide = bk < NBU;
    int node0, nn, rbase;
    const int* keys;
    if (userSide) {
        node0 = bk * UPB;
        nn    = min(UPB, U_N - node0);
        rbase = node0;
        keys  = us;
    } else {
        int b = bk - NBU;
        node0 = b * BPB;
        nn    = min(BPB, B_N - node0);
        rbase = U_N + node0;
        keys  = ud;
    }
    for (int i = threadIdx.x; i < nn; i += 1024) cur[i] = 0;
    __syncthreads();
    const int4* k4 = (const int4*)keys;
    const int q0 = sp * (LE_UB / 4), q1 = q0 + LE_UB / 4;
    for (int q = q0 + threadIdx.x; q < q1; q += 1024) {
        int4 kv = k4[q];
        int ka[4] = {kv.x, kv.y, kv.z, kv.w};
#pragma unroll
        for (int i = 0; i < 4; i++) {
            unsigned rel = (unsigned)(ka[i] - node0);
            if (rel < (unsigned)nn) atomicAdd(&cur[rel], 1);
        }
    }
    __syncthreads();
    for (int i = threadIdx.x; i < nn; i += 1024)
        cnt2[(size_t)(rbase + i) * SPL + sp] = cur[i];
}

__global__ __launch_bounds__(1024) void k_cnt_bb3(const int* __restrict__ bd,
                                                  int* __restrict__ cnt2) {
    __shared__ int cur[BPB2];
    const int bk = blockIdx.x >> 2;
    const int sp = blockIdx.x & 3;
    const int node0 = bk * BPB2;
    const int nn    = min(BPB2, B_N - node0);
    for (int i = threadIdx.x; i < nn; i += 1024) cur[i] = 0;
    __syncthreads();
    const int4* k4 = (const int4*)bd;
    const int q0 = sp * (LE_BB / 4), q1 = q0 + LE_BB / 4;
    for (int q = q0 + threadIdx.x; q < q1; q += 1024) {
        int4 kv = k4[q];
        int ka[4] = {kv.x, kv.y, kv.z, kv.w};
#pragma unroll
        for (int i = 0; i < 4; i++) {
            unsigned rel = (unsigned)(ka[i] - node0);
            if (rel < (unsigned)nn) atomicAdd(&cur[rel], 1);
        }
    }
    __syncthreads();
    for (int i = threadIdx.x; i < nn; i += 1024)
        cnt2[(size_t)(node0 + i) * SPL + sp] = cur[i];
}

__global__ void k_dinv2(const int* __restrict__ rs2, float* __restrict__ dsc,
                        int* __restrict__ rsn) {
    int i = blockIdx.x * blockDim.x + threadIdx.x;
    if (i < N_TOT) {
        int s = rs2[i * SPL];
        int e = (i == N_TOT - 1) ? (2 * NE_UB) : rs2[(i + 1) * SPL];
        rsn[i] = s;
        dsc[i] = 1.0f / sqrtf((float)max(e - s, 1));
    }
}

__global__ void k_rsx_bb(const int* __restrict__ rs2, int* __restrict__ rsn) {
    int i = blockIdx.x * blockDim.x + threadIdx.x;
    if (i < B_N) rsn[i] = rs2[i * SPL];
}

__global__ void k_scan1(const int* __restrict__ cnt, int* __restrict__ rs,
                        int* __restrict__ bsum, int n) {
    __shared__ int ts[256];
    const int t = threadIdx.x;
    const int base = blockIdx.x * 1024 + t * 4;
    int v0 = (base + 0 < n) ? cnt[base + 0] : 0;
    int v1 = (base + 1 < n) ? cnt[base + 1] : 0;
    int v2 = (base + 2 < n) ? cnt[base + 2] : 0;
    int v3 = (base + 3 < n) ? cnt[base + 3] : 0;
    int local = v0 + v1 + v2 + v3;
    ts[t] = local;
    __syncthreads();
    for (int off = 1; off < 256; off <<= 1) {
        int x = (t >= off) ? ts[t - off] : 0;
        __syncthreads();
        ts[t] += x;
        __syncthreads();
    }
    int ex = ts[t] - local;
    if (base + 0 < n) rs[base + 0] = ex;
    if (base + 1 < n) rs[base + 1] = ex + v0;
    if (base + 2 < n) rs[base + 2] = ex + v0 + v1;
    if (base + 3 < n) rs[base + 3] = ex + v0 + v1 + v2;
    if (t == 0) bsum[blockIdx.x] = ts[255];
}

__global__ void k_scan2(int* __restrict__ bsum, int nb) {
    __shared__ int ts[256];
    const int t = threadIdx.x;
    const int base = t * 4;
    int v0 = (base + 0 < nb) ? bsum[base + 0] : 0;
    int v1 = (base + 1 < nb) ? bsum[base + 1] : 0;
    int v2 = (base + 2 < nb) ? bsum[base + 2] : 0;
    int v3 = (base + 3 < nb) ? bsum[base + 3] : 0;
    int local = v0 + v1 + v2 + v3;
    ts[t] = local;
    __syncthreads();
    for (int off = 1; off < 256; off <<= 1) {
        int x = (t >= off) ? ts[t - off] : 0;
        __syncthreads();
        ts[t] += x;
        __syncthreads();
    }
    int ex = ts[t] - local;
    if (base + 0 < nb) bsum[base + 0] = ex;
    if (base + 1 < nb) bsum[base + 1] = ex + v0;
    if (base + 2 < nb) bsum[base + 2] = ex + v0 + v1;
    if (base + 3 < nb) bsum[base + 3] = ex + v0 + v1 + v2;
}

__global__ void k_scan3(int* __restrict__ rs, const int* __restrict__ bsum, int n) {
    int i = blockIdx.x * blockDim.x + threadIdx.x;
    if (i < n) rs[i] += bsum[i >> 10];
}

__global__ __launch_bounds__(1024) void k_fill_ub4(const int* __restrict__ us,
                                                   const int* __restrict__ ud,
                                                   const int* __restrict__ rs2,
                                                   int* __restrict__ eidx) {
    __shared__ int cur[UPB];
    const int bk = blockIdx.x >> 2;      // bucket
    const int sp = blockIdx.x & 3;       // split
    const bool userSide = bk < NBU;
    int node0, nn, rbase, add;
    const int *keys, *vals;
    if (userSide) {
        node0 = bk * UPB;
        nn    = min(UPB, U_N - node0);
        rbase = node0;
        keys  = us;
        vals  = ud;
        add   = U_N;
    } else {
        int b = bk - NBU;
        node0 = b * BPB;
        nn    = min(BPB, B_N - node0);
        rbase = U_N + node0;
        keys  = ud;
        vals  = us;
        add   = 0;
    }
    for (int i = threadIdx.x; i < nn; i += 1024)
        cur[i] = rs2[(size_t)(rbase + i) * SPL + sp];
    __syncthreads();
    const int4* k4 = (const int4*)keys;
    const int4* v4 = (const int4*)vals;
    const int q0 = sp * (LE_UB / 4), q1 = q0 + LE_UB / 4;
    for (int q = q0 + threadIdx.x; q < q1; q += 1024) {
        int4 kv = k4[q];
        int4 vv = v4[q];
        int ka[4] = {kv.x, kv.y, kv.z, kv.w};
        int va[4] = {vv.x, vv.y, vv.z, vv.w};
#pragma unroll
        for (int i = 0; i < 4; i++) {
            unsigned rel = (unsigned)(ka[i] - node0);
            if (rel < (unsigned)nn) {
                int p = atomicAdd(&cur[rel], 1);
                eidx[p] = va[i] + add;
            }
        }
    }
}

__global__ __launch_bounds__(1024) void k_fill_bb4(const int* __restrict__ bs,
                                                   const int* __restrict__ bd,
                                                   const int* __restrict__ rs2,
                                                   int* __restrict__ eidx) {
    __shared__ int cur[BPB2];
    const int bk = blockIdx.x >> 2;
    const int sp = blockIdx.x & 3;
    const int node0 = bk * BPB2;
    const int nn    = min(BPB2, B_N - node0);
    for (int i = threadIdx.x; i < nn; i += 1024)
        cur[i] = rs2[(size_t)(node0 + i) * SPL + sp];
    __syncthreads();
    const int4* k4 = (const int4*)bd;
    const int4* v4 = (const int4*)bs;
    const int q0 = sp * (LE_BB / 4), q1 = q0 + LE_BB / 4;
    for (int q = q0 + threadIdx.x; q < q1; q += 1024) {
        int4 kv = k4[q];
        int4 vv = v4[q];
        int ka[4] = {kv.x, kv.y, kv.z, kv.w};
        int va[4] = {vv.x, vv.y, vv.z, vv.w};
#pragma unroll
        for (int i = 0; i < 4; i++) {
            unsigned rel = (unsigned)(ka[i] - node0);
            if (rel < (unsigned)nn) {
                int p = atomicAdd(&cur[rel], 1);
                eidx[p] = va[i];
            }
        }
    }
}

// ---------------- pull-mode propagation (pre-scaled tables, side-phased) ----
// Edge loops with 16/8/4-edge levels: up to 16 independent row-loads in
// flight per wave for high-degree segments.

__global__ void k_gather1(const int* __restrict__ rs, const int* __restrict__ eidx,
                          const float* __restrict__ dsc,
                          const bf16* __restrict__ x0s, bf16* __restrict__ x1s,
                          int wbase, int wcnt) {
    int wid  = (blockIdx.x * blockDim.x + threadIdx.x) >> 6;
    int lane = threadIdx.x & 63;
    if (wid >= wcnt) return;
    int w = wbase + wid;
    int g = lane >> 4, l = lane & 15;
    int s = rs[w];
    int e = (w == N_TOT - 1) ? (2 * NE_UB) : rs[w + 1];
    s = __builtin_amdgcn_readfirstlane(s);
    e = __builtin_amdgcn_readfirstlane(e);
    float acc[8] = {0.f, 0.f, 0.f, 0.f, 0.f, 0.f, 0.f, 0.f};
    int j0 = s;
    for (; j0 + 16 <= e; j0 += 16) {
        int nb1 = eidx[j0 + g];
        int nb2 = eidx[j0 + 4 + g];
        int nb3 = eidx[j0 + 8 + g];
        int nb4 = eidx[j0 + 12 + g];
        int4 rv1 = ((const int4*)(x0s + (size_t)nb1 * HD))[l];
        int4 rv2 = ((const int4*)(x0s + (size_t)nb2 * HD))[l];
        int4 rv3 = ((const int4*)(x0s + (size_t)nb3 * HD))[l];
        int4 rv4 = ((const int4*)(x0s + (size_t)nb4 * HD))[l];
        add8(acc, rv1); add8(acc, rv2); add8(acc, rv3); add8(acc, rv4);
    }
    for (; j0 + 8 <= e; j0 += 8) {
        int nb1 = eidx[j0 + g];
        int nb2 = eidx[j0 + 4 + g];
        int4 rv1 = ((const int4*)(x0s + (size_t)nb1 * HD))[l];
        int4 rv2 = ((const int4*)(x0s + (size_t)nb2 * HD))[l];
        add8(acc, rv1); add8(acc, rv2);
    }
    for (; j0 < e; j0 += 4) {
        int j = j0 + g;
        if (j < e) {
            int nb = eidx[j];
            int4 rv = ((const int4*)(x0s + (size_t)nb * HD))[l];
            add8(acc, rv);
        }
    }
    xgred(acc);
    if (g == 0) {
        float nd = dsc[w];
        float s2 = nd * nd;
#pragma unroll
        for (int i = 0; i < 8; i++) acc[i] *= s2;
        ((int4*)(x1s + (size_t)w * HD))[l] = pack8bf(acc);
    }
}

__global__ void k_gather2(const int* __restrict__ rs, const int* __restrict__ eidx,
                          const float* __restrict__ dsc,
                          const bf16* __restrict__ x0s, const bf16* __restrict__ x1s,
                          bf16* __restrict__ xf16, int wbase, int wcnt) {
    int wid  = (blockIdx.x * blockDim.x + threadIdx.x) >> 6;
    int lane = threadIdx.x & 63;
    if (wid >= wcnt) return;
    int w = wbase + wid;
    int g = lane >> 4, l = lane & 15;
    int s = rs[w];
    int e = (w == N_TOT - 1) ? (2 * NE_UB) : rs[w + 1];
    s = __builtin_amdgcn_readfirstlane(s);
    e = __builtin_amdgcn_readfirstlane(e);
    float acc[8] = {0.f, 0.f, 0.f, 0.f, 0.f, 0.f, 0.f, 0.f};
    int j0 = s;
    for (; j0 + 16 <= e; j0 += 16) {
        int nb1 = eidx[j0 + g];
        int nb2 = eidx[j0 + 4 + g];
        int nb3 = eidx[j0 + 8 + g];
        int nb4 = eidx[j0 + 12 + g];
        int4 rv1 = ((const int4*)(x1s + (size_t)nb1 * HD))[l];
        int4 rv2 = ((const int4*)(x1s + (size_t)nb2 * HD))[l];
        int4 rv3 = ((const int4*)(x1s + (size_t)nb3 * HD))[l];
        int4 rv4 = ((const int4*)(x1s + (size_t)nb4 * HD))[l];
        add8(acc, rv1); add8(acc, rv2); add8(acc, rv3); add8(acc, rv4);
    }
    for (; j0 + 8 <= e; j0 += 8) {
        int nb1 = eidx[j0 + g];
        int nb2 = eidx[j0 + 4 + g];
        int4 rv1 = ((const int4*)(x1s + (size_t)nb1 * HD))[l];
        int4 rv2 = ((const int4*)(x1s + (size_t)nb2 * HD))[l];
        add8(acc, rv1); add8(acc, rv2);
    }
    for (; j0 < e; j0 += 4) {
        int j = j0 + g;
        if (j < e) {
            int nb = eidx[j];
            int4 rv = ((const int4*)(x1s + (size_t)nb * HD))[l];
            add8(acc, rv);
        }
    }
    xgred(acc);
    if (g == 0) {
        float nd = dsc[w];
        float sd = 1.0f / nd;
        float d0[8], d1[8];
        unp8(((const int4*)(x0s + (size_t)w * HD))[l], d0);
        unp8(((const int4*)(x1s + (size_t)w * HD))[l], d1);
        float o[8];
#pragma unroll
        for (int i = 0; i < 8; i++)
            o[i] = (acc[i] * nd + (d0[i] + d1[i]) * sd) * (1.0f / 3.0f);
        ((int4*)(xf16 + (size_t)w * HD))[l] = pack8bf(o);
    }
}

__global__ void k_gather_bb(const int* __restrict__ rs, const int* __restrict__ eidx,
                            const bf16* __restrict__ h16, bf16* __restrict__ agg16) {
    int w    = (blockIdx.x * blockDim.x + threadIdx.x) >> 6;
    int lane = threadIdx.x & 63;
    if (w >= B_N) return;
    int g = lane >> 4, l = lane & 15;
    int s = rs[w];
    int e = (w == B_N - 1) ? NE_BB : rs[w + 1];
    s = __builtin_amdgcn_readfirstlane(s);
    e = __builtin_amdgcn_readfirstlane(e);
    float acc[8] = {0.f, 0.f, 0.f, 0.f, 0.f, 0.f, 0.f, 0.f};
    int j0 = s;
    for (; j0 + 16 <= e; j0 += 16) {
        int nb1 = eidx[j0 + g];
        int nb2 = eidx[j0 + 4 + g];
        int nb3 = eidx[j0 + 8 + g];
        int nb4 = eidx[j0 + 12 + g];
        int4 rv1 = ((const int4*)(h16 + (size_t)nb1 * HD))[l];
        int4 rv2 = ((const int4*)(h16 + (size_t)nb2 * HD))[l];
        int4 rv3 = ((const int4*)(h16 + (size_t)nb3 * HD))[l];
        int4 rv4 = ((const int4*)(h16 + (size_t)nb4 * HD))[l];
        add8(acc, rv1); add8(acc, rv2); add8(acc, rv3); add8(acc, rv4);
    }
    for (; j0 + 8 <= e; j0 += 8) {
        int nb1 = eidx[j0 + g];
        int nb2 = eidx[j0 + 4 + g];
        int4 rv1 = ((const int4*)(h16 + (size_t)nb1 * HD))[l];
        int4 rv2 = ((const int4*)(h16 + (size_t)nb2 * HD))[l];
        add8(acc, rv1); add8(acc, rv2);
    }
    for (; j0 < e; j0 += 4) {
        int j = j0 + g;
        if (j < e) {
            int nb = eidx[j];
            int4 rv = ((const int4*)(h16 + (size_t)nb * HD))[l];
            add8(acc, rv);
        }
    }
    xgred(acc);
    if (g == 0) {
        float inv = 1.0f / fmaxf((float)(e - s), 1.0f);
#pragma unroll
        for (int i = 0; i < 8; i++) acc[i] *= inv;
        ((int4*)(agg16 + (size_t)w * HD))[l] = pack8bf(acc);
    }
}

// 8 predictions per wave: 8-lane groups, 2x int4 per lane per row
// (32 row-loads in flight per wave, 3-level reduce)
__global__ void k_score(const int* __restrict__ pu, const int* __restrict__ pb,
                        const bf16* __restrict__ uemb16, const bf16* __restrict__ fused16,
                        float* __restrict__ out) {
    int wid  = (blockIdx.x * blockDim.x + threadIdx.x) >> 6;
    int lane = threadIdx.x & 63;
    int g = lane >> 3;
    int l = lane & 7;
    int p = wid * 8 + g;
    if (p >= NP) return;
    int u = pu[p];
    int b = pb[p];
    const int4* ur = (const int4*)(uemb16 + (size_t)u * HD);
    const int4* br = (const int4*)(fused16 + (size_t)b * HD);
    int4 av1 = ur[l];
    int4 av2 = ur[l + 8];
    int4 fv1 = br[l];
    int4 fv2 = br[l + 8];
    float a1[8], a2[8], f1[8], f2[8];
    unp8(av1, a1); unp8(av2, a2); unp8(fv1, f1); unp8(fv2, f2);
    float s = 0.0f;
#pragma unroll
    for (int i = 0; i < 8; i++) {
        s = fmaf(a1[i], f1[i], s);
        s = fmaf(a2[i], f2[i], s);
    }
#pragma unroll
    for (int off = 4; off > 0; off >>= 1) s += __shfl_xor(s, off, 64);
    if (l == 0) out[p] = s;
}

extern "C" void kernel_launch(void* const* d_in, const int* in_sizes, int n_in,
                              void* d_out, int out_size, void* d_ws, size_t ws_size,
                              hipStream_t stream) {
    const float* user_x = (const float*)d_in[0];
    const float* book_x = (const float*)d_in[1];
    const int*   ub_src = (const int*)d_in[2];
    const int*   ub_dst = (const int*)d_in[3];
    const int*   bb_src = (const int*)d_in[4];
    const int*   bb_dst = (const int*)d_in[5];
    const int*   pred_u = (const int*)d_in[6];
    const int*   pred_b = (const int*)d_in[7];
    const float* Wu   = (const float*)d_in[8];
    const float* bu   = (const float*)d_in[9];
    const float* Wub  = (const float*)d_in[10];
    const float* bub  = (const float*)d_in[11];
    const float* Wbb  = (const float*)d_in[12];
    const float* bbb  = (const float*)d_in[13];
    const float* Wl1  = (const float*)d_in[14];
    const float* bl1  = (const float*)d_in[15];
    const float* Wr1  = (const float*)d_in[16];
    const float* Wl2  = (const float*)d_in[17];
    const float* bl2  = (const float*)d_in[18];
    const float* Wr2  = (const float*)d_in[19];
    const float* Wf1  = (const float*)d_in[20];
    const float* bf1v = (const float*)d_in[21];
    const float* Wf2  = (const float*)d_in[22];
    const float* bf2v = (const float*)d_in[23];
    float* out = (float*)d_out;

    // ---- workspace layout: unchanged from round 7 (verified no-overlap) ----
    float* ws = (float*)d_ws;
    const size_t need = 30960000ull * sizeof(float);
    if (ws_size < need) return;

    float* dsc     = ws;
    int*   rs_ub   = (int*)(ws + 300000);
    int*   rs_bb   = (int*)(ws + 500000);
    int*   bsum    = (int*)(ws + 550000);
    int*   eidx    = (int*)(ws + 560000);
    int*   cnt2_ub = (int*)(ws + 2160000);     // 600K
    int*   rs2_ub  = (int*)(ws + 2760000);     // 600K
    int*   cnt2_bb = (int*)(ws + 11760000);    // 200K
    int*   rs2_bb  = (int*)(ws + 11960000);    // 200K
    bf16*  X0s     = (bf16*)(ws + 2160000);
    bf16*  X1s     = (bf16*)(ws + 11760000);
    bf16*  XF16    = (bf16*)(ws + 21360000);

    // phase A aliases
    short* xu16  = (short*)(ws + 11760000);
    short* xb16  = (short*)(ws + 14960000);
    short* WuP   = (short*)(ws + 21360000);
    short* WubP  = (short*)(ws + 21364096);

    // content-phase aliases
    short* xb16c     = (short*)(ws + 2160000);
    bf16*  h16a      = (bf16*)(ws + 5360000);
    bf16*  h16b      = (bf16*)(ws + 8560000);
    bf16*  agg16     = (bf16*)(ws + 11760000);
    bf16*  content16 = (bf16*)(ws + 14960000);
    bf16*  fused16   = (bf16*)(ws + 18160000);
    bf16*  uemb16    = XF16;
    bf16*  collab16  = XF16 + (size_t)U_N * HD;
    short* WbbP = (short*)(ws + 150000);
    short* Wl1P = WbbP + 16384;
    short* Wr1P = WbbP + 32768;
    short* Wl2P = WbbP + 49152;
    short* Wr2P = WbbP + 65536;
    short* Wf1P = WbbP + 81920;                   // 32768 shorts (KTOT=256)

    // ---- phase A: bf16 inputs (1 launch) + all weight packs (1 launch) ----
    {
        int nA = U_N * DU, nB = B_N * DB;
        k_f2b2<<<((nA + nB) / 8 + 255) / 256, 256, 0, stream>>>(
            user_x, xu16, nA, book_x, xb16, nB);
    }
    k_pack_all<<<(17408 + 255) / 256, 256, 0, stream>>>(
        Wu, Wub, Wbb, Wl1, Wr1, Wl2, Wr2, Wf1,
        WuP, WubP, WbbP, Wl1P, Wr1P, Wl2P, Wr2P, Wf1P);

    // ---- CSR build (ub graph, split CSR; bucketed count, no global atomics) ----
    k_cnt_ub3<<<(NBU + NBB) * SPL, 1024, 0, stream>>>(ub_src, ub_dst, cnt2_ub);
    {
        int n = N_TOT * SPL;
        int nb = (n + 1023) / 1024;
        k_scan1<<<nb, 256, 0, stream>>>(cnt2_ub, rs2_ub, bsum, n);
        k_scan2<<<1, 256, 0, stream>>>(bsum, nb);
        k_scan3<<<(n + 255) / 256, 256, 0, stream>>>(rs2_ub, bsum, n);
    }
    k_dinv2<<<(N_TOT + 255) / 256, 256, 0, stream>>>(rs2_ub, dsc, rs_ub);
    k_fill_ub4<<<(NBU + NBB) * SPL, 1024, 0, stream>>>(ub_src, ub_dst, rs2_ub, eidx);

    // ---- init GEMMs (degree-pre-scaled; overwrite cnt2/rs2_ub region) ----
    k_mgemm<2, 0, false><<<(U_N + 63) / 64, 256, 0, stream>>>(
        xu16, WuP, nullptr, nullptr, bu, dsc, X0s, U_N);
    k_mgemm<4, 0, false><<<(B_N + 63) / 64, 256, 0, stream>>>(
        xb16, WubP, nullptr, nullptr, bub, dsc + U_N, X0s + (size_t)U_N * HD, B_N);

    // ---- LightGCN propagation (side-phased for L2 locality) ----
    k_gather1<<<(U_N + 3) / 4, 256, 0, stream>>>(rs_ub, eidx, dsc, X0s, X1s, 0, U_N);
    k_gather1<<<(B_N + 3) / 4, 256, 0, stream>>>(rs_ub, eidx, dsc, X0s, X1s, U_N, B_N);
    k_gather2<<<(U_N + 3) / 4, 256, 0, stream>>>(rs_ub, eidx, dsc, X0s, X1s, XF16, 0, U_N);
    k_gather2<<<(B_N + 3) / 4, 256, 0, stream>>>(rs_ub, eidx, dsc, X0s, X1s, XF16, U_N, B_N);

    // ---- CSR build (bb graph, split CSR) — X1s region dead ----
    k_cnt_bb3<<<NB2 * SPL, 1024, 0, stream>>>(bb_dst, cnt2_bb);
    {
        int n = B_N * SPL;
        int nb = (n + 1023) / 1024;
        k_scan1<<<nb, 256, 0, stream>>>(cnt2_bb, rs2_bb, bsum, n);
        k_scan2<<<1, 256, 0, stream>>>(bsum, nb);
        k_scan3<<<(n + 255) / 256, 256, 0, stream>>>(rs2_bb, bsum, n);
    }
    k_rsx_bb<<<(B_N + 255) / 256, 256, 0, stream>>>(rs2_bb, rs_bb);
    k_fill_bb4<<<NB2 * SPL, 1024, 0, stream>>>(bb_src, bb_dst, rs2_bb, eidx);

    // ---- content network (all MFMA) ----
    k_f2b<<<(B_N * DB / 8 + 255) / 256, 256, 0, stream>>>(book_x, xb16c, B_N * DB);
    k_mgemm<4, 0, false><<<(B_N + 63) / 64, 256, 0, stream>>>(
        xb16c, WbbP, nullptr, nullptr, bbb, nullptr, h16a, B_N);
    k_gather_bb<<<(B_N + 3) / 4, 256, 0, stream>>>(rs_bb, eidx, h16a, agg16);
    k_mgemm<4, 4, true><<<(B_N + 63) / 64, 256, 0, stream>>>(
        (const short*)agg16, Wl1P, (const short*)h16a, Wr1P, bl1, nullptr, h16b, B_N);
    k_gather_bb<<<(B_N + 3) / 4, 256, 0, stream>>>(rs_bb, eidx, h16b, agg16);
    k_mgemm<4, 4, true><<<(B_N + 63) / 64, 256, 0, stream>>>(
        (const short*)agg16, Wl2P, (const short*)h16b, Wr2P, bl2, nullptr, content16, B_N);

    // ---- fusion (MFMA attn head with merged blend epilogue) + scores ----
    k_attn<<<(B_N + 63) / 64, 256, 0, stream>>>(
        (const short*)collab16, Wf1P, (const short*)content16, Wf1P + 16384,
        bf1v, Wf2, bf2v, fused16, B_N);
    k_score<<<NP / 32, 256, 0, stream>>>(pred_u, pred_b, uemb16, fused16, out);
}